// Round 1
// baseline (2208.422 us; speedup 1.0000x reference)
//
#include <hip/hip_runtime.h>
#include <math.h>

// Problem constants (from reference)
constexpr int N_NODES = 50000;
constexpr int E_EDGES = 800000;
constexpr int ETOT    = E_EDGES + N_NODES;   // self-loops appended
constexpr int IN_C    = 128;
constexpr int HID     = 64;
constexpr int HEADS   = 5;
constexpr int CLS     = 40;
constexpr float NEG_SLOPE = 0.2f;

// ---------------------------------------------------------------------------
// monotone float<->uint key for atomicMax on floats
__device__ __forceinline__ unsigned fkey(float f) {
    unsigned u = __float_as_uint(f);
    return (u & 0x80000000u) ? ~u : (u | 0x80000000u);
}
__device__ __forceinline__ float funkey(unsigned k) {
    unsigned u = (k & 0x80000000u) ? (k ^ 0x80000000u) : ~k;
    return __uint_as_float(u);
}
__device__ __forceinline__ float lrelu(float v) {
    return v > 0.f ? v : NEG_SLOPE * v;
}

// ---------------------------------------------------------------------------
// Tiled f32 GEMM: C[M,N] = A[M,K] @ B[K,N] (+bias per col). 64x64 tile,
// 4x4 per-thread register block, K-tile 16. K must be a multiple of 16.
__global__ __launch_bounds__(256) void gemm_bias(
    const float* __restrict__ A, const float* __restrict__ B,
    const float* __restrict__ bias, float* __restrict__ C,
    int M, int K, int N)
{
    __shared__ float As[16][64];
    __shared__ float Bs[16][64];
    const int tid = threadIdx.x;
    const int tx = tid & 15;     // col group (0..15)
    const int ty = tid >> 4;     // row group (0..15)
    const int row0 = blockIdx.x * 64;
    const int col0 = blockIdx.y * 64;

    const int ar = tid >> 2;         // 0..63 (row in A tile)
    const int ak = (tid & 3) * 4;    // k offset (0,4,8,12)
    const int bk = tid >> 6;         // 0..3
    const int bn = tid & 63;         // col in B tile

    float acc[4][4] = {};

    for (int k0 = 0; k0 < K; k0 += 16) {
        // stage A (transposed into As[k][row])
        float4 av = make_float4(0.f, 0.f, 0.f, 0.f);
        int arow = row0 + ar;
        if (arow < M) av = *(const float4*)(A + (long)arow * K + k0 + ak);
        As[ak + 0][ar] = av.x; As[ak + 1][ar] = av.y;
        As[ak + 2][ar] = av.z; As[ak + 3][ar] = av.w;
        // stage B
        #pragma unroll
        for (int kk2 = 0; kk2 < 4; kk2++) {
            int krow = bk + kk2 * 4;
            int bcol = col0 + bn;
            Bs[krow][bn] = (bcol < N) ? B[(long)(k0 + krow) * N + bcol] : 0.f;
        }
        __syncthreads();
        #pragma unroll
        for (int kk = 0; kk < 16; kk++) {
            float4 a4 = *(const float4*)&As[kk][ty * 4];
            float4 b4 = *(const float4*)&Bs[kk][tx * 4];
            float ar4[4] = {a4.x, a4.y, a4.z, a4.w};
            float br4[4] = {b4.x, b4.y, b4.z, b4.w};
            #pragma unroll
            for (int i = 0; i < 4; i++)
                #pragma unroll
                for (int j = 0; j < 4; j++)
                    acc[i][j] += ar4[i] * br4[j];
        }
        __syncthreads();
    }

    #pragma unroll
    for (int i = 0; i < 4; i++) {
        int row = row0 + ty * 4 + i;
        if (row >= M) continue;
        #pragma unroll
        for (int j = 0; j < 4; j++) {
            int col = col0 + tx * 4 + j;
            if (col < N) {
                float v = acc[i][j];
                if (bias) v += bias[col];
                C[(long)row * N + col] = v;
            }
        }
    }
}

// ---------------------------------------------------------------------------
// a_s[n,h] = dot(hp[n,h,:], att_src[h,:]);  a_d likewise. one thread per (n,h)
__global__ void attn_scores(const float* __restrict__ hp,
                            const float* __restrict__ att_s,
                            const float* __restrict__ att_d,
                            float* __restrict__ a_s, float* __restrict__ a_d,
                            int N, int C)
{
    int i = blockIdx.x * blockDim.x + threadIdx.x;
    if (i >= N * HEADS) return;
    int n = i / HEADS, h = i % HEADS;
    const float* p  = hp + (long)n * HEADS * C + h * C;
    const float* as = att_s + h * C;
    const float* ad = att_d + h * C;
    float ss = 0.f, sd = 0.f;
    for (int c = 0; c < C; c += 4) {
        float4 xv = *(const float4*)(p + c);
        float4 uv = *(const float4*)(as + c);
        float4 wv = *(const float4*)(ad + c);
        ss += xv.x * uv.x + xv.y * uv.y + xv.z * uv.z + xv.w * uv.w;
        sd += xv.x * wv.x + xv.y * wv.y + xv.z * wv.z + xv.w * wv.w;
    }
    a_s[i] = ss;
    a_d[i] = sd;
}

// ---------------------------------------------------------------------------
__device__ __forceinline__ void edge_sd(const int* __restrict__ ei, int e,
                                        int& s, int& d)
{
    if (e < E_EDGES) { s = ei[e]; d = ei[E_EDGES + e]; }
    else             { s = d = e - E_EDGES; }
}

// pass 1: segment max (into uint keys, init 0)
__global__ void edge_max(const int* __restrict__ ei,
                         const float* __restrict__ a_s,
                         const float* __restrict__ a_d,
                         unsigned* __restrict__ m)
{
    int e = blockIdx.x * blockDim.x + threadIdx.x;
    if (e >= ETOT) return;
    int s, d; edge_sd(ei, e, s, d);
    #pragma unroll
    for (int h = 0; h < HEADS; h++) {
        float v = lrelu(a_s[s * HEADS + h] + a_d[d * HEADS + h]);
        atomicMax(&m[d * HEADS + h], fkey(v));
    }
}

// pass 2: segment sum of exp(v - m)
__global__ void edge_sum(const int* __restrict__ ei,
                         const float* __restrict__ a_s,
                         const float* __restrict__ a_d,
                         const unsigned* __restrict__ m,
                         float* __restrict__ ssum)
{
    int e = blockIdx.x * blockDim.x + threadIdx.x;
    if (e >= ETOT) return;
    int s, d; edge_sd(ei, e, s, d);
    #pragma unroll
    for (int h = 0; h < HEADS; h++) {
        float v  = lrelu(a_s[s * HEADS + h] + a_d[d * HEADS + h]);
        float mm = funkey(m[d * HEADS + h]);
        atomicAdd(&ssum[d * HEADS + h], __expf(v - mm));
    }
}

// pass 3 (layer 1): out[d,h,c] += hp[s,h,c]*alpha  (C=64, 5 heads → 320/edge)
__global__ void edge_aggr1(const int* __restrict__ ei,
                           const float* __restrict__ a_s,
                           const float* __restrict__ a_d,
                           const unsigned* __restrict__ m,
                           const float* __restrict__ ssum,
                           const float* __restrict__ hp,
                           float* __restrict__ out)
{
    int wave = (blockIdx.x * blockDim.x + threadIdx.x) >> 6;
    int lane = threadIdx.x & 63;
    if (wave >= ETOT) return;
    int s, d; edge_sd(ei, wave, s, d);
    float alpha[HEADS];
    #pragma unroll
    for (int h = 0; h < HEADS; h++) {
        float v  = lrelu(a_s[s * HEADS + h] + a_d[d * HEADS + h]);
        float mm = funkey(m[d * HEADS + h]);
        alpha[h] = __expf(v - mm) / (ssum[d * HEADS + h] + 1e-16f);
    }
    const float* hs = hp + (long)s * (HEADS * HID);
    float* od = out + (long)d * (HEADS * HID);
    #pragma unroll
    for (int i = 0; i < HEADS; i++) {
        int c = i * 64 + lane;           // head == i since HID==64
        atomicAdd(&od[c], hs[c] * alpha[i]);
    }
}

// pass 3 (layer 2): out[d,c] += mean_h hp[s,h,c]*alpha[h]   (C=40)
__global__ void edge_aggr2(const int* __restrict__ ei,
                           const float* __restrict__ a_s,
                           const float* __restrict__ a_d,
                           const unsigned* __restrict__ m,
                           const float* __restrict__ ssum,
                           const float* __restrict__ hp,
                           float* __restrict__ out)
{
    int wave = (blockIdx.x * blockDim.x + threadIdx.x) >> 6;
    int lane = threadIdx.x & 63;
    if (wave >= ETOT) return;
    int s, d; edge_sd(ei, wave, s, d);
    float alpha[HEADS];
    #pragma unroll
    for (int h = 0; h < HEADS; h++) {
        float v  = lrelu(a_s[s * HEADS + h] + a_d[d * HEADS + h]);
        float mm = funkey(m[d * HEADS + h]);
        alpha[h] = __expf(v - mm) / (ssum[d * HEADS + h] + 1e-16f);
    }
    if (lane < CLS) {
        const float* hs = hp + (long)s * (HEADS * CLS);
        float acc = 0.f;
        #pragma unroll
        for (int h = 0; h < HEADS; h++)
            acc += hs[h * CLS + lane] * alpha[h];
        atomicAdd(&out[(long)d * CLS + lane], 0.2f * acc);  // mean over 5 heads
    }
}

// bias + ELU (in place)
__global__ void bias_elu(float* __restrict__ x, const float* __restrict__ bias,
                         int total, int ncols)
{
    int i = blockIdx.x * blockDim.x + threadIdx.x;
    if (i >= total) return;
    float v = x[i] + bias[i % ncols];
    x[i] = v > 0.f ? v : expm1f(v);
}

// log_softmax over 40 classes, wave per node
__global__ void logsoftmax40(const float* __restrict__ in,
                             const float* __restrict__ bias,
                             float* __restrict__ out)
{
    int wave = (blockIdx.x * blockDim.x + threadIdx.x) >> 6;
    int lane = threadIdx.x & 63;
    if (wave >= N_NODES) return;
    float v = (lane < CLS) ? in[(long)wave * CLS + lane] + bias[lane] : -INFINITY;
    float mx = v;
    #pragma unroll
    for (int off = 32; off > 0; off >>= 1)
        mx = fmaxf(mx, __shfl_xor(mx, off));
    float ex = (lane < CLS) ? __expf(v - mx) : 0.f;
    float sm = ex;
    #pragma unroll
    for (int off = 32; off > 0; off >>= 1)
        sm += __shfl_xor(sm, off);
    float ls = logf(sm);
    if (lane < CLS) out[(long)wave * CLS + lane] = v - mx - ls;
}

// ---------------------------------------------------------------------------
extern "C" void kernel_launch(void* const* d_in, const int* in_sizes, int n_in,
                              void* d_out, int out_size, void* d_ws, size_t ws_size,
                              hipStream_t stream)
{
    const float* x     = (const float*)d_in[0];
    const int*   ei    = (const int*)d_in[1];
    const float* emb_W = (const float*)d_in[2];
    const float* emb_b = (const float*)d_in[3];
    const float* W1    = (const float*)d_in[4];
    const float* as1   = (const float*)d_in[5];
    const float* ad1   = (const float*)d_in[6];
    const float* b1    = (const float*)d_in[7];
    const float* W2    = (const float*)d_in[8];
    const float* as2   = (const float*)d_in[9];
    const float* ad2   = (const float*)d_in[10];
    const float* b2    = (const float*)d_in[11];

    float* out_emb = (float*)d_out;                         // [N,64]
    float* out_cls = (float*)d_out + (size_t)N_NODES * HID; // [N,40]

    char* ws = (char*)d_ws;
    // layer-1 buffers
    float*    hp1  = (float*)(ws);                  // 64 MB  [N,5,64]
    float*    h1   = (float*)(ws + 64000000);       // 64 MB  [N,320] acc -> h1
    float*    a_s1 = (float*)(ws + 128000000);      // 1 MB
    float*    a_d1 = (float*)(ws + 129000000);      // 1 MB
    unsigned* m1   = (unsigned*)(ws + 130000000);   // 1 MB
    float*    s1   = (float*)(ws + 131000000);      // 1 MB
    // layer-2 buffers reuse the hp1 region (hp1 dead after edge_aggr1)
    float*    hp2  = (float*)(ws);                  // 40 MB  [N,5,40]
    float*    o2   = (float*)(ws + 40000000);       // 8 MB   [N,40]
    float*    a_s2 = (float*)(ws + 48000000);
    float*    a_d2 = (float*)(ws + 49000000);
    unsigned* m2   = (unsigned*)(ws + 50000000);
    float*    s2   = (float*)(ws + 51000000);

    const dim3 blk(256);
    const int mt = (N_NODES + 63) / 64;            // 782 row tiles
    const int nhb = (N_NODES * HEADS + 255) / 256;
    const int eb  = (ETOT + 255) / 256;
    const int wb  = (ETOT + 3) / 4;                // 4 edge-waves per block

    // ---- embedding ----
    gemm_bias<<<dim3(mt, 1), blk, 0, stream>>>(x, emb_W, emb_b, out_emb,
                                               N_NODES, IN_C, HID);

    // ---- layer 1 ----
    gemm_bias<<<dim3(mt, 5), blk, 0, stream>>>(out_emb, W1, nullptr, hp1,
                                               N_NODES, HID, HEADS * HID);
    attn_scores<<<nhb, blk, 0, stream>>>(hp1, as1, ad1, a_s1, a_d1, N_NODES, HID);
    hipMemsetAsync(m1, 0, (size_t)N_NODES * HEADS * 4, stream);
    hipMemsetAsync(s1, 0, (size_t)N_NODES * HEADS * 4, stream);
    hipMemsetAsync(h1, 0, (size_t)N_NODES * HEADS * HID * 4, stream);
    edge_max<<<eb, blk, 0, stream>>>(ei, a_s1, a_d1, m1);
    edge_sum<<<eb, blk, 0, stream>>>(ei, a_s1, a_d1, m1, s1);
    edge_aggr1<<<wb, blk, 0, stream>>>(ei, a_s1, a_d1, m1, s1, hp1, h1);
    int tot1 = N_NODES * HEADS * HID;
    bias_elu<<<(tot1 + 255) / 256, blk, 0, stream>>>(h1, b1, tot1, HEADS * HID);

    // ---- layer 2 ----
    gemm_bias<<<dim3(mt, 4), blk, 0, stream>>>(h1, W2, nullptr, hp2,
                                               N_NODES, HEADS * HID, HEADS * CLS);
    attn_scores<<<nhb, blk, 0, stream>>>(hp2, as2, ad2, a_s2, a_d2, N_NODES, CLS);
    hipMemsetAsync(m2, 0, (size_t)N_NODES * HEADS * 4, stream);
    hipMemsetAsync(s2, 0, (size_t)N_NODES * HEADS * 4, stream);
    hipMemsetAsync(o2, 0, (size_t)N_NODES * CLS * 4, stream);
    edge_max<<<eb, blk, 0, stream>>>(ei, a_s2, a_d2, m2);
    edge_sum<<<eb, blk, 0, stream>>>(ei, a_s2, a_d2, m2, s2);
    edge_aggr2<<<wb, blk, 0, stream>>>(ei, a_s2, a_d2, m2, s2, hp2, o2);

    // ---- log_softmax ----
    logsoftmax40<<<(N_NODES + 3) / 4, blk, 0, stream>>>(o2, b2, out_cls);
}

// Round 2
// 896.774 us; speedup vs baseline: 2.4626x; 2.4626x over previous
//
#include <hip/hip_runtime.h>
#include <math.h>

// Problem constants (from reference)
constexpr int N_NODES = 50000;
constexpr int E_EDGES = 800000;
constexpr int ETOT    = E_EDGES + N_NODES;   // self-loops appended
constexpr int IN_C    = 128;
constexpr int HID     = 64;
constexpr int HEADS   = 5;
constexpr int CLS     = 40;
constexpr float NEG_SLOPE = 0.2f;

__device__ __forceinline__ float lrelu(float v) {
    return v > 0.f ? v : NEG_SLOPE * v;
}

// ---------------------------------------------------------------------------
// Tiled f32 GEMM: C[M,N] = A[M,K] @ B[K,N] (+bias per col). 64x64 tile,
// 4x4 per-thread register block, K-tile 16. K must be a multiple of 16.
__global__ __launch_bounds__(256) void gemm_bias(
    const float* __restrict__ A, const float* __restrict__ B,
    const float* __restrict__ bias, float* __restrict__ C,
    int M, int K, int N)
{
    __shared__ float As[16][64];
    __shared__ float Bs[16][64];
    const int tid = threadIdx.x;
    const int tx = tid & 15;     // col group (0..15)
    const int ty = tid >> 4;     // row group (0..15)
    const int row0 = blockIdx.x * 64;
    const int col0 = blockIdx.y * 64;

    const int ar = tid >> 2;         // 0..63 (row in A tile)
    const int ak = (tid & 3) * 4;    // k offset (0,4,8,12)
    const int bk = tid >> 6;         // 0..3
    const int bn = tid & 63;         // col in B tile

    float acc[4][4] = {};

    for (int k0 = 0; k0 < K; k0 += 16) {
        float4 av = make_float4(0.f, 0.f, 0.f, 0.f);
        int arow = row0 + ar;
        if (arow < M) av = *(const float4*)(A + (long)arow * K + k0 + ak);
        As[ak + 0][ar] = av.x; As[ak + 1][ar] = av.y;
        As[ak + 2][ar] = av.z; As[ak + 3][ar] = av.w;
        #pragma unroll
        for (int kk2 = 0; kk2 < 4; kk2++) {
            int krow = bk + kk2 * 4;
            int bcol = col0 + bn;
            Bs[krow][bn] = (bcol < N) ? B[(long)(k0 + krow) * N + bcol] : 0.f;
        }
        __syncthreads();
        #pragma unroll
        for (int kk = 0; kk < 16; kk++) {
            float4 a4 = *(const float4*)&As[kk][ty * 4];
            float4 b4 = *(const float4*)&Bs[kk][tx * 4];
            float ar4[4] = {a4.x, a4.y, a4.z, a4.w};
            float br4[4] = {b4.x, b4.y, b4.z, b4.w};
            #pragma unroll
            for (int i = 0; i < 4; i++)
                #pragma unroll
                for (int j = 0; j < 4; j++)
                    acc[i][j] += ar4[i] * br4[j];
        }
        __syncthreads();
    }

    #pragma unroll
    for (int i = 0; i < 4; i++) {
        int row = row0 + ty * 4 + i;
        if (row >= M) continue;
        #pragma unroll
        for (int j = 0; j < 4; j++) {
            int col = col0 + tx * 4 + j;
            if (col < N) {
                float v = acc[i][j];
                if (bias) v += bias[col];
                C[(long)row * N + col] = v;
            }
        }
    }
}

// ---------------------------------------------------------------------------
// a_s[n,h] = dot(hp[n,h,:], att_src[h,:]);  a_d likewise. one thread per (n,h)
__global__ void attn_scores(const float* __restrict__ hp,
                            const float* __restrict__ att_s,
                            const float* __restrict__ att_d,
                            float* __restrict__ a_s, float* __restrict__ a_d,
                            int N, int C)
{
    int i = blockIdx.x * blockDim.x + threadIdx.x;
    if (i >= N * HEADS) return;
    int n = i / HEADS, h = i % HEADS;
    const float* p  = hp + (long)n * HEADS * C + h * C;
    const float* as = att_s + h * C;
    const float* ad = att_d + h * C;
    float ss = 0.f, sd = 0.f;
    for (int c = 0; c < C; c += 4) {
        float4 xv = *(const float4*)(p + c);
        float4 uv = *(const float4*)(as + c);
        float4 wv = *(const float4*)(ad + c);
        ss += xv.x * uv.x + xv.y * uv.y + xv.z * uv.z + xv.w * uv.w;
        sd += xv.x * wv.x + xv.y * wv.y + xv.z * wv.z + xv.w * wv.w;
    }
    a_s[i] = ss;
    a_d[i] = sd;
}

// ---------------------------------------------------------------------------
// CSR build: histogram -> exclusive scan (3 kernels) -> scatter.
// rowptr[i] holds deg(i) after hist; after scan, start offset of node i;
// after scatter (atomicAdd cursor trick), rowptr[i] = end offset of node i.
__global__ void hist_deg(const int* __restrict__ ei, int* __restrict__ rowptr)
{
    int e = blockIdx.x * blockDim.x + threadIdx.x;
    if (e >= ETOT) return;
    int d = (e < E_EDGES) ? ei[E_EDGES + e] : e - E_EDGES;
    atomicAdd(&rowptr[d], 1);
}

__global__ void scan_block_sums(const int* __restrict__ v, int* __restrict__ bsum, int n)
{
    __shared__ int sm[256];
    int i = blockIdx.x * 256 + threadIdx.x;
    sm[threadIdx.x] = (i < n) ? v[i] : 0;
    __syncthreads();
    #pragma unroll
    for (int off = 128; off; off >>= 1) {
        if (threadIdx.x < off) sm[threadIdx.x] += sm[threadIdx.x + off];
        __syncthreads();
    }
    if (threadIdx.x == 0) bsum[blockIdx.x] = sm[0];
}

__global__ void scan_bsum(int* __restrict__ bsum, int nb)
{
    if (threadIdx.x != 0 || blockIdx.x != 0) return;
    int run = 0;
    for (int b = 0; b < nb; b++) { int t = bsum[b]; bsum[b] = run; run += t; }
}

__global__ void scan_final(int* __restrict__ v, const int* __restrict__ bsum, int n)
{
    __shared__ int sm[256];
    int i = blockIdx.x * 256 + threadIdx.x;
    int x = (i < n) ? v[i] : 0;
    sm[threadIdx.x] = x;
    __syncthreads();
    #pragma unroll
    for (int off = 1; off < 256; off <<= 1) {
        int t = (threadIdx.x >= (unsigned)off) ? sm[threadIdx.x - off] : 0;
        __syncthreads();
        sm[threadIdx.x] += t;
        __syncthreads();
    }
    if (i < n) v[i] = bsum[blockIdx.x] + sm[threadIdx.x] - x;  // exclusive
}

__global__ void scatter_src(const int* __restrict__ ei, int* __restrict__ rowptr,
                            unsigned short* __restrict__ srcs)
{
    int e = blockIdx.x * blockDim.x + threadIdx.x;
    if (e >= ETOT) return;
    int s, d;
    if (e < E_EDGES) { s = ei[e]; d = ei[E_EDGES + e]; }
    else             { s = d = e - E_EDGES; }
    int pos = atomicAdd(&rowptr[d], 1);
    srcs[pos] = (unsigned short)s;
}

// ---------------------------------------------------------------------------
// Layer-1 fused GAT: wave per dst node. max -> sumexp -> aggregate, all in
// registers via shuffle reductions. Fused bias + ELU. No atomics.
// Segment of node d (post-scatter): [d==0?0:rowptr[d-1], rowptr[d])
__global__ __launch_bounds__(256) void gat_node1(
    const int* __restrict__ rowptr, const unsigned short* __restrict__ srcs,
    const float* __restrict__ a_s, const float* __restrict__ a_d,
    const float* __restrict__ hp, const float* __restrict__ bias,
    float* __restrict__ out)
{
    int wid = (blockIdx.x * blockDim.x + threadIdx.x) >> 6;
    int lane = threadIdx.x & 63;
    if (wid >= N_NODES) return;
    int beg = (wid == 0) ? 0 : rowptr[wid - 1];
    int end = rowptr[wid];

    float adh[HEADS];
    #pragma unroll
    for (int h = 0; h < HEADS; h++) adh[h] = a_d[wid * HEADS + h];

    // pass 1: per-head max
    float mx[HEADS];
    #pragma unroll
    for (int h = 0; h < HEADS; h++) mx[h] = -1e30f;
    for (int e = beg + lane; e < end; e += 64) {
        int s = srcs[e];
        #pragma unroll
        for (int h = 0; h < HEADS; h++)
            mx[h] = fmaxf(mx[h], lrelu(a_s[s * HEADS + h] + adh[h]));
    }
    #pragma unroll
    for (int h = 0; h < HEADS; h++)
        #pragma unroll
        for (int off = 32; off; off >>= 1)
            mx[h] = fmaxf(mx[h], __shfl_xor(mx[h], off));

    // pass 2: per-head sum of exp
    float sm[HEADS] = {};
    for (int e = beg + lane; e < end; e += 64) {
        int s = srcs[e];
        #pragma unroll
        for (int h = 0; h < HEADS; h++)
            sm[h] += __expf(lrelu(a_s[s * HEADS + h] + adh[h]) - mx[h]);
    }
    #pragma unroll
    for (int h = 0; h < HEADS; h++) {
        #pragma unroll
        for (int off = 32; off; off >>= 1)
            sm[h] += __shfl_xor(sm[h], off);
        sm[h] = 1.f / (sm[h] + 1e-16f);
    }

    // pass 3: weighted aggregate, edge-sequential; lane = channel, head = chunk
    float acc[HEADS] = {};
    for (int e = beg; e < end; e++) {
        int s = srcs[e];
        const float* hs = hp + (long)s * (HEADS * HID);
        #pragma unroll
        for (int h = 0; h < HEADS; h++) {
            float alpha = __expf(lrelu(a_s[s * HEADS + h] + adh[h]) - mx[h]) * sm[h];
            acc[h] += hs[h * HID + lane] * alpha;
        }
    }

    // bias + ELU + store
    #pragma unroll
    for (int h = 0; h < HEADS; h++) {
        float v = acc[h] + bias[h * HID + lane];
        out[(long)wid * (HEADS * HID) + h * HID + lane] = v > 0.f ? v : expm1f(v);
    }
}

// ---------------------------------------------------------------------------
// Layer-2 fused GAT: wave per dst node, C=40. Fused head-mean + bias +
// log_softmax. Writes final output rows.
__global__ __launch_bounds__(256) void gat_node2(
    const int* __restrict__ rowptr, const unsigned short* __restrict__ srcs,
    const float* __restrict__ a_s, const float* __restrict__ a_d,
    const float* __restrict__ hp, const float* __restrict__ bias,
    float* __restrict__ out)
{
    int wid = (blockIdx.x * blockDim.x + threadIdx.x) >> 6;
    int lane = threadIdx.x & 63;
    if (wid >= N_NODES) return;
    int beg = (wid == 0) ? 0 : rowptr[wid - 1];
    int end = rowptr[wid];

    float adh[HEADS];
    #pragma unroll
    for (int h = 0; h < HEADS; h++) adh[h] = a_d[wid * HEADS + h];

    float mx[HEADS];
    #pragma unroll
    for (int h = 0; h < HEADS; h++) mx[h] = -1e30f;
    for (int e = beg + lane; e < end; e += 64) {
        int s = srcs[e];
        #pragma unroll
        for (int h = 0; h < HEADS; h++)
            mx[h] = fmaxf(mx[h], lrelu(a_s[s * HEADS + h] + adh[h]));
    }
    #pragma unroll
    for (int h = 0; h < HEADS; h++)
        #pragma unroll
        for (int off = 32; off; off >>= 1)
            mx[h] = fmaxf(mx[h], __shfl_xor(mx[h], off));

    float sm[HEADS] = {};
    for (int e = beg + lane; e < end; e += 64) {
        int s = srcs[e];
        #pragma unroll
        for (int h = 0; h < HEADS; h++)
            sm[h] += __expf(lrelu(a_s[s * HEADS + h] + adh[h]) - mx[h]);
    }
    #pragma unroll
    for (int h = 0; h < HEADS; h++) {
        #pragma unroll
        for (int off = 32; off; off >>= 1)
            sm[h] += __shfl_xor(sm[h], off);
        sm[h] = 1.f / (sm[h] + 1e-16f);
    }

    float acc[HEADS] = {};
    for (int e = beg; e < end; e++) {
        int s = srcs[e];
        const float* hs = hp + (long)s * (HEADS * CLS);
        #pragma unroll
        for (int h = 0; h < HEADS; h++) {
            float alpha = __expf(lrelu(a_s[s * HEADS + h] + adh[h]) - mx[h]) * sm[h];
            if (lane < CLS) acc[h] += hs[h * CLS + lane] * alpha;
        }
    }

    // head mean + bias
    float v = -1e30f;
    if (lane < CLS) {
        float t = 0.f;
        #pragma unroll
        for (int h = 0; h < HEADS; h++) t += acc[h];
        v = 0.2f * t + bias[lane];
    }
    // log_softmax over 40 classes within the wave
    float mxv = v;
    #pragma unroll
    for (int off = 32; off; off >>= 1) mxv = fmaxf(mxv, __shfl_xor(mxv, off));
    float ex = (lane < CLS) ? __expf(v - mxv) : 0.f;
    float sme = ex;
    #pragma unroll
    for (int off = 32; off; off >>= 1) sme += __shfl_xor(sme, off);
    float ls = logf(sme);
    if (lane < CLS) out[(long)wid * CLS + lane] = v - mxv - ls;
}

// ---------------------------------------------------------------------------
extern "C" void kernel_launch(void* const* d_in, const int* in_sizes, int n_in,
                              void* d_out, int out_size, void* d_ws, size_t ws_size,
                              hipStream_t stream)
{
    const float* x     = (const float*)d_in[0];
    const int*   ei    = (const int*)d_in[1];
    const float* emb_W = (const float*)d_in[2];
    const float* emb_b = (const float*)d_in[3];
    const float* W1    = (const float*)d_in[4];
    const float* as1   = (const float*)d_in[5];
    const float* ad1   = (const float*)d_in[6];
    const float* b1    = (const float*)d_in[7];
    const float* W2    = (const float*)d_in[8];
    const float* as2   = (const float*)d_in[9];
    const float* ad2   = (const float*)d_in[10];
    const float* b2    = (const float*)d_in[11];

    float* out_emb = (float*)d_out;                         // [N,64]
    float* out_cls = (float*)d_out + (size_t)N_NODES * HID; // [N,40]

    char* ws = (char*)d_ws;
    float*          hp1    = (float*)(ws);                    // 64 MB [N,5,64]
    float*          h1     = (float*)(ws + 64000000);         // 64 MB [N,320]
    float*          a_s    = (float*)(ws + 128000000);        // 1 MB [N,5]
    float*          a_d    = (float*)(ws + 129000000);        // 1 MB [N,5]
    int*            rowptr = (int*)(ws + 130000000);          // (N+1)*4
    int*            bsum   = (int*)(ws + 130200064);          // 196*4
    unsigned short* srcs   = (unsigned short*)(ws + 130200896); // 1.7 MB
    // layer-2 hp reuses hp1 region (hp1 dead after gat_node1): [N,5,40] 40 MB
    float*          hp2    = (float*)(ws);

    const dim3 blk(256);
    const int mt  = (N_NODES + 63) / 64;           // 782 row tiles
    const int nhb = (N_NODES * HEADS + 255) / 256;
    const int eb  = (ETOT + 255) / 256;            // 3321
    const int nb4 = (N_NODES + 3) / 4;             // 12500 (wave-per-node)
    const int nscan = N_NODES + 1;                 // 50001
    const int NB = (nscan + 255) / 256;            // 196

    // ---- CSR build (graph is identical for both layers) ----
    hipMemsetAsync(rowptr, 0, (size_t)nscan * 4, stream);
    hist_deg<<<eb, blk, 0, stream>>>(ei, rowptr);
    scan_block_sums<<<NB, blk, 0, stream>>>(rowptr, bsum, nscan);
    scan_bsum<<<1, 64, 0, stream>>>(bsum, NB);
    scan_final<<<NB, blk, 0, stream>>>(rowptr, bsum, nscan);
    scatter_src<<<eb, blk, 0, stream>>>(ei, rowptr, srcs);

    // ---- embedding ----
    gemm_bias<<<dim3(mt, 1), blk, 0, stream>>>(x, emb_W, emb_b, out_emb,
                                               N_NODES, IN_C, HID);

    // ---- layer 1 ----
    gemm_bias<<<dim3(mt, 5), blk, 0, stream>>>(out_emb, W1, nullptr, hp1,
                                               N_NODES, HID, HEADS * HID);
    attn_scores<<<nhb, blk, 0, stream>>>(hp1, as1, ad1, a_s, a_d, N_NODES, HID);
    gat_node1<<<nb4, blk, 0, stream>>>(rowptr, srcs, a_s, a_d, hp1, b1, h1);

    // ---- layer 2 ----
    gemm_bias<<<dim3(mt, 4), blk, 0, stream>>>(h1, W2, nullptr, hp2,
                                               N_NODES, HEADS * HID, HEADS * CLS);
    attn_scores<<<nhb, blk, 0, stream>>>(hp2, as2, ad2, a_s, a_d, N_NODES, CLS);
    gat_node2<<<nb4, blk, 0, stream>>>(rowptr, srcs, a_s, a_d, hp2, b2, out_cls);
}

// Round 3
// 645.718 us; speedup vs baseline: 3.4201x; 1.3888x over previous
//
#include <hip/hip_runtime.h>
#include <hip/hip_bf16.h>
#include <math.h>

// Problem constants (from reference)
constexpr int N_NODES = 50000;
constexpr int E_EDGES = 800000;
constexpr int ETOT    = E_EDGES + N_NODES;   // self-loops appended
constexpr int IN_C    = 128;
constexpr int HID     = 64;
constexpr int HEADS   = 5;
constexpr int CLS     = 40;
constexpr float NEG_SLOPE = 0.2f;

__device__ __forceinline__ float lrelu(float v) {
    return v > 0.f ? v : NEG_SLOPE * v;
}
__device__ __forceinline__ float bf2f(unsigned short u) {
    return __uint_as_float(((unsigned)u) << 16);
}

// ---------------------------------------------------------------------------
// Tiled f32 GEMM, f32 output (+bias). Used for the embedding (output 0).
__global__ __launch_bounds__(256) void gemm_bias(
    const float* __restrict__ A, const float* __restrict__ B,
    const float* __restrict__ bias, float* __restrict__ C,
    int M, int K, int N)
{
    __shared__ float As[16][64];
    __shared__ float Bs[16][64];
    const int tid = threadIdx.x;
    const int tx = tid & 15;
    const int ty = tid >> 4;
    const int row0 = blockIdx.x * 64;
    const int col0 = blockIdx.y * 64;

    const int ar = tid >> 2;
    const int ak = (tid & 3) * 4;
    const int bk = tid >> 6;
    const int bn = tid & 63;

    float acc[4][4] = {};

    for (int k0 = 0; k0 < K; k0 += 16) {
        float4 av = make_float4(0.f, 0.f, 0.f, 0.f);
        int arow = row0 + ar;
        if (arow < M) av = *(const float4*)(A + (long)arow * K + k0 + ak);
        As[ak + 0][ar] = av.x; As[ak + 1][ar] = av.y;
        As[ak + 2][ar] = av.z; As[ak + 3][ar] = av.w;
        #pragma unroll
        for (int kk2 = 0; kk2 < 4; kk2++) {
            int krow = bk + kk2 * 4;
            int bcol = col0 + bn;
            Bs[krow][bn] = (bcol < N) ? B[(long)(k0 + krow) * N + bcol] : 0.f;
        }
        __syncthreads();
        #pragma unroll
        for (int kk = 0; kk < 16; kk++) {
            float4 a4 = *(const float4*)&As[kk][ty * 4];
            float4 b4 = *(const float4*)&Bs[kk][tx * 4];
            float ar4[4] = {a4.x, a4.y, a4.z, a4.w};
            float br4[4] = {b4.x, b4.y, b4.z, b4.w};
            #pragma unroll
            for (int i = 0; i < 4; i++)
                #pragma unroll
                for (int j = 0; j < 4; j++)
                    acc[i][j] += ar4[i] * br4[j];
        }
        __syncthreads();
    }

    #pragma unroll
    for (int i = 0; i < 4; i++) {
        int row = row0 + ty * 4 + i;
        if (row >= M) continue;
        #pragma unroll
        for (int j = 0; j < 4; j++) {
            int col = col0 + tx * 4 + j;
            if (col < N) {
                float v = acc[i][j];
                if (bias) v += bias[col];
                C[(long)row * N + col] = v;
            }
        }
    }
}

// Same GEMM, bf16 output, no bias (hp projections).
__global__ __launch_bounds__(256) void gemm_bf16out(
    const float* __restrict__ A, const float* __restrict__ B,
    __hip_bfloat16* __restrict__ C, int M, int K, int N)
{
    __shared__ float As[16][64];
    __shared__ float Bs[16][64];
    const int tid = threadIdx.x;
    const int tx = tid & 15;
    const int ty = tid >> 4;
    const int row0 = blockIdx.x * 64;
    const int col0 = blockIdx.y * 64;

    const int ar = tid >> 2;
    const int ak = (tid & 3) * 4;
    const int bk = tid >> 6;
    const int bn = tid & 63;

    float acc[4][4] = {};

    for (int k0 = 0; k0 < K; k0 += 16) {
        float4 av = make_float4(0.f, 0.f, 0.f, 0.f);
        int arow = row0 + ar;
        if (arow < M) av = *(const float4*)(A + (long)arow * K + k0 + ak);
        As[ak + 0][ar] = av.x; As[ak + 1][ar] = av.y;
        As[ak + 2][ar] = av.z; As[ak + 3][ar] = av.w;
        #pragma unroll
        for (int kk2 = 0; kk2 < 4; kk2++) {
            int krow = bk + kk2 * 4;
            int bcol = col0 + bn;
            Bs[krow][bn] = (bcol < N) ? B[(long)(k0 + krow) * N + bcol] : 0.f;
        }
        __syncthreads();
        #pragma unroll
        for (int kk = 0; kk < 16; kk++) {
            float4 a4 = *(const float4*)&As[kk][ty * 4];
            float4 b4 = *(const float4*)&Bs[kk][tx * 4];
            float ar4[4] = {a4.x, a4.y, a4.z, a4.w};
            float br4[4] = {b4.x, b4.y, b4.z, b4.w};
            #pragma unroll
            for (int i = 0; i < 4; i++)
                #pragma unroll
                for (int j = 0; j < 4; j++)
                    acc[i][j] += ar4[i] * br4[j];
        }
        __syncthreads();
    }

    #pragma unroll
    for (int i = 0; i < 4; i++) {
        int row = row0 + ty * 4 + i;
        if (row >= M) continue;
        #pragma unroll
        for (int j = 0; j < 4; j++) {
            int col = col0 + tx * 4 + j;
            if (col < N)
                C[(long)row * N + col] = __float2bfloat16(acc[i][j]);
        }
    }
}

// ---------------------------------------------------------------------------
// a_s[n,h] = dot(hp[n,h,:], att_src[h,:]); hp in bf16. one thread per (n,h)
__global__ void attn_scores(const unsigned short* __restrict__ hp,
                            const float* __restrict__ att_s,
                            const float* __restrict__ att_d,
                            float* __restrict__ a_s, float* __restrict__ a_d,
                            int N, int C)
{
    int i = blockIdx.x * blockDim.x + threadIdx.x;
    if (i >= N * HEADS) return;
    int n = i / HEADS, h = i % HEADS;
    const unsigned short* p = hp + (long)n * HEADS * C + h * C;
    const float* as = att_s + h * C;
    const float* ad = att_d + h * C;
    float ss = 0.f, sd = 0.f;
    for (int c = 0; c < C; c += 4) {
        ushort4 xq = *(const ushort4*)(p + c);
        float4 uv = *(const float4*)(as + c);
        float4 wv = *(const float4*)(ad + c);
        float x0 = bf2f(xq.x), x1 = bf2f(xq.y), x2 = bf2f(xq.z), x3 = bf2f(xq.w);
        ss += x0 * uv.x + x1 * uv.y + x2 * uv.z + x3 * uv.w;
        sd += x0 * wv.x + x1 * wv.y + x2 * wv.z + x3 * wv.w;
    }
    a_s[i] = ss;
    a_d[i] = sd;
}

// ---------------------------------------------------------------------------
// CSR build: histogram -> exclusive scan -> scatter.
__global__ void hist_deg(const int* __restrict__ ei, int* __restrict__ rowptr)
{
    int e = blockIdx.x * blockDim.x + threadIdx.x;
    if (e >= ETOT) return;
    int d = (e < E_EDGES) ? ei[E_EDGES + e] : e - E_EDGES;
    atomicAdd(&rowptr[d], 1);
}

__global__ void scan_block_sums(const int* __restrict__ v, int* __restrict__ bsum, int n)
{
    __shared__ int sm[256];
    int i = blockIdx.x * 256 + threadIdx.x;
    sm[threadIdx.x] = (i < n) ? v[i] : 0;
    __syncthreads();
    #pragma unroll
    for (int off = 128; off; off >>= 1) {
        if (threadIdx.x < off) sm[threadIdx.x] += sm[threadIdx.x + off];
        __syncthreads();
    }
    if (threadIdx.x == 0) bsum[blockIdx.x] = sm[0];
}

__global__ void scan_bsum(int* __restrict__ bsum, int nb)
{
    if (threadIdx.x != 0 || blockIdx.x != 0) return;
    int run = 0;
    for (int b = 0; b < nb; b++) { int t = bsum[b]; bsum[b] = run; run += t; }
}

__global__ void scan_final(int* __restrict__ v, const int* __restrict__ bsum, int n)
{
    __shared__ int sm[256];
    int i = blockIdx.x * 256 + threadIdx.x;
    int x = (i < n) ? v[i] : 0;
    sm[threadIdx.x] = x;
    __syncthreads();
    #pragma unroll
    for (int off = 1; off < 256; off <<= 1) {
        int t = (threadIdx.x >= (unsigned)off) ? sm[threadIdx.x - off] : 0;
        __syncthreads();
        sm[threadIdx.x] += t;
        __syncthreads();
    }
    if (i < n) v[i] = bsum[blockIdx.x] + sm[threadIdx.x] - x;  // exclusive
}

__global__ void scatter_src(const int* __restrict__ ei, int* __restrict__ rowptr,
                            unsigned short* __restrict__ srcs)
{
    int e = blockIdx.x * blockDim.x + threadIdx.x;
    if (e >= ETOT) return;
    int s, d;
    if (e < E_EDGES) { s = ei[e]; d = ei[E_EDGES + e]; }
    else             { s = d = e - E_EDGES; }
    int pos = atomicAdd(&rowptr[d], 1);
    srcs[pos] = (unsigned short)s;
}

// ---------------------------------------------------------------------------
// edge_w: wave per dst node; computes normalized attention weights per edge:
//   w[e,h] = scale * exp(lrelu(a_s[s]+a_d[d]) - max) / (sumexp + 1e-16)
// Fast path deg<=64: one edge per lane, scores stay in registers.
__global__ __launch_bounds__(256) void edge_w(
    const int* __restrict__ rowptr, const unsigned short* __restrict__ srcs,
    const float* __restrict__ a_s, const float* __restrict__ a_d,
    float* __restrict__ w, float scale)
{
    int wid = (blockIdx.x * blockDim.x + threadIdx.x) >> 6;
    int lane = threadIdx.x & 63;
    if (wid >= N_NODES) return;
    int beg = (wid == 0) ? 0 : rowptr[wid - 1];
    int end = rowptr[wid];
    int deg = end - beg;

    float adh[HEADS];
    #pragma unroll
    for (int h = 0; h < HEADS; h++) adh[h] = a_d[wid * HEADS + h];

    if (deg <= 64) {
        bool has = lane < deg;
        int s = has ? srcs[beg + lane] : 0;
        float v[HEADS], mx[HEADS], sm[HEADS];
        #pragma unroll
        for (int h = 0; h < HEADS; h++) {
            v[h] = has ? lrelu(a_s[s * HEADS + h] + adh[h]) : -1e30f;
            mx[h] = v[h];
        }
        #pragma unroll
        for (int h = 0; h < HEADS; h++)
            #pragma unroll
            for (int off = 32; off; off >>= 1)
                mx[h] = fmaxf(mx[h], __shfl_xor(mx[h], off));
        #pragma unroll
        for (int h = 0; h < HEADS; h++) {
            float e = has ? __expf(v[h] - mx[h]) : 0.f;
            v[h] = e;     // keep numerator
            sm[h] = e;
        }
        #pragma unroll
        for (int h = 0; h < HEADS; h++)
            #pragma unroll
            for (int off = 32; off; off >>= 1)
                sm[h] += __shfl_xor(sm[h], off);
        if (has) {
            #pragma unroll
            for (int h = 0; h < HEADS; h++)
                w[(long)(beg + lane) * HEADS + h] = scale * v[h] / (sm[h] + 1e-16f);
        }
    } else {
        float mx[HEADS], sm[HEADS] = {};
        #pragma unroll
        for (int h = 0; h < HEADS; h++) mx[h] = -1e30f;
        for (int e = beg + lane; e < end; e += 64) {
            int s = srcs[e];
            #pragma unroll
            for (int h = 0; h < HEADS; h++)
                mx[h] = fmaxf(mx[h], lrelu(a_s[s * HEADS + h] + adh[h]));
        }
        #pragma unroll
        for (int h = 0; h < HEADS; h++)
            #pragma unroll
            for (int off = 32; off; off >>= 1)
                mx[h] = fmaxf(mx[h], __shfl_xor(mx[h], off));
        for (int e = beg + lane; e < end; e += 64) {
            int s = srcs[e];
            #pragma unroll
            for (int h = 0; h < HEADS; h++)
                sm[h] += __expf(lrelu(a_s[s * HEADS + h] + adh[h]) - mx[h]);
        }
        #pragma unroll
        for (int h = 0; h < HEADS; h++) {
            #pragma unroll
            for (int off = 32; off; off >>= 1)
                sm[h] += __shfl_xor(sm[h], off);
            sm[h] = scale / (sm[h] + 1e-16f);
        }
        for (int e = beg + lane; e < end; e += 64) {
            int s = srcs[e];
            #pragma unroll
            for (int h = 0; h < HEADS; h++)
                w[(long)e * HEADS + h] =
                    __expf(lrelu(a_s[s * HEADS + h] + adh[h]) - mx[h]) * sm[h];
        }
    }
}

// ---------------------------------------------------------------------------
// Layer-1 aggregate: wave per dst; lane covers channels [lane*4, lane*4+4)
// (head = lane/16) plus tail channel 256+lane (head 4). bf16 gather, fused
// bias+ELU. Edge loop unrolled x2.
__global__ __launch_bounds__(256) void aggr1(
    const int* __restrict__ rowptr, const unsigned short* __restrict__ srcs,
    const float* __restrict__ w, const unsigned short* __restrict__ hp,
    const float* __restrict__ bias, float* __restrict__ out)
{
    int wid = (blockIdx.x * blockDim.x + threadIdx.x) >> 6;
    int lane = threadIdx.x & 63;
    if (wid >= N_NODES) return;
    int beg = (wid == 0) ? 0 : rowptr[wid - 1];
    int end = rowptr[wid];

    const int ch4 = lane * 4;           // quad channels (head = lane>>4)
    const int hq  = lane >> 4;
    float acc0 = 0.f, acc1 = 0.f, acc2 = 0.f, acc3 = 0.f, accT = 0.f;

    int e = beg;
    for (; e + 1 < end; e += 2) {
        int s0 = srcs[e], s1 = srcs[e + 1];
        const unsigned short* r0 = hp + (long)s0 * 320;
        const unsigned short* r1 = hp + (long)s1 * 320;
        ushort4 q0 = *(const ushort4*)(r0 + ch4);
        ushort4 q1 = *(const ushort4*)(r1 + ch4);
        unsigned short t0 = r0[256 + lane];
        unsigned short t1 = r1[256 + lane];
        float a0 = w[(long)e * HEADS + hq];
        float a1 = w[(long)(e + 1) * HEADS + hq];
        float a0t = w[(long)e * HEADS + 4];
        float a1t = w[(long)(e + 1) * HEADS + 4];
        acc0 += bf2f(q0.x) * a0 + bf2f(q1.x) * a1;
        acc1 += bf2f(q0.y) * a0 + bf2f(q1.y) * a1;
        acc2 += bf2f(q0.z) * a0 + bf2f(q1.z) * a1;
        acc3 += bf2f(q0.w) * a0 + bf2f(q1.w) * a1;
        accT += bf2f(t0) * a0t + bf2f(t1) * a1t;
    }
    if (e < end) {
        int s0 = srcs[e];
        const unsigned short* r0 = hp + (long)s0 * 320;
        ushort4 q0 = *(const ushort4*)(r0 + ch4);
        unsigned short t0 = r0[256 + lane];
        float a0 = w[(long)e * HEADS + hq];
        float a0t = w[(long)e * HEADS + 4];
        acc0 += bf2f(q0.x) * a0;
        acc1 += bf2f(q0.y) * a0;
        acc2 += bf2f(q0.z) * a0;
        acc3 += bf2f(q0.w) * a0;
        accT += bf2f(t0) * a0t;
    }

    float4 v;
    v.x = acc0 + bias[ch4 + 0];
    v.y = acc1 + bias[ch4 + 1];
    v.z = acc2 + bias[ch4 + 2];
    v.w = acc3 + bias[ch4 + 3];
    v.x = v.x > 0.f ? v.x : expm1f(v.x);
    v.y = v.y > 0.f ? v.y : expm1f(v.y);
    v.z = v.z > 0.f ? v.z : expm1f(v.z);
    v.w = v.w > 0.f ? v.w : expm1f(v.w);
    float vt = accT + bias[256 + lane];
    vt = vt > 0.f ? vt : expm1f(vt);
    *(float4*)(out + (long)wid * 320 + ch4) = v;
    out[(long)wid * 320 + 256 + lane] = vt;
}

// ---------------------------------------------------------------------------
// Layer-2 aggregate: wave per dst; lanes 0..49 cover channels [lane*4,+4)
// (head = lane/10, quads never cross heads since 40%4==0). Head-mean is
// pre-folded into w (scale=0.2). Fused bias + log_softmax; writes final rows.
__global__ __launch_bounds__(256) void aggr2(
    const int* __restrict__ rowptr, const unsigned short* __restrict__ srcs,
    const float* __restrict__ w, const unsigned short* __restrict__ hp,
    const float* __restrict__ bias, float* __restrict__ out)
{
    int wid = (blockIdx.x * blockDim.x + threadIdx.x) >> 6;
    int lane = threadIdx.x & 63;
    if (wid >= N_NODES) return;
    int beg = (wid == 0) ? 0 : rowptr[wid - 1];
    int end = rowptr[wid];

    const bool act = lane < 50;
    const int ch4 = lane * 4;
    const int hq  = lane / 10;          // head for the quad (lanes<50)
    float acc0 = 0.f, acc1 = 0.f, acc2 = 0.f, acc3 = 0.f;

    int e = beg;
    for (; e + 1 < end; e += 2) {
        int s0 = srcs[e], s1 = srcs[e + 1];
        if (act) {
            ushort4 q0 = *(const ushort4*)(hp + (long)s0 * 200 + ch4);
            ushort4 q1 = *(const ushort4*)(hp + (long)s1 * 200 + ch4);
            float a0 = w[(long)e * HEADS + hq];
            float a1 = w[(long)(e + 1) * HEADS + hq];
            acc0 += bf2f(q0.x) * a0 + bf2f(q1.x) * a1;
            acc1 += bf2f(q0.y) * a0 + bf2f(q1.y) * a1;
            acc2 += bf2f(q0.z) * a0 + bf2f(q1.z) * a1;
            acc3 += bf2f(q0.w) * a0 + bf2f(q1.w) * a1;
        }
    }
    if (e < end) {
        int s0 = srcs[e];
        if (act) {
            ushort4 q0 = *(const ushort4*)(hp + (long)s0 * 200 + ch4);
            float a0 = w[(long)e * HEADS + hq];
            acc0 += bf2f(q0.x) * a0;
            acc1 += bf2f(q0.y) * a0;
            acc2 += bf2f(q0.z) * a0;
            acc3 += bf2f(q0.w) * a0;
        }
    }

    // cross-lane head reduction: lane l (<10) sums lanes l+10h, h=0..4
    float r0 = acc0, r1 = acc1, r2 = acc2, r3 = acc3;
    #pragma unroll
    for (int h5 = 1; h5 < 5; h5++) {
        int sl = (lane + 10 * h5) & 63;
        r0 += __shfl(acc0, sl);
        r1 += __shfl(acc1, sl);
        r2 += __shfl(acc2, sl);
        r3 += __shfl(acc3, sl);
    }

    // lanes 0..9 hold classes [lane*4, lane*4+4)
    float vb0 = -1e30f, vb1 = -1e30f, vb2 = -1e30f, vb3 = -1e30f;
    if (lane < 10) {
        vb0 = r0 + bias[ch4 + 0];
        vb1 = r1 + bias[ch4 + 1];
        vb2 = r2 + bias[ch4 + 2];
        vb3 = r3 + bias[ch4 + 3];
    }
    float mxv = fmaxf(fmaxf(vb0, vb1), fmaxf(vb2, vb3));
    #pragma unroll
    for (int off = 32; off; off >>= 1)
        mxv = fmaxf(mxv, __shfl_xor(mxv, off));
    float sme = 0.f;
    if (lane < 10)
        sme = __expf(vb0 - mxv) + __expf(vb1 - mxv) +
              __expf(vb2 - mxv) + __expf(vb3 - mxv);
    #pragma unroll
    for (int off = 32; off; off >>= 1)
        sme += __shfl_xor(sme, off);
    float ls = mxv + logf(sme);
    if (lane < 10) {
        float4 o = make_float4(vb0 - ls, vb1 - ls, vb2 - ls, vb3 - ls);
        *(float4*)(out + (long)wid * CLS + ch4) = o;
    }
}

// ---------------------------------------------------------------------------
extern "C" void kernel_launch(void* const* d_in, const int* in_sizes, int n_in,
                              void* d_out, int out_size, void* d_ws, size_t ws_size,
                              hipStream_t stream)
{
    const float* x     = (const float*)d_in[0];
    const int*   ei    = (const int*)d_in[1];
    const float* emb_W = (const float*)d_in[2];
    const float* emb_b = (const float*)d_in[3];
    const float* W1    = (const float*)d_in[4];
    const float* as1   = (const float*)d_in[5];
    const float* ad1   = (const float*)d_in[6];
    const float* b1    = (const float*)d_in[7];
    const float* W2    = (const float*)d_in[8];
    const float* as2   = (const float*)d_in[9];
    const float* ad2   = (const float*)d_in[10];
    const float* b2    = (const float*)d_in[11];

    float* out_emb = (float*)d_out;                         // [N,64]
    float* out_cls = (float*)d_out + (size_t)N_NODES * HID; // [N,40]

    char* ws = (char*)d_ws;
    unsigned short* hp1b   = (unsigned short*)(ws);               // 32 MB [N,320] bf16
    float*          h1     = (float*)(ws + 32000000);             // 64 MB [N,320] f32
    unsigned short* hp2b   = (unsigned short*)(ws);               // 20 MB (reuses hp1b)
    float*          w      = (float*)(ws + 96000000);             // 17 MB [ETOT,5]
    float*          a_s    = (float*)(ws + 113000000);            // 1 MB
    float*          a_d    = (float*)(ws + 114000000);            // 1 MB
    int*            rowptr = (int*)(ws + 115000000);              // 200 KB
    int*            bsum   = (int*)(ws + 115200064);              // ~1 KB
    unsigned short* srcs   = (unsigned short*)(ws + 115201024);   // 1.7 MB

    const dim3 blk(256);
    const int mt  = (N_NODES + 63) / 64;           // 782 row tiles
    const int nhb = (N_NODES * HEADS + 255) / 256;
    const int eb  = (ETOT + 255) / 256;
    const int nb4 = (N_NODES + 3) / 4;             // wave-per-node grids
    const int nscan = N_NODES + 1;
    const int NB = (nscan + 255) / 256;

    // ---- CSR build (graph identical for both layers) ----
    hipMemsetAsync(rowptr, 0, (size_t)nscan * 4, stream);
    hist_deg<<<eb, blk, 0, stream>>>(ei, rowptr);
    scan_block_sums<<<NB, blk, 0, stream>>>(rowptr, bsum, nscan);
    scan_bsum<<<1, 64, 0, stream>>>(bsum, NB);
    scan_final<<<NB, blk, 0, stream>>>(rowptr, bsum, nscan);
    scatter_src<<<eb, blk, 0, stream>>>(ei, rowptr, srcs);

    // ---- embedding (output 0, f32) ----
    gemm_bias<<<dim3(mt, 1), blk, 0, stream>>>(x, emb_W, emb_b, out_emb,
                                               N_NODES, IN_C, HID);

    // ---- layer 1 ----
    gemm_bf16out<<<dim3(mt, 5), blk, 0, stream>>>(out_emb, W1,
                                                  (__hip_bfloat16*)hp1b,
                                                  N_NODES, HID, HEADS * HID);
    attn_scores<<<nhb, blk, 0, stream>>>(hp1b, as1, ad1, a_s, a_d, N_NODES, HID);
    edge_w<<<nb4, blk, 0, stream>>>(rowptr, srcs, a_s, a_d, w, 1.0f);
    aggr1<<<nb4, blk, 0, stream>>>(rowptr, srcs, w, hp1b, b1, h1);

    // ---- layer 2 ----
    gemm_bf16out<<<dim3(mt, 4), blk, 0, stream>>>(h1, W2,
                                                  (__hip_bfloat16*)hp2b,
                                                  N_NODES, HEADS * HID, HEADS * CLS);
    attn_scores<<<nhb, blk, 0, stream>>>(hp2b, as2, ad2, a_s, a_d, N_NODES, CLS);
    edge_w<<<nb4, blk, 0, stream>>>(rowptr, srcs, a_s, a_d, w, 0.2f);
    aggr2<<<nb4, blk, 0, stream>>>(rowptr, srcs, w, hp2b, b2, out_cls);
}

// Round 4
// 530.254 us; speedup vs baseline: 4.1648x; 1.2178x over previous
//
#include <hip/hip_runtime.h>
#include <math.h>

// Problem constants (from reference)
constexpr int N_NODES = 50000;
constexpr int E_EDGES = 800000;
constexpr int ETOT    = E_EDGES + N_NODES;   // self-loops appended
constexpr int IN_C    = 128;
constexpr int HID     = 64;
constexpr int HEADS   = 5;
constexpr int CLS     = 40;
constexpr float NEG_SLOPE = 0.2f;

typedef __attribute__((ext_vector_type(8))) short short8;
typedef __attribute__((ext_vector_type(4))) float float4v;

__device__ __forceinline__ float lrelu(float v) {
    return v > 0.f ? v : NEG_SLOPE * v;
}
__device__ __forceinline__ float bf2f(unsigned short u) {
    return __uint_as_float(((unsigned)u) << 16);
}
__device__ __forceinline__ unsigned short f2bf(float f) {   // RNE
    unsigned u = __float_as_uint(f);
    return (unsigned short)((u + 0x7fffu + ((u >> 16) & 1u)) >> 16);
}

// ---------------------------------------------------------------------------
// f32 -> bf16 cast, float4-vectorized (n4 = n/4)
__global__ void cast_bf16(const float* __restrict__ src,
                          unsigned short* __restrict__ dst, int n4)
{
    int i = blockIdx.x * blockDim.x + threadIdx.x;
    if (i >= n4) return;
    float4 v = ((const float4*)src)[i];
    ((ushort4*)dst)[i] = make_ushort4(f2bf(v.x), f2bf(v.y), f2bf(v.z), f2bf(v.w));
}

// ---------------------------------------------------------------------------
// Pack B [K x N] f32 into MFMA b-frag order, bf16:
//   Bp[((nt*KS + ks)*4 + f)*512 + lane*8 + j] = B[ks*32+(lane>>4)*8+j][nt*64+f*16+(lane&15)]
// Cols >= N are zero-padded. One thread per (nt,ks,f,lane) writes 16 B.
__global__ void pack_B(const float* __restrict__ B, unsigned short* __restrict__ Bp,
                       int K, int N, int NT)
{
    int t = blockIdx.x * blockDim.x + threadIdx.x;
    int KS = K >> 5;
    int total = NT * KS * 4 * 64;
    if (t >= total) return;
    int lane = t & 63;
    int f = (t >> 6) & 3;
    int rest = t >> 8;
    int ks = rest % KS;
    int nt = rest / KS;
    int n = nt * 64 + f * 16 + (lane & 15);
    int kbase = ks * 32 + (lane >> 4) * 8;
    unsigned short vals[8];
    #pragma unroll
    for (int j = 0; j < 8; j++) {
        float v = (n < N) ? B[(long)(kbase + j) * N + n] : 0.f;
        vals[j] = f2bf(v);
    }
    *(ushort4*)(Bp + (long)t * 8)     = make_ushort4(vals[0], vals[1], vals[2], vals[3]);
    *(ushort4*)(Bp + (long)t * 8 + 4) = make_ushort4(vals[4], vals[5], vals[6], vals[7]);
}

// ---------------------------------------------------------------------------
// MFMA GEMM, bf16 A (row-major [M x K]) x packed bf16 B -> bf16 C [M x ldC].
// Block = 4 waves; wave w covers rows [bx*64+w*16, +16), 64 cols (blockIdx.y tile).
// A-frag: A[m=lane&15][k=(lane>>4)*8+j] -> contiguous 16B per lane, no LDS.
__global__ __launch_bounds__(256) void gemm_mfma_b16(
    const unsigned short* __restrict__ A, const unsigned short* __restrict__ Bp,
    unsigned short* __restrict__ C, int M, int K, int ldC)
{
    const int w = threadIdx.x >> 6, lane = threadIdx.x & 63;
    const int cl = lane & 15, kq = lane >> 4;
    const int KS = K >> 5;
    int rowA = blockIdx.x * 64 + w * 16 + cl;
    if (rowA >= M) rowA = M - 1;                      // clamp; stores masked
    const unsigned short* ap = A + (long)rowA * K + kq * 8;
    const unsigned short* bp = Bp + (long)blockIdx.y * KS * 2048 + lane * 8;
    float4v acc[4] = {};
    for (int ks = 0; ks < KS; ks++) {
        short8 a = *(const short8*)(ap + ks * 32);
        #pragma unroll
        for (int f = 0; f < 4; f++) {
            short8 b = *(const short8*)(bp + ks * 2048 + f * 512);
            acc[f] = __builtin_amdgcn_mfma_f32_16x16x32_bf16(a, b, acc[f], 0, 0, 0);
        }
    }
    int rbase = blockIdx.x * 64 + w * 16 + kq * 4;    // C/D: col=lane&15, row=kq*4+r
    #pragma unroll
    for (int f = 0; f < 4; f++) {
        int col = blockIdx.y * 64 + f * 16 + cl;
        #pragma unroll
        for (int r = 0; r < 4; r++) {
            int row = rbase + r;
            if (row < M) C[(long)row * ldC + col] = f2bf(acc[f][r]);
        }
    }
}

// Embedding GEMM: K=128, N=64; +bias; writes f32 (d_out) and bf16 copy.
__global__ __launch_bounds__(256) void gemm_mfma_emb(
    const unsigned short* __restrict__ A, const unsigned short* __restrict__ Bp,
    const float* __restrict__ bias, float* __restrict__ Cf,
    unsigned short* __restrict__ Cb, int M)
{
    const int K = 128, KS = 4;
    const int w = threadIdx.x >> 6, lane = threadIdx.x & 63;
    const int cl = lane & 15, kq = lane >> 4;
    int rowA = blockIdx.x * 64 + w * 16 + cl;
    if (rowA >= M) rowA = M - 1;
    const unsigned short* ap = A + (long)rowA * K + kq * 8;
    const unsigned short* bp = Bp + lane * 8;
    float4v acc[4] = {};
    for (int ks = 0; ks < KS; ks++) {
        short8 a = *(const short8*)(ap + ks * 32);
        #pragma unroll
        for (int f = 0; f < 4; f++) {
            short8 b = *(const short8*)(bp + ks * 2048 + f * 512);
            acc[f] = __builtin_amdgcn_mfma_f32_16x16x32_bf16(a, b, acc[f], 0, 0, 0);
        }
    }
    int rbase = blockIdx.x * 64 + w * 16 + kq * 4;
    #pragma unroll
    for (int f = 0; f < 4; f++) {
        int col = f * 16 + cl;
        float bc = bias[col];
        #pragma unroll
        for (int r = 0; r < 4; r++) {
            int row = rbase + r;
            if (row < M) {
                float v = acc[f][r] + bc;
                Cf[(long)row * 64 + col] = v;
                Cb[(long)row * 64 + col] = f2bf(v);
            }
        }
    }
}

// ---------------------------------------------------------------------------
// a_s[n,h] = dot(hp[n,h,:], att_src[h,:]); hp bf16, row stride ld.
__global__ void attn_scores(const unsigned short* __restrict__ hp,
                            const float* __restrict__ att_s,
                            const float* __restrict__ att_d,
                            float* __restrict__ a_s, float* __restrict__ a_d,
                            int N, int C, int ld)
{
    int i = blockIdx.x * blockDim.x + threadIdx.x;
    if (i >= N * HEADS) return;
    int n = i / HEADS, h = i % HEADS;
    const unsigned short* p = hp + (long)n * ld + h * C;
    const float* as = att_s + h * C;
    const float* ad = att_d + h * C;
    float ss = 0.f, sd = 0.f;
    for (int c = 0; c < C; c += 4) {
        ushort4 xq = *(const ushort4*)(p + c);
        float4 uv = *(const float4*)(as + c);
        float4 wv = *(const float4*)(ad + c);
        float x0 = bf2f(xq.x), x1 = bf2f(xq.y), x2 = bf2f(xq.z), x3 = bf2f(xq.w);
        ss += x0 * uv.x + x1 * uv.y + x2 * uv.z + x3 * uv.w;
        sd += x0 * wv.x + x1 * wv.y + x2 * wv.z + x3 * wv.w;
    }
    a_s[i] = ss;
    a_d[i] = sd;
}

// ---------------------------------------------------------------------------
// CSR build: histogram -> exclusive scan -> scatter.
__global__ void hist_deg(const int* __restrict__ ei, int* __restrict__ rowptr)
{
    int e = blockIdx.x * blockDim.x + threadIdx.x;
    if (e >= ETOT) return;
    int d = (e < E_EDGES) ? ei[E_EDGES + e] : e - E_EDGES;
    atomicAdd(&rowptr[d], 1);
}

__global__ void scan_block_sums(const int* __restrict__ v, int* __restrict__ bsum, int n)
{
    __shared__ int sm[256];
    int i = blockIdx.x * 256 + threadIdx.x;
    sm[threadIdx.x] = (i < n) ? v[i] : 0;
    __syncthreads();
    #pragma unroll
    for (int off = 128; off; off >>= 1) {
        if (threadIdx.x < off) sm[threadIdx.x] += sm[threadIdx.x + off];
        __syncthreads();
    }
    if (threadIdx.x == 0) bsum[blockIdx.x] = sm[0];
}

__global__ void scan_bsum(int* __restrict__ bsum, int nb)
{
    if (threadIdx.x != 0 || blockIdx.x != 0) return;
    int run = 0;
    for (int b = 0; b < nb; b++) { int t = bsum[b]; bsum[b] = run; run += t; }
}

__global__ void scan_final(int* __restrict__ v, const int* __restrict__ bsum, int n)
{
    __shared__ int sm[256];
    int i = blockIdx.x * 256 + threadIdx.x;
    int x = (i < n) ? v[i] : 0;
    sm[threadIdx.x] = x;
    __syncthreads();
    #pragma unroll
    for (int off = 1; off < 256; off <<= 1) {
        int t = (threadIdx.x >= (unsigned)off) ? sm[threadIdx.x - off] : 0;
        __syncthreads();
        sm[threadIdx.x] += t;
        __syncthreads();
    }
    if (i < n) v[i] = bsum[blockIdx.x] + sm[threadIdx.x] - x;  // exclusive
}

__global__ void scatter_src(const int* __restrict__ ei, int* __restrict__ rowptr,
                            unsigned short* __restrict__ srcs)
{
    int e = blockIdx.x * blockDim.x + threadIdx.x;
    if (e >= ETOT) return;
    int s, d;
    if (e < E_EDGES) { s = ei[e]; d = ei[E_EDGES + e]; }
    else             { s = d = e - E_EDGES; }
    int pos = atomicAdd(&rowptr[d], 1);
    srcs[pos] = (unsigned short)s;
}

// ---------------------------------------------------------------------------
// edge_w: wave per dst node; normalized attention weights per edge.
__global__ __launch_bounds__(256) void edge_w(
    const int* __restrict__ rowptr, const unsigned short* __restrict__ srcs,
    const float* __restrict__ a_s, const float* __restrict__ a_d,
    float* __restrict__ w, float scale)
{
    int wid = (blockIdx.x * blockDim.x + threadIdx.x) >> 6;
    int lane = threadIdx.x & 63;
    if (wid >= N_NODES) return;
    int beg = (wid == 0) ? 0 : rowptr[wid - 1];
    int end = rowptr[wid];
    int deg = end - beg;

    float adh[HEADS];
    #pragma unroll
    for (int h = 0; h < HEADS; h++) adh[h] = a_d[wid * HEADS + h];

    if (deg <= 64) {
        bool has = lane < deg;
        int s = has ? srcs[beg + lane] : 0;
        float v[HEADS], mx[HEADS], sm[HEADS];
        #pragma unroll
        for (int h = 0; h < HEADS; h++) {
            v[h] = has ? lrelu(a_s[s * HEADS + h] + adh[h]) : -1e30f;
            mx[h] = v[h];
        }
        #pragma unroll
        for (int h = 0; h < HEADS; h++)
            #pragma unroll
            for (int off = 32; off; off >>= 1)
                mx[h] = fmaxf(mx[h], __shfl_xor(mx[h], off));
        #pragma unroll
        for (int h = 0; h < HEADS; h++) {
            float e = has ? __expf(v[h] - mx[h]) : 0.f;
            v[h] = e;
            sm[h] = e;
        }
        #pragma unroll
        for (int h = 0; h < HEADS; h++)
            #pragma unroll
            for (int off = 32; off; off >>= 1)
                sm[h] += __shfl_xor(sm[h], off);
        if (has) {
            #pragma unroll
            for (int h = 0; h < HEADS; h++)
                w[(long)(beg + lane) * HEADS + h] = scale * v[h] / (sm[h] + 1e-16f);
        }
    } else {
        float mx[HEADS], sm[HEADS] = {};
        #pragma unroll
        for (int h = 0; h < HEADS; h++) mx[h] = -1e30f;
        for (int e = beg + lane; e < end; e += 64) {
            int s = srcs[e];
            #pragma unroll
            for (int h = 0; h < HEADS; h++)
                mx[h] = fmaxf(mx[h], lrelu(a_s[s * HEADS + h] + adh[h]));
        }
        #pragma unroll
        for (int h = 0; h < HEADS; h++)
            #pragma unroll
            for (int off = 32; off; off >>= 1)
                mx[h] = fmaxf(mx[h], __shfl_xor(mx[h], off));
        for (int e = beg + lane; e < end; e += 64) {
            int s = srcs[e];
            #pragma unroll
            for (int h = 0; h < HEADS; h++)
                sm[h] += __expf(lrelu(a_s[s * HEADS + h] + adh[h]) - mx[h]);
        }
        #pragma unroll
        for (int h = 0; h < HEADS; h++) {
            #pragma unroll
            for (int off = 32; off; off >>= 1)
                sm[h] += __shfl_xor(sm[h], off);
            sm[h] = scale / (sm[h] + 1e-16f);
        }
        for (int e = beg + lane; e < end; e += 64) {
            int s = srcs[e];
            #pragma unroll
            for (int h = 0; h < HEADS; h++)
                w[(long)e * HEADS + h] =
                    __expf(lrelu(a_s[s * HEADS + h] + adh[h]) - mx[h]) * sm[h];
        }
    }
}

// ---------------------------------------------------------------------------
// Layer-1 aggregate: wave per dst; bf16 gather; fused bias+ELU; bf16 output.
__global__ __launch_bounds__(256) void aggr1(
    const int* __restrict__ rowptr, const unsigned short* __restrict__ srcs,
    const float* __restrict__ w, const unsigned short* __restrict__ hp,
    const float* __restrict__ bias, unsigned short* __restrict__ out)
{
    int wid = (blockIdx.x * blockDim.x + threadIdx.x) >> 6;
    int lane = threadIdx.x & 63;
    if (wid >= N_NODES) return;
    int beg = (wid == 0) ? 0 : rowptr[wid - 1];
    int end = rowptr[wid];

    const int ch4 = lane * 4;
    const int hq  = lane >> 4;
    float acc0 = 0.f, acc1 = 0.f, acc2 = 0.f, acc3 = 0.f, accT = 0.f;

    int e = beg;
    for (; e + 1 < end; e += 2) {
        int s0 = srcs[e], s1 = srcs[e + 1];
        const unsigned short* r0 = hp + (long)s0 * 320;
        const unsigned short* r1 = hp + (long)s1 * 320;
        ushort4 q0 = *(const ushort4*)(r0 + ch4);
        ushort4 q1 = *(const ushort4*)(r1 + ch4);
        unsigned short t0 = r0[256 + lane];
        unsigned short t1 = r1[256 + lane];
        float a0 = w[(long)e * HEADS + hq];
        float a1 = w[(long)(e + 1) * HEADS + hq];
        float a0t = w[(long)e * HEADS + 4];
        float a1t = w[(long)(e + 1) * HEADS + 4];
        acc0 += bf2f(q0.x) * a0 + bf2f(q1.x) * a1;
        acc1 += bf2f(q0.y) * a0 + bf2f(q1.y) * a1;
        acc2 += bf2f(q0.z) * a0 + bf2f(q1.z) * a1;
        acc3 += bf2f(q0.w) * a0 + bf2f(q1.w) * a1;
        accT += bf2f(t0) * a0t + bf2f(t1) * a1t;
    }
    if (e < end) {
        int s0 = srcs[e];
        const unsigned short* r0 = hp + (long)s0 * 320;
        ushort4 q0 = *(const ushort4*)(r0 + ch4);
        unsigned short t0 = r0[256 + lane];
        float a0 = w[(long)e * HEADS + hq];
        float a0t = w[(long)e * HEADS + 4];
        acc0 += bf2f(q0.x) * a0;
        acc1 += bf2f(q0.y) * a0;
        acc2 += bf2f(q0.z) * a0;
        acc3 += bf2f(q0.w) * a0;
        accT += bf2f(t0) * a0t;
    }

    float v0 = acc0 + bias[ch4 + 0];
    float v1 = acc1 + bias[ch4 + 1];
    float v2 = acc2 + bias[ch4 + 2];
    float v3 = acc3 + bias[ch4 + 3];
    v0 = v0 > 0.f ? v0 : expm1f(v0);
    v1 = v1 > 0.f ? v1 : expm1f(v1);
    v2 = v2 > 0.f ? v2 : expm1f(v2);
    v3 = v3 > 0.f ? v3 : expm1f(v3);
    float vt = accT + bias[256 + lane];
    vt = vt > 0.f ? vt : expm1f(vt);
    *(ushort4*)(out + (long)wid * 320 + ch4) =
        make_ushort4(f2bf(v0), f2bf(v1), f2bf(v2), f2bf(v3));
    out[(long)wid * 320 + 256 + lane] = f2bf(vt);
}

// ---------------------------------------------------------------------------
// Layer-2 aggregate (hp row stride 256): fused head-mean + bias + log_softmax.
__global__ __launch_bounds__(256) void aggr2(
    const int* __restrict__ rowptr, const unsigned short* __restrict__ srcs,
    const float* __restrict__ w, const unsigned short* __restrict__ hp,
    const float* __restrict__ bias, float* __restrict__ out)
{
    int wid = (blockIdx.x * blockDim.x + threadIdx.x) >> 6;
    int lane = threadIdx.x & 63;
    if (wid >= N_NODES) return;
    int beg = (wid == 0) ? 0 : rowptr[wid - 1];
    int end = rowptr[wid];

    const bool act = lane < 50;
    const int ch4 = lane * 4;
    const int hq  = lane / 10;
    float acc0 = 0.f, acc1 = 0.f, acc2 = 0.f, acc3 = 0.f;

    int e = beg;
    for (; e + 1 < end; e += 2) {
        int s0 = srcs[e], s1 = srcs[e + 1];
        if (act) {
            ushort4 q0 = *(const ushort4*)(hp + (long)s0 * 256 + ch4);
            ushort4 q1 = *(const ushort4*)(hp + (long)s1 * 256 + ch4);
            float a0 = w[(long)e * HEADS + hq];
            float a1 = w[(long)(e + 1) * HEADS + hq];
            acc0 += bf2f(q0.x) * a0 + bf2f(q1.x) * a1;
            acc1 += bf2f(q0.y) * a0 + bf2f(q1.y) * a1;
            acc2 += bf2f(q0.z) * a0 + bf2f(q1.z) * a1;
            acc3 += bf2f(q0.w) * a0 + bf2f(q1.w) * a1;
        }
    }
    if (e < end) {
        int s0 = srcs[e];
        if (act) {
            ushort4 q0 = *(const ushort4*)(hp + (long)s0 * 256 + ch4);
            float a0 = w[(long)e * HEADS + hq];
            acc0 += bf2f(q0.x) * a0;
            acc1 += bf2f(q0.y) * a0;
            acc2 += bf2f(q0.z) * a0;
            acc3 += bf2f(q0.w) * a0;
        }
    }

    float r0 = acc0, r1 = acc1, r2 = acc2, r3 = acc3;
    #pragma unroll
    for (int h5 = 1; h5 < 5; h5++) {
        int sl = (lane + 10 * h5) & 63;
        r0 += __shfl(acc0, sl);
        r1 += __shfl(acc1, sl);
        r2 += __shfl(acc2, sl);
        r3 += __shfl(acc3, sl);
    }

    float vb0 = -1e30f, vb1 = -1e30f, vb2 = -1e30f, vb3 = -1e30f;
    if (lane < 10) {
        vb0 = r0 + bias[ch4 + 0];
        vb1 = r1 + bias[ch4 + 1];
        vb2 = r2 + bias[ch4 + 2];
        vb3 = r3 + bias[ch4 + 3];
    }
    float mxv = fmaxf(fmaxf(vb0, vb1), fmaxf(vb2, vb3));
    #pragma unroll
    for (int off = 32; off; off >>= 1)
        mxv = fmaxf(mxv, __shfl_xor(mxv, off));
    float sme = 0.f;
    if (lane < 10)
        sme = __expf(vb0 - mxv) + __expf(vb1 - mxv) +
              __expf(vb2 - mxv) + __expf(vb3 - mxv);
    #pragma unroll
    for (int off = 32; off; off >>= 1)
        sme += __shfl_xor(sme, off);
    float ls = mxv + logf(sme);
    if (lane < 10) {
        float4 o = make_float4(vb0 - ls, vb1 - ls, vb2 - ls, vb3 - ls);
        *(float4*)(out + (long)wid * CLS + ch4) = o;
    }
}

// ---------------------------------------------------------------------------
extern "C" void kernel_launch(void* const* d_in, const int* in_sizes, int n_in,
                              void* d_out, int out_size, void* d_ws, size_t ws_size,
                              hipStream_t stream)
{
    const float* x     = (const float*)d_in[0];
    const int*   ei    = (const int*)d_in[1];
    const float* emb_W = (const float*)d_in[2];
    const float* emb_b = (const float*)d_in[3];
    const float* W1    = (const float*)d_in[4];
    const float* as1   = (const float*)d_in[5];
    const float* ad1   = (const float*)d_in[6];
    const float* b1    = (const float*)d_in[7];
    const float* W2    = (const float*)d_in[8];
    const float* as2   = (const float*)d_in[9];
    const float* ad2   = (const float*)d_in[10];
    const float* b2    = (const float*)d_in[11];

    float* out_emb = (float*)d_out;                         // [N,64] f32
    float* out_cls = (float*)d_out + (size_t)N_NODES * HID; // [N,40] f32

    char* ws = (char*)d_ws;
    unsigned short* hp1b   = (unsigned short*)(ws);               // 32 MB [N,320] bf16
    unsigned short* hp2b   = (unsigned short*)(ws);               // 25.6 MB [N,256] (reuse)
    unsigned short* h1b    = (unsigned short*)(ws + 32000000);    // 32 MB [N,320] bf16
    unsigned short* xb16   = (unsigned short*)(ws + 64000000);    // 12.8 MB [N,128]
    unsigned short* embb   = (unsigned short*)(ws + 76800000);    // 6.4 MB [N,64]
    float*          w      = (float*)(ws + 83200000);             // 17 MB [ETOT,5]
    float*          a_s    = (float*)(ws + 101000000);            // 1 MB
    float*          a_d    = (float*)(ws + 102000000);            // 1 MB
    unsigned short* Bp0    = (unsigned short*)(ws + 103000000);   // 16 KB (emb)
    unsigned short* Bp1    = (unsigned short*)(ws + 103100000);   // 40 KB (W1)
    unsigned short* Bp2    = (unsigned short*)(ws + 103200000);   // 160 KB (W2)
    int*            rowptr = (int*)(ws + 103400000);              // 200 KB
    int*            bsum   = (int*)(ws + 103700000);              // ~1 KB
    unsigned short* srcs   = (unsigned short*)(ws + 103710000);   // 1.7 MB

    const dim3 blk(256);
    const int nhb = (N_NODES * HEADS + 255) / 256;
    const int eb  = (ETOT + 255) / 256;
    const int nb4 = (N_NODES + 3) / 4;
    const int nscan = N_NODES + 1;
    const int NB = (nscan + 255) / 256;
    const int mgrid = (N_NODES + 63) / 64;         // 782

    // ---- input casts & weight packing ----
    cast_bf16<<<(1600000 + 255) / 256, blk, 0, stream>>>(x, xb16, 1600000);
    pack_B<<<4,  blk, 0, stream>>>(emb_W, Bp0, 128, 64, 1);     // 1024 thr
    pack_B<<<10, blk, 0, stream>>>(W1,    Bp1, 64, 320, 5);     // 2560 thr
    pack_B<<<40, blk, 0, stream>>>(W2,    Bp2, 320, 200, 4);    // 10240 thr

    // ---- CSR build ----
    hipMemsetAsync(rowptr, 0, (size_t)nscan * 4, stream);
    hist_deg<<<eb, blk, 0, stream>>>(ei, rowptr);
    scan_block_sums<<<NB, blk, 0, stream>>>(rowptr, bsum, nscan);
    scan_bsum<<<1, 64, 0, stream>>>(bsum, NB);
    scan_final<<<NB, blk, 0, stream>>>(rowptr, bsum, nscan);
    scatter_src<<<eb, blk, 0, stream>>>(ei, rowptr, srcs);

    // ---- embedding (output 0 f32 + bf16 copy) ----
    gemm_mfma_emb<<<dim3(mgrid, 1), blk, 0, stream>>>(xb16, Bp0, emb_b,
                                                      out_emb, embb, N_NODES);

    // ---- layer 1 ----
    gemm_mfma_b16<<<dim3(mgrid, 5), blk, 0, stream>>>(embb, Bp1, hp1b,
                                                      N_NODES, 64, 320);
    attn_scores<<<nhb, blk, 0, stream>>>(hp1b, as1, ad1, a_s, a_d, N_NODES, 64, 320);
    edge_w<<<nb4, blk, 0, stream>>>(rowptr, srcs, a_s, a_d, w, 1.0f);
    aggr1<<<nb4, blk, 0, stream>>>(rowptr, srcs, w, hp1b, b1, h1b);

    // ---- layer 2 ----
    gemm_mfma_b16<<<dim3(mgrid, 4), blk, 0, stream>>>(h1b, Bp2, hp2b,
                                                      N_NODES, 320, 256);
    attn_scores<<<nhb, blk, 0, stream>>>(hp2b, as2, ad2, a_s, a_d, N_NODES, 40, 256);
    edge_w<<<nb4, blk, 0, stream>>>(rowptr, srcs, a_s, a_d, w, 0.2f);
    aggr2<<<nb4, blk, 0, stream>>>(rowptr, srcs, w, hp2b, b2, out_cls);
}

// Round 5
// 507.784 us; speedup vs baseline: 4.3491x; 1.0443x over previous
//
#include <hip/hip_runtime.h>
#include <math.h>

// Problem constants (from reference)
constexpr int N_NODES = 50000;
constexpr int E_EDGES = 800000;
constexpr int ETOT    = E_EDGES + N_NODES;   // self-loops appended
constexpr int IN_C    = 128;
constexpr int HID     = 64;
constexpr int HEADS   = 5;
constexpr int CLS     = 40;
constexpr float NEG_SLOPE = 0.2f;

typedef __attribute__((ext_vector_type(8))) short short8;
typedef __attribute__((ext_vector_type(4))) float float4v;

__device__ __forceinline__ float lrelu(float v) {
    return v > 0.f ? v : NEG_SLOPE * v;
}
__device__ __forceinline__ float bf2f(unsigned short u) {
    return __uint_as_float(((unsigned)u) << 16);
}
__device__ __forceinline__ unsigned short f2bf(float f) {   // RNE
    unsigned u = __float_as_uint(f);
    return (unsigned short)((u + 0x7fffu + ((u >> 16) & 1u)) >> 16);
}

// ---------------------------------------------------------------------------
// f32 -> bf16 cast, float4-vectorized (n4 = n/4)
__global__ void cast_bf16(const float* __restrict__ src,
                          unsigned short* __restrict__ dst, int n4)
{
    int i = blockIdx.x * blockDim.x + threadIdx.x;
    if (i >= n4) return;
    float4 v = ((const float4*)src)[i];
    ((ushort4*)dst)[i] = make_ushort4(f2bf(v.x), f2bf(v.y), f2bf(v.z), f2bf(v.w));
}

// ---------------------------------------------------------------------------
// Pack B [K x N] f32 into MFMA b-frag order, bf16:
//   Bp[((nt*KS + ks)*4 + f)*512 + lane*8 + j] = B[ks*32+(lane>>4)*8+j][nt*64+f*16+(lane&15)]
__global__ void pack_B(const float* __restrict__ B, unsigned short* __restrict__ Bp,
                       int K, int N, int NT)
{
    int t = blockIdx.x * blockDim.x + threadIdx.x;
    int KS = K >> 5;
    int total = NT * KS * 4 * 64;
    if (t >= total) return;
    int lane = t & 63;
    int f = (t >> 6) & 3;
    int rest = t >> 8;
    int ks = rest % KS;
    int nt = rest / KS;
    int n = nt * 64 + f * 16 + (lane & 15);
    int kbase = ks * 32 + (lane >> 4) * 8;
    unsigned short vals[8];
    #pragma unroll
    for (int j = 0; j < 8; j++) {
        float v = (n < N) ? B[(long)(kbase + j) * N + n] : 0.f;
        vals[j] = f2bf(v);
    }
    *(ushort4*)(Bp + (long)t * 8)     = make_ushort4(vals[0], vals[1], vals[2], vals[3]);
    *(ushort4*)(Bp + (long)t * 8 + 4) = make_ushort4(vals[4], vals[5], vals[6], vals[7]);
}

// ---------------------------------------------------------------------------
// Embedding GEMM: K=128, N=64; +bias; writes f32 (d_out) and bf16 copy.
__global__ __launch_bounds__(256) void gemm_mfma_emb(
    const unsigned short* __restrict__ A, const unsigned short* __restrict__ Bp,
    const float* __restrict__ bias, float* __restrict__ Cf,
    unsigned short* __restrict__ Cb, int M)
{
    const int K = 128, KS = 4;
    const int w = threadIdx.x >> 6, lane = threadIdx.x & 63;
    const int cl = lane & 15, kq = lane >> 4;
    int rowA = blockIdx.x * 64 + w * 16 + cl;
    if (rowA >= M) rowA = M - 1;
    const unsigned short* ap = A + (long)rowA * K + kq * 8;
    const unsigned short* bp = Bp + lane * 8;
    float4v acc[4] = {};
    for (int ks = 0; ks < KS; ks++) {
        short8 a = *(const short8*)(ap + ks * 32);
        #pragma unroll
        for (int f = 0; f < 4; f++) {
            short8 b = *(const short8*)(bp + ks * 2048 + f * 512);
            acc[f] = __builtin_amdgcn_mfma_f32_16x16x32_bf16(a, b, acc[f], 0, 0, 0);
        }
    }
    int rbase = blockIdx.x * 64 + w * 16 + kq * 4;
    #pragma unroll
    for (int f = 0; f < 4; f++) {
        int col = f * 16 + cl;
        float bc = bias[col];
        #pragma unroll
        for (int r = 0; r < 4; r++) {
            int row = rbase + r;
            if (row < M) {
                float v = acc[f][r] + bc;
                Cf[(long)row * 64 + col] = v;
                Cb[(long)row * 64 + col] = f2bf(v);
            }
        }
    }
}

// ---------------------------------------------------------------------------
// Layer-1 GEMM (K=64, all 5 col-tiles per block) + fused attention scores.
// Writes hp1b [M x 320] bf16 and a_s/a_d [M x 5] f32.
__global__ __launch_bounds__(256) void gemm_attn_l1(
    const unsigned short* __restrict__ A, const unsigned short* __restrict__ Bp,
    const float* __restrict__ att_s, const float* __restrict__ att_d,
    unsigned short* __restrict__ C, float* __restrict__ a_s,
    float* __restrict__ a_d, int M)
{
    const int K = 64, KS = 2;
    const int w = threadIdx.x >> 6, lane = threadIdx.x & 63;
    const int cl = lane & 15, kq = lane >> 4;
    int rowA = blockIdx.x * 64 + w * 16 + cl;
    if (rowA >= M) rowA = M - 1;
    const unsigned short* ap = A + (long)rowA * K + kq * 8;
    const unsigned short* bp = Bp + lane * 8;
    float4v acc[20] = {};
    #pragma unroll
    for (int ks = 0; ks < KS; ks++) {
        short8 a = *(const short8*)(ap + ks * 32);
        #pragma unroll
        for (int nt = 0; nt < 5; nt++)
            #pragma unroll
            for (int f = 0; f < 4; f++) {
                short8 b = *(const short8*)(bp + (nt * KS + ks) * 2048 + f * 512);
                acc[nt * 4 + f] =
                    __builtin_amdgcn_mfma_f32_16x16x32_bf16(a, b, acc[nt * 4 + f], 0, 0, 0);
            }
    }
    int rbase = blockIdx.x * 64 + w * 16 + kq * 4;
    // store hp1b
    #pragma unroll
    for (int nt = 0; nt < 5; nt++)
        #pragma unroll
        for (int f = 0; f < 4; f++) {
            int col = nt * 64 + f * 16 + cl;
            #pragma unroll
            for (int r = 0; r < 4; r++) {
                int row = rbase + r;
                if (row < M) C[(long)row * 320 + col] = f2bf(acc[nt * 4 + f][r]);
            }
        }
    // fused attention scores: a_s[row,h] = dot(hp[row, h*64 : h*64+64], att_s[h])
    #pragma unroll
    for (int nt = 0; nt < 5; nt++) {
        float av[4], dv[4];
        #pragma unroll
        for (int f = 0; f < 4; f++) {
            av[f] = att_s[nt * 64 + f * 16 + cl];
            dv[f] = att_d[nt * 64 + f * 16 + cl];
        }
        #pragma unroll
        for (int r = 0; r < 4; r++) {
            float ps = 0.f, pd = 0.f;
            #pragma unroll
            for (int f = 0; f < 4; f++) {
                ps += acc[nt * 4 + f][r] * av[f];
                pd += acc[nt * 4 + f][r] * dv[f];
            }
            #pragma unroll
            for (int off = 1; off < 16; off <<= 1) {
                ps += __shfl_xor(ps, off);
                pd += __shfl_xor(pd, off);
            }
            int row = rbase + r;
            if (cl == 0 && row < M) {
                a_s[row * 5 + nt] = ps;
                a_d[row * 5 + nt] = pd;
            }
        }
    }
}

// ---------------------------------------------------------------------------
// Layer-2 GEMM: K=320, all 4 col-tiles per block; ldC=256 (cols>=200 are 0).
__global__ __launch_bounds__(256) void gemm_mfma_l2(
    const unsigned short* __restrict__ A, const unsigned short* __restrict__ Bp,
    unsigned short* __restrict__ C, int M)
{
    const int K = 320, KS = 10;
    const int w = threadIdx.x >> 6, lane = threadIdx.x & 63;
    const int cl = lane & 15, kq = lane >> 4;
    int rowA = blockIdx.x * 64 + w * 16 + cl;
    if (rowA >= M) rowA = M - 1;
    const unsigned short* ap = A + (long)rowA * K + kq * 8;
    const unsigned short* bp = Bp + lane * 8;
    float4v acc[16] = {};
    for (int ks = 0; ks < KS; ks++) {
        short8 a = *(const short8*)(ap + ks * 32);
        #pragma unroll
        for (int nt = 0; nt < 4; nt++)
            #pragma unroll
            for (int f = 0; f < 4; f++) {
                short8 b = *(const short8*)(bp + (nt * KS + ks) * 2048 + f * 512);
                acc[nt * 4 + f] =
                    __builtin_amdgcn_mfma_f32_16x16x32_bf16(a, b, acc[nt * 4 + f], 0, 0, 0);
            }
    }
    int rbase = blockIdx.x * 64 + w * 16 + kq * 4;
    #pragma unroll
    for (int nt = 0; nt < 4; nt++)
        #pragma unroll
        for (int f = 0; f < 4; f++) {
            int col = nt * 64 + f * 16 + cl;
            #pragma unroll
            for (int r = 0; r < 4; r++) {
                int row = rbase + r;
                if (row < M) C[(long)row * 256 + col] = f2bf(acc[nt * 4 + f][r]);
            }
        }
}

// ---------------------------------------------------------------------------
// a_s[n,h] = dot(hp[n,h,:], att_src[h,:]); hp bf16, row stride ld. (layer 2)
__global__ void attn_scores(const unsigned short* __restrict__ hp,
                            const float* __restrict__ att_s,
                            const float* __restrict__ att_d,
                            float* __restrict__ a_s, float* __restrict__ a_d,
                            int N, int C, int ld)
{
    int i = blockIdx.x * blockDim.x + threadIdx.x;
    if (i >= N * HEADS) return;
    int n = i / HEADS, h = i % HEADS;
    const unsigned short* p = hp + (long)n * ld + h * C;
    const float* as = att_s + h * C;
    const float* ad = att_d + h * C;
    float ss = 0.f, sd = 0.f;
    for (int c = 0; c < C; c += 4) {
        ushort4 xq = *(const ushort4*)(p + c);
        float4 uv = *(const float4*)(as + c);
        float4 wv = *(const float4*)(ad + c);
        float x0 = bf2f(xq.x), x1 = bf2f(xq.y), x2 = bf2f(xq.z), x3 = bf2f(xq.w);
        ss += x0 * uv.x + x1 * uv.y + x2 * uv.z + x3 * uv.w;
        sd += x0 * wv.x + x1 * wv.y + x2 * wv.z + x3 * wv.w;
    }
    a_s[i] = ss;
    a_d[i] = sd;
}

// ---------------------------------------------------------------------------
// CSR build: histogram -> exclusive scan -> scatter.
__global__ void hist_deg(const int* __restrict__ ei, int* __restrict__ rowptr)
{
    int e = blockIdx.x * blockDim.x + threadIdx.x;
    if (e >= ETOT) return;
    int d = (e < E_EDGES) ? ei[E_EDGES + e] : e - E_EDGES;
    atomicAdd(&rowptr[d], 1);
}

__global__ void scan_block_sums(const int* __restrict__ v, int* __restrict__ bsum, int n)
{
    __shared__ int sm[256];
    int i = blockIdx.x * 256 + threadIdx.x;
    sm[threadIdx.x] = (i < n) ? v[i] : 0;
    __syncthreads();
    #pragma unroll
    for (int off = 128; off; off >>= 1) {
        if (threadIdx.x < off) sm[threadIdx.x] += sm[threadIdx.x + off];
        __syncthreads();
    }
    if (threadIdx.x == 0) bsum[blockIdx.x] = sm[0];
}

__global__ void scan_bsum(int* __restrict__ bsum, int nb)
{
    if (threadIdx.x != 0 || blockIdx.x != 0) return;
    int run = 0;
    for (int b = 0; b < nb; b++) { int t = bsum[b]; bsum[b] = run; run += t; }
}

__global__ void scan_final(int* __restrict__ v, const int* __restrict__ bsum, int n)
{
    __shared__ int sm[256];
    int i = blockIdx.x * 256 + threadIdx.x;
    int x = (i < n) ? v[i] : 0;
    sm[threadIdx.x] = x;
    __syncthreads();
    #pragma unroll
    for (int off = 1; off < 256; off <<= 1) {
        int t = (threadIdx.x >= (unsigned)off) ? sm[threadIdx.x - off] : 0;
        __syncthreads();
        sm[threadIdx.x] += t;
        __syncthreads();
    }
    if (i < n) v[i] = bsum[blockIdx.x] + sm[threadIdx.x] - x;  // exclusive
}

__global__ void scatter_src(const int* __restrict__ ei, int* __restrict__ rowptr,
                            unsigned short* __restrict__ srcs)
{
    int e = blockIdx.x * blockDim.x + threadIdx.x;
    if (e >= ETOT) return;
    int s, d;
    if (e < E_EDGES) { s = ei[e]; d = ei[E_EDGES + e]; }
    else             { s = d = e - E_EDGES; }
    int pos = atomicAdd(&rowptr[d], 1);
    srcs[pos] = (unsigned short)s;
}

// ---------------------------------------------------------------------------
// Fused layer-1: softmax weights (LDS stash, deg<=64 fast path) + aggregate
// + bias + ELU -> bf16 h1. Wave per dst node; no atomics.
__global__ __launch_bounds__(256) void aggr1_fused(
    const int* __restrict__ rowptr, const unsigned short* __restrict__ srcs,
    const float* __restrict__ a_s, const float* __restrict__ a_d,
    const unsigned short* __restrict__ hp, const float* __restrict__ bias,
    unsigned short* __restrict__ out)
{
    __shared__ float alph[4][320];   // per wave: 64 edges x 5 heads
    int wid = (blockIdx.x * blockDim.x + threadIdx.x) >> 6;
    int w = threadIdx.x >> 6;
    int lane = threadIdx.x & 63;
    bool valid = wid < N_NODES;
    int beg = 0, end = 0;
    if (valid) {
        beg = (wid == 0) ? 0 : rowptr[wid - 1];
        end = rowptr[wid];
    }
    int deg = end - beg;
    bool fast = deg <= 64;

    float adh[HEADS];
    #pragma unroll
    for (int h = 0; h < HEADS; h++) adh[h] = valid ? a_d[wid * HEADS + h] : 0.f;

    float mx[HEADS], inv[HEADS];
    if (valid && fast) {
        bool has = lane < deg;
        int s = has ? srcs[beg + lane] : 0;
        float v[HEADS], sm[HEADS];
        #pragma unroll
        for (int h = 0; h < HEADS; h++) {
            v[h] = has ? lrelu(a_s[s * HEADS + h] + adh[h]) : -1e30f;
            mx[h] = v[h];
        }
        #pragma unroll
        for (int h = 0; h < HEADS; h++)
            #pragma unroll
            for (int off = 32; off; off >>= 1)
                mx[h] = fmaxf(mx[h], __shfl_xor(mx[h], off));
        #pragma unroll
        for (int h = 0; h < HEADS; h++) {
            float e = has ? __expf(v[h] - mx[h]) : 0.f;
            v[h] = e;
            sm[h] = e;
        }
        #pragma unroll
        for (int h = 0; h < HEADS; h++)
            #pragma unroll
            for (int off = 32; off; off >>= 1)
                sm[h] += __shfl_xor(sm[h], off);
        if (has) {
            #pragma unroll
            for (int h = 0; h < HEADS; h++)
                alph[w][lane * 5 + h] = v[h] / (sm[h] + 1e-16f);
        }
    } else if (valid) {
        float sm[HEADS] = {};
        #pragma unroll
        for (int h = 0; h < HEADS; h++) mx[h] = -1e30f;
        for (int e = beg + lane; e < end; e += 64) {
            int s = srcs[e];
            #pragma unroll
            for (int h = 0; h < HEADS; h++)
                mx[h] = fmaxf(mx[h], lrelu(a_s[s * HEADS + h] + adh[h]));
        }
        #pragma unroll
        for (int h = 0; h < HEADS; h++)
            #pragma unroll
            for (int off = 32; off; off >>= 1)
                mx[h] = fmaxf(mx[h], __shfl_xor(mx[h], off));
        for (int e = beg + lane; e < end; e += 64) {
            int s = srcs[e];
            #pragma unroll
            for (int h = 0; h < HEADS; h++)
                sm[h] += __expf(lrelu(a_s[s * HEADS + h] + adh[h]) - mx[h]);
        }
        #pragma unroll
        for (int h = 0; h < HEADS; h++) {
            #pragma unroll
            for (int off = 32; off; off >>= 1)
                sm[h] += __shfl_xor(sm[h], off);
            inv[h] = 1.f / (sm[h] + 1e-16f);
        }
    }
    __syncthreads();
    if (!valid) return;

    const int ch4 = lane * 4;
    const int hq  = lane >> 4;
    float acc0 = 0.f, acc1 = 0.f, acc2 = 0.f, acc3 = 0.f, accT = 0.f;

    if (fast) {
        int e = beg;
        for (; e + 1 < end; e += 2) {
            int i = e - beg;
            int s0 = srcs[e], s1 = srcs[e + 1];
            const unsigned short* r0 = hp + (long)s0 * 320;
            const unsigned short* r1 = hp + (long)s1 * 320;
            ushort4 q0 = *(const ushort4*)(r0 + ch4);
            ushort4 q1 = *(const ushort4*)(r1 + ch4);
            unsigned short t0 = r0[256 + lane];
            unsigned short t1 = r1[256 + lane];
            float a0  = alph[w][i * 5 + hq];
            float a1  = alph[w][(i + 1) * 5 + hq];
            float a0t = alph[w][i * 5 + 4];
            float a1t = alph[w][(i + 1) * 5 + 4];
            acc0 += bf2f(q0.x) * a0 + bf2f(q1.x) * a1;
            acc1 += bf2f(q0.y) * a0 + bf2f(q1.y) * a1;
            acc2 += bf2f(q0.z) * a0 + bf2f(q1.z) * a1;
            acc3 += bf2f(q0.w) * a0 + bf2f(q1.w) * a1;
            accT += bf2f(t0) * a0t + bf2f(t1) * a1t;
        }
        if (e < end) {
            int i = e - beg;
            int s0 = srcs[e];
            const unsigned short* r0 = hp + (long)s0 * 320;
            ushort4 q0 = *(const ushort4*)(r0 + ch4);
            unsigned short t0 = r0[256 + lane];
            float a0  = alph[w][i * 5 + hq];
            float a0t = alph[w][i * 5 + 4];
            acc0 += bf2f(q0.x) * a0;
            acc1 += bf2f(q0.y) * a0;
            acc2 += bf2f(q0.z) * a0;
            acc3 += bf2f(q0.w) * a0;
            accT += bf2f(t0) * a0t;
        }
    } else {
        for (int e = beg; e < end; e++) {
            int s0 = srcs[e];
            const unsigned short* r0 = hp + (long)s0 * 320;
            ushort4 q0 = *(const ushort4*)(r0 + ch4);
            unsigned short t0 = r0[256 + lane];
            float a0  = __expf(lrelu(a_s[s0 * HEADS + hq] + adh[hq]) - mx[hq]) * inv[hq];
            float a0t = __expf(lrelu(a_s[s0 * HEADS + 4] + adh[4]) - mx[4]) * inv[4];
            acc0 += bf2f(q0.x) * a0;
            acc1 += bf2f(q0.y) * a0;
            acc2 += bf2f(q0.z) * a0;
            acc3 += bf2f(q0.w) * a0;
            accT += bf2f(t0) * a0t;
        }
    }

    float v0 = acc0 + bias[ch4 + 0];
    float v1 = acc1 + bias[ch4 + 1];
    float v2 = acc2 + bias[ch4 + 2];
    float v3 = acc3 + bias[ch4 + 3];
    v0 = v0 > 0.f ? v0 : expm1f(v0);
    v1 = v1 > 0.f ? v1 : expm1f(v1);
    v2 = v2 > 0.f ? v2 : expm1f(v2);
    v3 = v3 > 0.f ? v3 : expm1f(v3);
    float vt = accT + bias[256 + lane];
    vt = vt > 0.f ? vt : expm1f(vt);
    *(ushort4*)(out + (long)wid * 320 + ch4) =
        make_ushort4(f2bf(v0), f2bf(v1), f2bf(v2), f2bf(v3));
    out[(long)wid * 320 + 256 + lane] = f2bf(vt);
}

// ---------------------------------------------------------------------------
// Fused layer-2: softmax weights (0.2 head-mean folded) + aggregate (hp stride
// 256) + bias + log_softmax -> final rows.
__global__ __launch_bounds__(256) void aggr2_fused(
    const int* __restrict__ rowptr, const unsigned short* __restrict__ srcs,
    const float* __restrict__ a_s, const float* __restrict__ a_d,
    const unsigned short* __restrict__ hp, const float* __restrict__ bias,
    float* __restrict__ out)
{
    __shared__ float alph[4][320];
    int wid = (blockIdx.x * blockDim.x + threadIdx.x) >> 6;
    int w = threadIdx.x >> 6;
    int lane = threadIdx.x & 63;
    bool valid = wid < N_NODES;
    int beg = 0, end = 0;
    if (valid) {
        beg = (wid == 0) ? 0 : rowptr[wid - 1];
        end = rowptr[wid];
    }
    int deg = end - beg;
    bool fast = deg <= 64;

    float adh[HEADS];
    #pragma unroll
    for (int h = 0; h < HEADS; h++) adh[h] = valid ? a_d[wid * HEADS + h] : 0.f;

    float mx[HEADS], inv[HEADS];
    if (valid && fast) {
        bool has = lane < deg;
        int s = has ? srcs[beg + lane] : 0;
        float v[HEADS], sm[HEADS];
        #pragma unroll
        for (int h = 0; h < HEADS; h++) {
            v[h] = has ? lrelu(a_s[s * HEADS + h] + adh[h]) : -1e30f;
            mx[h] = v[h];
        }
        #pragma unroll
        for (int h = 0; h < HEADS; h++)
            #pragma unroll
            for (int off = 32; off; off >>= 1)
                mx[h] = fmaxf(mx[h], __shfl_xor(mx[h], off));
        #pragma unroll
        for (int h = 0; h < HEADS; h++) {
            float e = has ? __expf(v[h] - mx[h]) : 0.f;
            v[h] = e;
            sm[h] = e;
        }
        #pragma unroll
        for (int h = 0; h < HEADS; h++)
            #pragma unroll
            for (int off = 32; off; off >>= 1)
                sm[h] += __shfl_xor(sm[h], off);
        if (has) {
            #pragma unroll
            for (int h = 0; h < HEADS; h++)
                alph[w][lane * 5 + h] = 0.2f * v[h] / (sm[h] + 1e-16f);
        }
    } else if (valid) {
        float sm[HEADS] = {};
        #pragma unroll
        for (int h = 0; h < HEADS; h++) mx[h] = -1e30f;
        for (int e = beg + lane; e < end; e += 64) {
            int s = srcs[e];
            #pragma unroll
            for (int h = 0; h < HEADS; h++)
                mx[h] = fmaxf(mx[h], lrelu(a_s[s * HEADS + h] + adh[h]));
        }
        #pragma unroll
        for (int h = 0; h < HEADS; h++)
            #pragma unroll
            for (int off = 32; off; off >>= 1)
                mx[h] = fmaxf(mx[h], __shfl_xor(mx[h], off));
        for (int e = beg + lane; e < end; e += 64) {
            int s = srcs[e];
            #pragma unroll
            for (int h = 0; h < HEADS; h++)
                sm[h] += __expf(lrelu(a_s[s * HEADS + h] + adh[h]) - mx[h]);
        }
        #pragma unroll
        for (int h = 0; h < HEADS; h++) {
            #pragma unroll
            for (int off = 32; off; off >>= 1)
                sm[h] += __shfl_xor(sm[h], off);
            inv[h] = 0.2f / (sm[h] + 1e-16f);
        }
    }
    __syncthreads();
    if (!valid) return;

    const bool act = lane < 50;
    const int ch4 = lane * 4;
    const int hq  = lane / 10;
    float acc0 = 0.f, acc1 = 0.f, acc2 = 0.f, acc3 = 0.f;

    if (fast) {
        int e = beg;
        for (; e + 1 < end; e += 2) {
            int i = e - beg;
            int s0 = srcs[e], s1 = srcs[e + 1];
            if (act) {
                ushort4 q0 = *(const ushort4*)(hp + (long)s0 * 256 + ch4);
                ushort4 q1 = *(const ushort4*)(hp + (long)s1 * 256 + ch4);
                float a0 = alph[w][i * 5 + hq];
                float a1 = alph[w][(i + 1) * 5 + hq];
                acc0 += bf2f(q0.x) * a0 + bf2f(q1.x) * a1;
                acc1 += bf2f(q0.y) * a0 + bf2f(q1.y) * a1;
                acc2 += bf2f(q0.z) * a0 + bf2f(q1.z) * a1;
                acc3 += bf2f(q0.w) * a0 + bf2f(q1.w) * a1;
            }
        }
        if (e < end) {
            int i = e - beg;
            int s0 = srcs[e];
            if (act) {
                ushort4 q0 = *(const ushort4*)(hp + (long)s0 * 256 + ch4);
                float a0 = alph[w][i * 5 + hq];
                acc0 += bf2f(q0.x) * a0;
                acc1 += bf2f(q0.y) * a0;
                acc2 += bf2f(q0.z) * a0;
                acc3 += bf2f(q0.w) * a0;
            }
        }
    } else {
        for (int e = beg; e < end; e++) {
            int s0 = srcs[e];
            if (act) {
                ushort4 q0 = *(const ushort4*)(hp + (long)s0 * 256 + ch4);
                float a0 = __expf(lrelu(a_s[s0 * HEADS + hq] + adh[hq]) - mx[hq]) * inv[hq];
                acc0 += bf2f(q0.x) * a0;
                acc1 += bf2f(q0.y) * a0;
                acc2 += bf2f(q0.z) * a0;
                acc3 += bf2f(q0.w) * a0;
            }
        }
    }

    float r0 = acc0, r1 = acc1, r2 = acc2, r3 = acc3;
    #pragma unroll
    for (int h5 = 1; h5 < 5; h5++) {
        int sl = (lane + 10 * h5) & 63;
        r0 += __shfl(acc0, sl);
        r1 += __shfl(acc1, sl);
        r2 += __shfl(acc2, sl);
        r3 += __shfl(acc3, sl);
    }

    float vb0 = -1e30f, vb1 = -1e30f, vb2 = -1e30f, vb3 = -1e30f;
    if (lane < 10) {
        vb0 = r0 + bias[ch4 + 0];
        vb1 = r1 + bias[ch4 + 1];
        vb2 = r2 + bias[ch4 + 2];
        vb3 = r3 + bias[ch4 + 3];
    }
    float mxv = fmaxf(fmaxf(vb0, vb1), fmaxf(vb2, vb3));
    #pragma unroll
    for (int off = 32; off; off >>= 1)
        mxv = fmaxf(mxv, __shfl_xor(mxv, off));
    float sme = 0.f;
    if (lane < 10)
        sme = __expf(vb0 - mxv) + __expf(vb1 - mxv) +
              __expf(vb2 - mxv) + __expf(vb3 - mxv);
    #pragma unroll
    for (int off = 32; off; off >>= 1)
        sme += __shfl_xor(sme, off);
    float ls = mxv + logf(sme);
    if (lane < 10) {
        float4 o = make_float4(vb0 - ls, vb1 - ls, vb2 - ls, vb3 - ls);
        *(float4*)(out + (long)wid * CLS + ch4) = o;
    }
}

// ---------------------------------------------------------------------------
extern "C" void kernel_launch(void* const* d_in, const int* in_sizes, int n_in,
                              void* d_out, int out_size, void* d_ws, size_t ws_size,
                              hipStream_t stream)
{
    const float* x     = (const float*)d_in[0];
    const int*   ei    = (const int*)d_in[1];
    const float* emb_W = (const float*)d_in[2];
    const float* emb_b = (const float*)d_in[3];
    const float* W1    = (const float*)d_in[4];
    const float* as1   = (const float*)d_in[5];
    const float* ad1   = (const float*)d_in[6];
    const float* b1    = (const float*)d_in[7];
    const float* W2    = (const float*)d_in[8];
    const float* as2   = (const float*)d_in[9];
    const float* ad2   = (const float*)d_in[10];
    const float* b2    = (const float*)d_in[11];

    float* out_emb = (float*)d_out;                         // [N,64] f32
    float* out_cls = (float*)d_out + (size_t)N_NODES * HID; // [N,40] f32

    char* ws = (char*)d_ws;
    unsigned short* hp1b   = (unsigned short*)(ws);               // 32 MB [N,320]
    unsigned short* hp2b   = (unsigned short*)(ws);               // 25.6 MB [N,256] (reuse)
    unsigned short* h1b    = (unsigned short*)(ws + 32000000);    // 32 MB [N,320]
    unsigned short* xb16   = (unsigned short*)(ws + 64000000);    // 12.8 MB [N,128]
    unsigned short* embb   = (unsigned short*)(ws + 76800000);    // 6.4 MB [N,64]
    float*          a_s    = (float*)(ws + 83200000);             // 1 MB
    float*          a_d    = (float*)(ws + 84200000);             // 1 MB
    unsigned short* Bp0    = (unsigned short*)(ws + 85200000);    // 16 KB
    unsigned short* Bp1    = (unsigned short*)(ws + 85300000);    // 40 KB
    unsigned short* Bp2    = (unsigned short*)(ws + 85400000);    // 160 KB
    int*            rowptr = (int*)(ws + 85600000);               // 200 KB
    int*            bsum   = (int*)(ws + 85900000);               // ~1 KB
    unsigned short* srcs   = (unsigned short*)(ws + 85910000);    // 1.7 MB

    const dim3 blk(256);
    const int nhb = (N_NODES * HEADS + 255) / 256;
    const int eb  = (ETOT + 255) / 256;
    const int nb4 = (N_NODES + 3) / 4;
    const int nscan = N_NODES + 1;
    const int NB = (nscan + 255) / 256;
    const int mgrid = (N_NODES + 63) / 64;         // 782

    // ---- input casts & weight packing ----
    cast_bf16<<<(1600000 + 255) / 256, blk, 0, stream>>>(x, xb16, 1600000);
    pack_B<<<4,  blk, 0, stream>>>(emb_W, Bp0, 128, 64, 1);
    pack_B<<<10, blk, 0, stream>>>(W1,    Bp1, 64, 320, 5);
    pack_B<<<40, blk, 0, stream>>>(W2,    Bp2, 320, 200, 4);

    // ---- CSR build ----
    hipMemsetAsync(rowptr, 0, (size_t)nscan * 4, stream);
    hist_deg<<<eb, blk, 0, stream>>>(ei, rowptr);
    scan_block_sums<<<NB, blk, 0, stream>>>(rowptr, bsum, nscan);
    scan_bsum<<<1, 64, 0, stream>>>(bsum, NB);
    scan_final<<<NB, blk, 0, stream>>>(rowptr, bsum, nscan);
    scatter_src<<<eb, blk, 0, stream>>>(ei, rowptr, srcs);

    // ---- embedding (output 0 f32 + bf16 copy) ----
    gemm_mfma_emb<<<mgrid, blk, 0, stream>>>(xb16, Bp0, emb_b,
                                             out_emb, embb, N_NODES);

    // ---- layer 1 ----
    gemm_attn_l1<<<mgrid, blk, 0, stream>>>(embb, Bp1, as1, ad1,
                                            hp1b, a_s, a_d, N_NODES);
    aggr1_fused<<<nb4, blk, 0, stream>>>(rowptr, srcs, a_s, a_d, hp1b, b1, h1b);

    // ---- layer 2 ----
    gemm_mfma_l2<<<mgrid, blk, 0, stream>>>(h1b, Bp2, hp2b, N_NODES);
    attn_scores<<<nhb, blk, 0, stream>>>(hp2b, as2, ad2, a_s, a_d, N_NODES, 40, 256);
    aggr2_fused<<<nb4, blk, 0, stream>>>(rowptr, srcs, a_s, a_d, hp2b, b2, out_cls);
}

// Round 6
// 443.438 us; speedup vs baseline: 4.9802x; 1.1451x over previous
//
#include <hip/hip_runtime.h>
#include <math.h>

// Problem constants (from reference)
constexpr int N_NODES = 50000;
constexpr int E_EDGES = 800000;
constexpr int ETOT    = E_EDGES + N_NODES;   // self-loops appended
constexpr int IN_C    = 128;
constexpr int HID     = 64;
constexpr int HEADS   = 5;
constexpr int CLS     = 40;
constexpr float NEG_SLOPE = 0.2f;

typedef __attribute__((ext_vector_type(8))) short short8;
typedef __attribute__((ext_vector_type(4))) float float4v;

__device__ __forceinline__ float lrelu(float v) {
    return v > 0.f ? v : NEG_SLOPE * v;
}
__device__ __forceinline__ float bf2f(unsigned short u) {
    return __uint_as_float(((unsigned)u) << 16);
}
__device__ __forceinline__ unsigned short f2bf(float f) {   // RNE
    unsigned u = __float_as_uint(f);
    return (unsigned short)((u + 0x7fffu + ((u >> 16) & 1u)) >> 16);
}

// ---------------------------------------------------------------------------
// Pack B [K x N] f32 into MFMA b-frag order, bf16 (one thread per 16B frag):
//   Bp[((nt*KS + ks)*4 + f)*512 + lane*8 + j] = B[ks*32+(lane>>4)*8+j][nt*64+f*16+(lane&15)]
__device__ __forceinline__ void pack_one(const float* __restrict__ B,
                                         unsigned short* __restrict__ Bp,
                                         int N, int KS, int t)
{
    int lane = t & 63;
    int f = (t >> 6) & 3;
    int rest = t >> 8;
    int ks = rest % KS;
    int nt = rest / KS;
    int n = nt * 64 + f * 16 + (lane & 15);
    int kbase = ks * 32 + (lane >> 4) * 8;
    unsigned short vals[8];
    #pragma unroll
    for (int j = 0; j < 8; j++) {
        float v = (n < N) ? B[(long)(kbase + j) * N + n] : 0.f;
        vals[j] = f2bf(v);
    }
    *(ushort4*)(Bp + (long)t * 8)     = make_ushort4(vals[0], vals[1], vals[2], vals[3]);
    *(ushort4*)(Bp + (long)t * 8 + 4) = make_ushort4(vals[4], vals[5], vals[6], vals[7]);
}

__global__ void pack_all(const float* __restrict__ W0, const float* __restrict__ W1,
                         const float* __restrict__ W2,
                         unsigned short* __restrict__ Bp0,
                         unsigned short* __restrict__ Bp1,
                         unsigned short* __restrict__ Bp2)
{
    int t = blockIdx.x * blockDim.x + threadIdx.x;
    if (t < 1024)       pack_one(W0, Bp0, 64,  4,  t);          // emb_W 128x64
    else if (t < 3584)  pack_one(W1, Bp1, 320, 2,  t - 1024);   // W1 64x320
    else if (t < 13824) pack_one(W2, Bp2, 200, 10, t - 3584);   // W2 320x200
}

// ---------------------------------------------------------------------------
// Embedding GEMM: f32 A in, K=128, N=64; +bias; writes f32 (d_out) + bf16 copy.
__global__ __launch_bounds__(256) void gemm_mfma_emb(
    const float* __restrict__ A, const unsigned short* __restrict__ Bp,
    const float* __restrict__ bias, float* __restrict__ Cf,
    unsigned short* __restrict__ Cb, int M)
{
    const int K = 128, KS = 4;
    const int w = threadIdx.x >> 6, lane = threadIdx.x & 63;
    const int cl = lane & 15, kq = lane >> 4;
    int rowA = blockIdx.x * 64 + w * 16 + cl;
    if (rowA >= M) rowA = M - 1;
    const float* ap = A + (long)rowA * K + kq * 8;
    const unsigned short* bp = Bp + lane * 8;
    float4v acc[4] = {};
    #pragma unroll
    for (int ks = 0; ks < KS; ks++) {
        float4 u0 = *(const float4*)(ap + ks * 32);
        float4 u1 = *(const float4*)(ap + ks * 32 + 4);
        short8 a;
        a[0] = f2bf(u0.x); a[1] = f2bf(u0.y); a[2] = f2bf(u0.z); a[3] = f2bf(u0.w);
        a[4] = f2bf(u1.x); a[5] = f2bf(u1.y); a[6] = f2bf(u1.z); a[7] = f2bf(u1.w);
        #pragma unroll
        for (int f = 0; f < 4; f++) {
            short8 b = *(const short8*)(bp + ks * 2048 + f * 512);
            acc[f] = __builtin_amdgcn_mfma_f32_16x16x32_bf16(a, b, acc[f], 0, 0, 0);
        }
    }
    int rbase = blockIdx.x * 64 + w * 16 + kq * 4;
    #pragma unroll
    for (int f = 0; f < 4; f++) {
        int col = f * 16 + cl;
        float bc = bias[col];
        #pragma unroll
        for (int r = 0; r < 4; r++) {
            int row = rbase + r;
            if (row < M) {
                float v = acc[f][r] + bc;
                Cf[(long)row * 64 + col] = v;
                Cb[(long)row * 64 + col] = f2bf(v);
            }
        }
    }
}

// ---------------------------------------------------------------------------
// Layer-1 GEMM (K=64, all 5 col-tiles per block) + fused attention scores.
__global__ __launch_bounds__(256) void gemm_attn_l1(
    const unsigned short* __restrict__ A, const unsigned short* __restrict__ Bp,
    const float* __restrict__ att_s, const float* __restrict__ att_d,
    unsigned short* __restrict__ C, float* __restrict__ a_s,
    float* __restrict__ a_d, int M)
{
    const int K = 64, KS = 2;
    const int w = threadIdx.x >> 6, lane = threadIdx.x & 63;
    const int cl = lane & 15, kq = lane >> 4;
    int rowA = blockIdx.x * 64 + w * 16 + cl;
    if (rowA >= M) rowA = M - 1;
    const unsigned short* ap = A + (long)rowA * K + kq * 8;
    const unsigned short* bp = Bp + lane * 8;
    float4v acc[20] = {};
    #pragma unroll
    for (int ks = 0; ks < KS; ks++) {
        short8 a = *(const short8*)(ap + ks * 32);
        #pragma unroll
        for (int nt = 0; nt < 5; nt++)
            #pragma unroll
            for (int f = 0; f < 4; f++) {
                short8 b = *(const short8*)(bp + (nt * KS + ks) * 2048 + f * 512);
                acc[nt * 4 + f] =
                    __builtin_amdgcn_mfma_f32_16x16x32_bf16(a, b, acc[nt * 4 + f], 0, 0, 0);
            }
    }
    int rbase = blockIdx.x * 64 + w * 16 + kq * 4;
    #pragma unroll
    for (int nt = 0; nt < 5; nt++)
        #pragma unroll
        for (int f = 0; f < 4; f++) {
            int col = nt * 64 + f * 16 + cl;
            #pragma unroll
            for (int r = 0; r < 4; r++) {
                int row = rbase + r;
                if (row < M) C[(long)row * 320 + col] = f2bf(acc[nt * 4 + f][r]);
            }
        }
    #pragma unroll
    for (int nt = 0; nt < 5; nt++) {
        float av[4], dv[4];
        #pragma unroll
        for (int f = 0; f < 4; f++) {
            av[f] = att_s[nt * 64 + f * 16 + cl];
            dv[f] = att_d[nt * 64 + f * 16 + cl];
        }
        #pragma unroll
        for (int r = 0; r < 4; r++) {
            float ps = 0.f, pd = 0.f;
            #pragma unroll
            for (int f = 0; f < 4; f++) {
                ps += acc[nt * 4 + f][r] * av[f];
                pd += acc[nt * 4 + f][r] * dv[f];
            }
            #pragma unroll
            for (int off = 1; off < 16; off <<= 1) {
                ps += __shfl_xor(ps, off);
                pd += __shfl_xor(pd, off);
            }
            int row = rbase + r;
            if (cl == 0 && row < M) {
                a_s[row * 5 + nt] = ps;
                a_d[row * 5 + nt] = pd;
            }
        }
    }
}

// ---------------------------------------------------------------------------
// Layer-2 GEMM: K=320, all 4 col-tiles per block; ldC=256 (cols>=200 are 0).
__global__ __launch_bounds__(256) void gemm_mfma_l2(
    const unsigned short* __restrict__ A, const unsigned short* __restrict__ Bp,
    unsigned short* __restrict__ C, int M)
{
    const int K = 320, KS = 10;
    const int w = threadIdx.x >> 6, lane = threadIdx.x & 63;
    const int cl = lane & 15, kq = lane >> 4;
    int rowA = blockIdx.x * 64 + w * 16 + cl;
    if (rowA >= M) rowA = M - 1;
    const unsigned short* ap = A + (long)rowA * K + kq * 8;
    const unsigned short* bp = Bp + lane * 8;
    float4v acc[16] = {};
    for (int ks = 0; ks < KS; ks++) {
        short8 a = *(const short8*)(ap + ks * 32);
        #pragma unroll
        for (int nt = 0; nt < 4; nt++)
            #pragma unroll
            for (int f = 0; f < 4; f++) {
                short8 b = *(const short8*)(bp + (nt * KS + ks) * 2048 + f * 512);
                acc[nt * 4 + f] =
                    __builtin_amdgcn_mfma_f32_16x16x32_bf16(a, b, acc[nt * 4 + f], 0, 0, 0);
            }
    }
    int rbase = blockIdx.x * 64 + w * 16 + kq * 4;
    #pragma unroll
    for (int nt = 0; nt < 4; nt++)
        #pragma unroll
        for (int f = 0; f < 4; f++) {
            int col = nt * 64 + f * 16 + cl;
            #pragma unroll
            for (int r = 0; r < 4; r++) {
                int row = rbase + r;
                if (row < M) C[(long)row * 256 + col] = f2bf(acc[nt * 4 + f][r]);
            }
        }
}

// ---------------------------------------------------------------------------
// a_s[n,h] = dot(hp[n,h,:], att_src[h,:]); hp bf16, row stride ld. (layer 2)
__global__ void attn_scores(const unsigned short* __restrict__ hp,
                            const float* __restrict__ att_s,
                            const float* __restrict__ att_d,
                            float* __restrict__ a_s, float* __restrict__ a_d,
                            int N, int C, int ld)
{
    int i = blockIdx.x * blockDim.x + threadIdx.x;
    if (i >= N * HEADS) return;
    int n = i / HEADS, h = i % HEADS;
    const unsigned short* p = hp + (long)n * ld + h * C;
    const float* as = att_s + h * C;
    const float* ad = att_d + h * C;
    float ss = 0.f, sd = 0.f;
    for (int c = 0; c < C; c += 4) {
        ushort4 xq = *(const ushort4*)(p + c);
        float4 uv = *(const float4*)(as + c);
        float4 wv = *(const float4*)(ad + c);
        float x0 = bf2f(xq.x), x1 = bf2f(xq.y), x2 = bf2f(xq.z), x3 = bf2f(xq.w);
        ss += x0 * uv.x + x1 * uv.y + x2 * uv.z + x3 * uv.w;
        sd += x0 * wv.x + x1 * wv.y + x2 * wv.z + x3 * wv.w;
    }
    a_s[i] = ss;
    a_d[i] = sd;
}

// ---------------------------------------------------------------------------
// CSR build: histogram -> exclusive scan -> scatter.
__global__ void hist_deg(const int* __restrict__ ei, int* __restrict__ rowptr)
{
    int e = blockIdx.x * blockDim.x + threadIdx.x;
    if (e >= ETOT) return;
    int d = (e < E_EDGES) ? ei[E_EDGES + e] : e - E_EDGES;
    atomicAdd(&rowptr[d], 1);
}

__global__ void scan_block_sums(const int* __restrict__ v, int* __restrict__ bsum, int n)
{
    __shared__ int sm[256];
    int i = blockIdx.x * 256 + threadIdx.x;
    sm[threadIdx.x] = (i < n) ? v[i] : 0;
    __syncthreads();
    #pragma unroll
    for (int off = 128; off; off >>= 1) {
        if (threadIdx.x < off) sm[threadIdx.x] += sm[threadIdx.x + off];
        __syncthreads();
    }
    if (threadIdx.x == 0) bsum[blockIdx.x] = sm[0];
}

// single-block exclusive scan over nb (<256) block sums
__global__ void scan_bsum(int* __restrict__ bsum, int nb)
{
    __shared__ int sm[256];
    int t = threadIdx.x;
    int x = (t < nb) ? bsum[t] : 0;
    sm[t] = x;
    __syncthreads();
    #pragma unroll
    for (int off = 1; off < 256; off <<= 1) {
        int v = (t >= (unsigned)off) ? sm[t - off] : 0;
        __syncthreads();
        sm[t] += v;
        __syncthreads();
    }
    if (t < nb) bsum[t] = sm[t] - x;   // exclusive
}

__global__ void scan_final(int* __restrict__ v, const int* __restrict__ bsum, int n)
{
    __shared__ int sm[256];
    int i = blockIdx.x * 256 + threadIdx.x;
    int x = (i < n) ? v[i] : 0;
    sm[threadIdx.x] = x;
    __syncthreads();
    #pragma unroll
    for (int off = 1; off < 256; off <<= 1) {
        int t = (threadIdx.x >= (unsigned)off) ? sm[threadIdx.x - off] : 0;
        __syncthreads();
        sm[threadIdx.x] += t;
        __syncthreads();
    }
    if (i < n) v[i] = bsum[blockIdx.x] + sm[threadIdx.x] - x;  // exclusive
}

__global__ void scatter_src(const int* __restrict__ ei, int* __restrict__ rowptr,
                            unsigned short* __restrict__ srcs)
{
    int e = blockIdx.x * blockDim.x + threadIdx.x;
    if (e >= ETOT) return;
    int s, d;
    if (e < E_EDGES) { s = ei[e]; d = ei[E_EDGES + e]; }
    else             { s = d = e - E_EDGES; }
    int pos = atomicAdd(&rowptr[d], 1);
    srcs[pos] = (unsigned short)s;
}

// ---------------------------------------------------------------------------
// Fused layer-1 GAT: wave per dst node. Fast path (deg<=64): alpha + src live
// in lane registers; src broadcast via shfl; alpha pairs (head_g, head_4) in
// wave-private LDS (no barrier). Gather unrolled x4 for MLP. No atomics.
__global__ __launch_bounds__(256) void aggr1_fused(
    const int* __restrict__ rowptr, const unsigned short* __restrict__ srcs,
    const float* __restrict__ a_s, const float* __restrict__ a_d,
    const unsigned short* __restrict__ hp, const float* __restrict__ bias,
    unsigned short* __restrict__ out)
{
    __shared__ float2 alph2[4][320];   // [wave][edge*5 + g] = (alpha_g, alpha_4)
    int wid = (blockIdx.x * blockDim.x + threadIdx.x) >> 6;
    int w = threadIdx.x >> 6;
    int lane = threadIdx.x & 63;
    if (wid >= N_NODES) return;
    int beg = (wid == 0) ? 0 : rowptr[wid - 1];
    int end = rowptr[wid];
    int deg = end - beg;

    float adh[HEADS];
    #pragma unroll
    for (int h = 0; h < HEADS; h++) adh[h] = a_d[wid * HEADS + h];

    const int ch4 = lane * 4;
    const int g = lane >> 4;
    float acc0 = 0.f, acc1 = 0.f, acc2 = 0.f, acc3 = 0.f, accT = 0.f;

    if (deg <= 64) {
        bool has = lane < deg;
        int s = has ? (int)srcs[beg + lane] : 0;
        float v[HEADS], mx[HEADS], sm[HEADS];
        #pragma unroll
        for (int h = 0; h < HEADS; h++) {
            v[h] = has ? lrelu(a_s[s * HEADS + h] + adh[h]) : -1e30f;
            mx[h] = v[h];
        }
        #pragma unroll
        for (int h = 0; h < HEADS; h++)
            #pragma unroll
            for (int off = 32; off; off >>= 1)
                mx[h] = fmaxf(mx[h], __shfl_xor(mx[h], off));
        #pragma unroll
        for (int h = 0; h < HEADS; h++) {
            float e = has ? __expf(v[h] - mx[h]) : 0.f;
            v[h] = e;
            sm[h] = e;
        }
        #pragma unroll
        for (int h = 0; h < HEADS; h++)
            #pragma unroll
            for (int off = 32; off; off >>= 1)
                sm[h] += __shfl_xor(sm[h], off);
        if (has) {
            #pragma unroll
            for (int h = 0; h < HEADS; h++)
                v[h] = v[h] / (sm[h] + 1e-16f);
            #pragma unroll
            for (int gg = 0; gg < 4; gg++)
                alph2[w][lane * 5 + gg] = make_float2(v[gg], v[4]);
        }
        // gather, unrolled x4 (wave-private LDS: no barrier needed)
        int i = 0;
        for (; i + 3 < deg; i += 4) {
            int s0 = __shfl(s, i), s1 = __shfl(s, i + 1);
            int s2 = __shfl(s, i + 2), s3 = __shfl(s, i + 3);
            const unsigned short* r0 = hp + (long)s0 * 320;
            const unsigned short* r1 = hp + (long)s1 * 320;
            const unsigned short* r2 = hp + (long)s2 * 320;
            const unsigned short* r3 = hp + (long)s3 * 320;
            ushort4 q0 = *(const ushort4*)(r0 + ch4);
            ushort4 q1 = *(const ushort4*)(r1 + ch4);
            ushort4 q2 = *(const ushort4*)(r2 + ch4);
            ushort4 q3 = *(const ushort4*)(r3 + ch4);
            unsigned short t0 = r0[256 + lane], t1 = r1[256 + lane];
            unsigned short t2 = r2[256 + lane], t3 = r3[256 + lane];
            float2 p0 = alph2[w][(i + 0) * 5 + g];
            float2 p1 = alph2[w][(i + 1) * 5 + g];
            float2 p2 = alph2[w][(i + 2) * 5 + g];
            float2 p3 = alph2[w][(i + 3) * 5 + g];
            acc0 += bf2f(q0.x) * p0.x + bf2f(q1.x) * p1.x
                  + bf2f(q2.x) * p2.x + bf2f(q3.x) * p3.x;
            acc1 += bf2f(q0.y) * p0.x + bf2f(q1.y) * p1.x
                  + bf2f(q2.y) * p2.x + bf2f(q3.y) * p3.x;
            acc2 += bf2f(q0.z) * p0.x + bf2f(q1.z) * p1.x
                  + bf2f(q2.z) * p2.x + bf2f(q3.z) * p3.x;
            acc3 += bf2f(q0.w) * p0.x + bf2f(q1.w) * p1.x
                  + bf2f(q2.w) * p2.x + bf2f(q3.w) * p3.x;
            accT += bf2f(t0) * p0.y + bf2f(t1) * p1.y
                  + bf2f(t2) * p2.y + bf2f(t3) * p3.y;
        }
        for (; i < deg; i++) {
            int s0 = __shfl(s, i);
            const unsigned short* r0 = hp + (long)s0 * 320;
            ushort4 q0 = *(const ushort4*)(r0 + ch4);
            unsigned short t0 = r0[256 + lane];
            float2 p0 = alph2[w][i * 5 + g];
            acc0 += bf2f(q0.x) * p0.x;
            acc1 += bf2f(q0.y) * p0.x;
            acc2 += bf2f(q0.z) * p0.x;
            acc3 += bf2f(q0.w) * p0.x;
            accT += bf2f(t0) * p0.y;
        }
    } else {
        float mx[HEADS], inv[HEADS], sm[HEADS] = {};
        #pragma unroll
        for (int h = 0; h < HEADS; h++) mx[h] = -1e30f;
        for (int e = beg + lane; e < end; e += 64) {
            int s = srcs[e];
            #pragma unroll
            for (int h = 0; h < HEADS; h++)
                mx[h] = fmaxf(mx[h], lrelu(a_s[s * HEADS + h] + adh[h]));
        }
        #pragma unroll
        for (int h = 0; h < HEADS; h++)
            #pragma unroll
            for (int off = 32; off; off >>= 1)
                mx[h] = fmaxf(mx[h], __shfl_xor(mx[h], off));
        for (int e = beg + lane; e < end; e += 64) {
            int s = srcs[e];
            #pragma unroll
            for (int h = 0; h < HEADS; h++)
                sm[h] += __expf(lrelu(a_s[s * HEADS + h] + adh[h]) - mx[h]);
        }
        #pragma unroll
        for (int h = 0; h < HEADS; h++) {
            #pragma unroll
            for (int off = 32; off; off >>= 1)
                sm[h] += __shfl_xor(sm[h], off);
            inv[h] = 1.f / (sm[h] + 1e-16f);
        }
        for (int e = beg; e < end; e++) {
            int s0 = srcs[e];
            const unsigned short* r0 = hp + (long)s0 * 320;
            ushort4 q0 = *(const ushort4*)(r0 + ch4);
            unsigned short t0 = r0[256 + lane];
            int hq = g;
            float a0  = __expf(lrelu(a_s[s0 * HEADS + hq] + adh[hq]) - mx[hq]) * inv[hq];
            float a0t = __expf(lrelu(a_s[s0 * HEADS + 4] + adh[4]) - mx[4]) * inv[4];
            acc0 += bf2f(q0.x) * a0;
            acc1 += bf2f(q0.y) * a0;
            acc2 += bf2f(q0.z) * a0;
            acc3 += bf2f(q0.w) * a0;
            accT += bf2f(t0) * a0t;
        }
    }

    float v0 = acc0 + bias[ch4 + 0];
    float v1 = acc1 + bias[ch4 + 1];
    float v2 = acc2 + bias[ch4 + 2];
    float v3 = acc3 + bias[ch4 + 3];
    v0 = v0 > 0.f ? v0 : expm1f(v0);
    v1 = v1 > 0.f ? v1 : expm1f(v1);
    v2 = v2 > 0.f ? v2 : expm1f(v2);
    v3 = v3 > 0.f ? v3 : expm1f(v3);
    float vt = accT + bias[256 + lane];
    vt = vt > 0.f ? vt : expm1f(vt);
    *(ushort4*)(out + (long)wid * 320 + ch4) =
        make_ushort4(f2bf(v0), f2bf(v1), f2bf(v2), f2bf(v3));
    out[(long)wid * 320 + 256 + lane] = f2bf(vt);
}

// ---------------------------------------------------------------------------
// Fused layer-2 GAT: same structure; 0.2 head-mean folded into alpha; fused
// bias + log_softmax; hp row stride 256; final rows to d_out.
__global__ __launch_bounds__(256) void aggr2_fused(
    const int* __restrict__ rowptr, const unsigned short* __restrict__ srcs,
    const float* __restrict__ a_s, const float* __restrict__ a_d,
    const unsigned short* __restrict__ hp, const float* __restrict__ bias,
    float* __restrict__ out)
{
    __shared__ float alph[4][320];   // [wave][edge*5 + h]
    int wid = (blockIdx.x * blockDim.x + threadIdx.x) >> 6;
    int w = threadIdx.x >> 6;
    int lane = threadIdx.x & 63;
    if (wid >= N_NODES) return;
    int beg = (wid == 0) ? 0 : rowptr[wid - 1];
    int end = rowptr[wid];
    int deg = end - beg;

    float adh[HEADS];
    #pragma unroll
    for (int h = 0; h < HEADS; h++) adh[h] = a_d[wid * HEADS + h];

    const bool act = lane < 50;
    const int ch4 = lane * 4;
    const int hq  = act ? lane / 10 : 0;
    float acc0 = 0.f, acc1 = 0.f, acc2 = 0.f, acc3 = 0.f;

    if (deg <= 64) {
        bool has = lane < deg;
        int s = has ? (int)srcs[beg + lane] : 0;
        float v[HEADS], mx[HEADS], sm[HEADS];
        #pragma unroll
        for (int h = 0; h < HEADS; h++) {
            v[h] = has ? lrelu(a_s[s * HEADS + h] + adh[h]) : -1e30f;
            mx[h] = v[h];
        }
        #pragma unroll
        for (int h = 0; h < HEADS; h++)
            #pragma unroll
            for (int off = 32; off; off >>= 1)
                mx[h] = fmaxf(mx[h], __shfl_xor(mx[h], off));
        #pragma unroll
        for (int h = 0; h < HEADS; h++) {
            float e = has ? __expf(v[h] - mx[h]) : 0.f;
            v[h] = e;
            sm[h] = e;
        }
        #pragma unroll
        for (int h = 0; h < HEADS; h++)
            #pragma unroll
            for (int off = 32; off; off >>= 1)
                sm[h] += __shfl_xor(sm[h], off);
        if (has) {
            #pragma unroll
            for (int h = 0; h < HEADS; h++)
                alph[w][lane * 5 + h] = 0.2f * v[h] / (sm[h] + 1e-16f);
        }
        int i = 0;
        for (; i + 3 < deg; i += 4) {
            int s0 = __shfl(s, i), s1 = __shfl(s, i + 1);
            int s2 = __shfl(s, i + 2), s3 = __shfl(s, i + 3);
            if (act) {
                ushort4 q0 = *(const ushort4*)(hp + (long)s0 * 256 + ch4);
                ushort4 q1 = *(const ushort4*)(hp + (long)s1 * 256 + ch4);
                ushort4 q2 = *(const ushort4*)(hp + (long)s2 * 256 + ch4);
                ushort4 q3 = *(const ushort4*)(hp + (long)s3 * 256 + ch4);
                float a0 = alph[w][(i + 0) * 5 + hq];
                float a1 = alph[w][(i + 1) * 5 + hq];
                float a2 = alph[w][(i + 2) * 5 + hq];
                float a3 = alph[w][(i + 3) * 5 + hq];
                acc0 += bf2f(q0.x) * a0 + bf2f(q1.x) * a1
                      + bf2f(q2.x) * a2 + bf2f(q3.x) * a3;
                acc1 += bf2f(q0.y) * a0 + bf2f(q1.y) * a1
                      + bf2f(q2.y) * a2 + bf2f(q3.y) * a3;
                acc2 += bf2f(q0.z) * a0 + bf2f(q1.z) * a1
                      + bf2f(q2.z) * a2 + bf2f(q3.z) * a3;
                acc3 += bf2f(q0.w) * a0 + bf2f(q1.w) * a1
                      + bf2f(q2.w) * a2 + bf2f(q3.w) * a3;
            }
        }
        for (; i < deg; i++) {
            int s0 = __shfl(s, i);
            if (act) {
                ushort4 q0 = *(const ushort4*)(hp + (long)s0 * 256 + ch4);
                float a0 = alph[w][i * 5 + hq];
                acc0 += bf2f(q0.x) * a0;
                acc1 += bf2f(q0.y) * a0;
                acc2 += bf2f(q0.z) * a0;
                acc3 += bf2f(q0.w) * a0;
            }
        }
    } else {
        float mx[HEADS], inv[HEADS], sm[HEADS] = {};
        #pragma unroll
        for (int h = 0; h < HEADS; h++) mx[h] = -1e30f;
        for (int e = beg + lane; e < end; e += 64) {
            int s = srcs[e];
            #pragma unroll
            for (int h = 0; h < HEADS; h++)
                mx[h] = fmaxf(mx[h], lrelu(a_s[s * HEADS + h] + adh[h]));
        }
        #pragma unroll
        for (int h = 0; h < HEADS; h++)
            #pragma unroll
            for (int off = 32; off; off >>= 1)
                mx[h] = fmaxf(mx[h], __shfl_xor(mx[h], off));
        for (int e = beg + lane; e < end; e += 64) {
            int s = srcs[e];
            #pragma unroll
            for (int h = 0; h < HEADS; h++)
                sm[h] += __expf(lrelu(a_s[s * HEADS + h] + adh[h]) - mx[h]);
        }
        #pragma unroll
        for (int h = 0; h < HEADS; h++) {
            #pragma unroll
            for (int off = 32; off; off >>= 1)
                sm[h] += __shfl_xor(sm[h], off);
            inv[h] = 0.2f / (sm[h] + 1e-16f);
        }
        for (int e = beg; e < end; e++) {
            int s0 = srcs[e];
            if (act) {
                ushort4 q0 = *(const ushort4*)(hp + (long)s0 * 256 + ch4);
                float a0 = __expf(lrelu(a_s[s0 * HEADS + hq] + adh[hq]) - mx[hq]) * inv[hq];
                acc0 += bf2f(q0.x) * a0;
                acc1 += bf2f(q0.y) * a0;
                acc2 += bf2f(q0.z) * a0;
                acc3 += bf2f(q0.w) * a0;
            }
        }
    }

    float r0 = acc0, r1 = acc1, r2 = acc2, r3 = acc3;
    #pragma unroll
    for (int h5 = 1; h5 < 5; h5++) {
        int sl = (lane + 10 * h5) & 63;
        r0 += __shfl(acc0, sl);
        r1 += __shfl(acc1, sl);
        r2 += __shfl(acc2, sl);
        r3 += __shfl(acc3, sl);
    }

    float vb0 = -1e30f, vb1 = -1e30f, vb2 = -1e30f, vb3 = -1e30f;
    if (lane < 10) {
        vb0 = r0 + bias[ch4 + 0];
        vb1 = r1 + bias[ch4 + 1];
        vb2 = r2 + bias[ch4 + 2];
        vb3 = r3 + bias[ch4 + 3];
    }
    float mxv = fmaxf(fmaxf(vb0, vb1), fmaxf(vb2, vb3));
    #pragma unroll
    for (int off = 32; off; off >>= 1)
        mxv = fmaxf(mxv, __shfl_xor(mxv, off));
    float sme = 0.f;
    if (lane < 10)
        sme = __expf(vb0 - mxv) + __expf(vb1 - mxv) +
              __expf(vb2 - mxv) + __expf(vb3 - mxv);
    #pragma unroll
    for (int off = 32; off; off >>= 1)
        sme += __shfl_xor(sme, off);
    float ls = mxv + logf(sme);
    if (lane < 10) {
        float4 o = make_float4(vb0 - ls, vb1 - ls, vb2 - ls, vb3 - ls);
        *(float4*)(out + (long)wid * CLS + ch4) = o;
    }
}

// ---------------------------------------------------------------------------
extern "C" void kernel_launch(void* const* d_in, const int* in_sizes, int n_in,
                              void* d_out, int out_size, void* d_ws, size_t ws_size,
                              hipStream_t stream)
{
    const float* x     = (const float*)d_in[0];
    const int*   ei    = (const int*)d_in[1];
    const float* emb_W = (const float*)d_in[2];
    const float* emb_b = (const float*)d_in[3];
    const float* W1    = (const float*)d_in[4];
    const float* as1   = (const float*)d_in[5];
    const float* ad1   = (const float*)d_in[6];
    const float* b1    = (const float*)d_in[7];
    const float* W2    = (const float*)d_in[8];
    const float* as2   = (const float*)d_in[9];
    const float* ad2   = (const float*)d_in[10];
    const float* b2    = (const float*)d_in[11];

    float* out_emb = (float*)d_out;                         // [N,64] f32
    float* out_cls = (float*)d_out + (size_t)N_NODES * HID; // [N,40] f32

    char* ws = (char*)d_ws;
    unsigned short* hp1b   = (unsigned short*)(ws);               // 32 MB [N,320]
    unsigned short* hp2b   = (unsigned short*)(ws);               // 25.6 MB [N,256] (reuse)
    unsigned short* h1b    = (unsigned short*)(ws + 32000000);    // 32 MB [N,320]
    unsigned short* embb   = (unsigned short*)(ws + 64000000);    // 6.4 MB [N,64]
    float*          a_s    = (float*)(ws + 70400000);             // 1 MB
    float*          a_d    = (float*)(ws + 71400000);             // 1 MB
    unsigned short* Bp0    = (unsigned short*)(ws + 72400000);    // 16 KB
    unsigned short* Bp1    = (unsigned short*)(ws + 72500000);    // 40 KB
    unsigned short* Bp2    = (unsigned short*)(ws + 72600000);    // 160 KB
    int*            rowptr = (int*)(ws + 72800000);               // 200 KB
    int*            bsum   = (int*)(ws + 73100000);               // ~1 KB
    unsigned short* srcs   = (unsigned short*)(ws + 73110000);    // 1.7 MB

    const dim3 blk(256);
    const int nhb = (N_NODES * HEADS + 255) / 256;
    const int eb  = (ETOT + 255) / 256;
    const int nb4 = (N_NODES + 3) / 4;
    const int nscan = N_NODES + 1;
    const int NB = (nscan + 255) / 256;            // 196
    const int mgrid = (N_NODES + 63) / 64;         // 782

    // ---- weight packing (single kernel) ----
    pack_all<<<(13824 + 255) / 256, blk, 0, stream>>>(emb_W, W1, W2, Bp0, Bp1, Bp2);

    // ---- CSR build ----
    hipMemsetAsync(rowptr, 0, (size_t)nscan * 4, stream);
    hist_deg<<<eb, blk, 0, stream>>>(ei, rowptr);
    scan_block_sums<<<NB, blk, 0, stream>>>(rowptr, bsum, nscan);
    scan_bsum<<<1, blk, 0, stream>>>(bsum, NB);
    scan_final<<<NB, blk, 0, stream>>>(rowptr, bsum, nscan);
    scatter_src<<<eb, blk, 0, stream>>>(ei, rowptr, srcs);

    // ---- embedding (output 0 f32 + bf16 copy), reads f32 x directly ----
    gemm_mfma_emb<<<mgrid, blk, 0, stream>>>(x, Bp0, emb_b, out_emb, embb, N_NODES);

    // ---- layer 1 ----
    gemm_attn_l1<<<mgrid, blk, 0, stream>>>(embb, Bp1, as1, ad1,
                                            hp1b, a_s, a_d, N_NODES);
    aggr1_fused<<<nb4, blk, 0, stream>>>(rowptr, srcs, a_s, a_d, hp1b, b1, h1b);

    // ---- layer 2 ----
    gemm_mfma_l2<<<mgrid, blk, 0, stream>>>(h1b, Bp2, hp2b, N_NODES);
    attn_scores<<<nhb, blk, 0, stream>>>(hp2b, as2, ad2, a_s, a_d, N_NODES, 40, 256);
    aggr2_fused<<<nb4, blk, 0, stream>>>(rowptr, srcs, a_s, a_d, hp2b, b2, out_cls);
}

// Round 7
// 412.930 us; speedup vs baseline: 5.3482x; 1.0739x over previous
//
#include <hip/hip_runtime.h>
#include <math.h>

// Problem constants (from reference)
constexpr int N_NODES = 50000;
constexpr int E_EDGES = 800000;
constexpr int ETOT    = E_EDGES + N_NODES;   // self-loops appended
constexpr int IN_C    = 128;
constexpr int HID     = 64;
constexpr int HEADS   = 5;
constexpr int CLS     = 40;
constexpr int SLOTW   = 96;                  // ELL slot width (max deg ~45)
constexpr float NEG_SLOPE = 0.2f;

typedef __attribute__((ext_vector_type(8))) short short8;
typedef __attribute__((ext_vector_type(4))) float float4v;

__device__ __forceinline__ float lrelu(float v) {
    return v > 0.f ? v : NEG_SLOPE * v;
}
__device__ __forceinline__ float bf2f(unsigned short u) {
    return __uint_as_float(((unsigned)u) << 16);
}
__device__ __forceinline__ unsigned short f2bf(float f) {   // RNE
    unsigned u = __float_as_uint(f);
    return (unsigned short)((u + 0x7fffu + ((u >> 16) & 1u)) >> 16);
}

// ---------------------------------------------------------------------------
// Pack B [K x N] f32 into MFMA b-frag order, bf16 (one thread per 16B frag):
//   Bp[((nt*KS + ks)*4 + f)*512 + lane*8 + j] = B[ks*32+(lane>>4)*8+j][nt*64+f*16+(lane&15)]
__device__ __forceinline__ void pack_one(const float* __restrict__ B,
                                         unsigned short* __restrict__ Bp,
                                         int N, int KS, int t)
{
    int lane = t & 63;
    int f = (t >> 6) & 3;
    int rest = t >> 8;
    int ks = rest % KS;
    int nt = rest / KS;
    int n = nt * 64 + f * 16 + (lane & 15);
    int kbase = ks * 32 + (lane >> 4) * 8;
    unsigned short vals[8];
    #pragma unroll
    for (int j = 0; j < 8; j++) {
        float v = (n < N) ? B[(long)(kbase + j) * N + n] : 0.f;
        vals[j] = f2bf(v);
    }
    *(ushort4*)(Bp + (long)t * 8)     = make_ushort4(vals[0], vals[1], vals[2], vals[3]);
    *(ushort4*)(Bp + (long)t * 8 + 4) = make_ushort4(vals[4], vals[5], vals[6], vals[7]);
}

// ---------------------------------------------------------------------------
// build_graph: ELL slot scatter (cnt must be pre-zeroed) + weight packing.
// slots[d*96 + pos] = src; cnt[d] = degree.
__global__ void build_graph(const int* __restrict__ ei, int* __restrict__ cnt,
                            unsigned short* __restrict__ slots,
                            const float* __restrict__ W0, const float* __restrict__ W1,
                            const float* __restrict__ W2,
                            unsigned short* __restrict__ Bp0,
                            unsigned short* __restrict__ Bp1,
                            unsigned short* __restrict__ Bp2)
{
    int t = blockIdx.x * blockDim.x + threadIdx.x;
    if (t < 13824) {
        if (t < 1024)      pack_one(W0, Bp0, 64,  4,  t);           // emb_W 128x64
        else if (t < 3584) pack_one(W1, Bp1, 320, 2,  t - 1024);    // W1 64x320
        else               pack_one(W2, Bp2, 200, 10, t - 3584);    // W2 320x200
    }
    if (t >= ETOT) return;
    int s, d;
    if (t < E_EDGES) { s = ei[t]; d = ei[E_EDGES + t]; }
    else             { s = d = t - E_EDGES; }
    int pos = atomicAdd(&cnt[d], 1);
    if (pos < SLOTW) slots[d * SLOTW + pos] = (unsigned short)s;
}

// ---------------------------------------------------------------------------
// Embedding GEMM: f32 A in, K=128, N=64; +bias; writes f32 (d_out) + bf16 copy.
__global__ __launch_bounds__(256) void gemm_mfma_emb(
    const float* __restrict__ A, const unsigned short* __restrict__ Bp,
    const float* __restrict__ bias, float* __restrict__ Cf,
    unsigned short* __restrict__ Cb, int M)
{
    const int K = 128, KS = 4;
    const int w = threadIdx.x >> 6, lane = threadIdx.x & 63;
    const int cl = lane & 15, kq = lane >> 4;
    int rowA = blockIdx.x * 64 + w * 16 + cl;
    if (rowA >= M) rowA = M - 1;
    const float* ap = A + (long)rowA * K + kq * 8;
    const unsigned short* bp = Bp + lane * 8;
    float4v acc[4] = {};
    #pragma unroll
    for (int ks = 0; ks < KS; ks++) {
        float4 u0 = *(const float4*)(ap + ks * 32);
        float4 u1 = *(const float4*)(ap + ks * 32 + 4);
        short8 a;
        a[0] = f2bf(u0.x); a[1] = f2bf(u0.y); a[2] = f2bf(u0.z); a[3] = f2bf(u0.w);
        a[4] = f2bf(u1.x); a[5] = f2bf(u1.y); a[6] = f2bf(u1.z); a[7] = f2bf(u1.w);
        #pragma unroll
        for (int f = 0; f < 4; f++) {
            short8 b = *(const short8*)(bp + ks * 2048 + f * 512);
            acc[f] = __builtin_amdgcn_mfma_f32_16x16x32_bf16(a, b, acc[f], 0, 0, 0);
        }
    }
    int rbase = blockIdx.x * 64 + w * 16 + kq * 4;
    #pragma unroll
    for (int f = 0; f < 4; f++) {
        int col = f * 16 + cl;
        float bc = bias[col];
        #pragma unroll
        for (int r = 0; r < 4; r++) {
            int row = rbase + r;
            if (row < M) {
                float v = acc[f][r] + bc;
                Cf[(long)row * 64 + col] = v;
                Cb[(long)row * 64 + col] = f2bf(v);
            }
        }
    }
}

// ---------------------------------------------------------------------------
// Layer-1 GEMM (K=64, all 5 col-tiles per block) + fused attention scores.
__global__ __launch_bounds__(256) void gemm_attn_l1(
    const unsigned short* __restrict__ A, const unsigned short* __restrict__ Bp,
    const float* __restrict__ att_s, const float* __restrict__ att_d,
    unsigned short* __restrict__ C, float* __restrict__ a_s,
    float* __restrict__ a_d, int M)
{
    const int K = 64, KS = 2;
    const int w = threadIdx.x >> 6, lane = threadIdx.x & 63;
    const int cl = lane & 15, kq = lane >> 4;
    int rowA = blockIdx.x * 64 + w * 16 + cl;
    if (rowA >= M) rowA = M - 1;
    const unsigned short* ap = A + (long)rowA * K + kq * 8;
    const unsigned short* bp = Bp + lane * 8;
    float4v acc[20] = {};
    #pragma unroll
    for (int ks = 0; ks < KS; ks++) {
        short8 a = *(const short8*)(ap + ks * 32);
        #pragma unroll
        for (int nt = 0; nt < 5; nt++)
            #pragma unroll
            for (int f = 0; f < 4; f++) {
                short8 b = *(const short8*)(bp + (nt * KS + ks) * 2048 + f * 512);
                acc[nt * 4 + f] =
                    __builtin_amdgcn_mfma_f32_16x16x32_bf16(a, b, acc[nt * 4 + f], 0, 0, 0);
            }
    }
    int rbase = blockIdx.x * 64 + w * 16 + kq * 4;
    #pragma unroll
    for (int nt = 0; nt < 5; nt++)
        #pragma unroll
        for (int f = 0; f < 4; f++) {
            int col = nt * 64 + f * 16 + cl;
            #pragma unroll
            for (int r = 0; r < 4; r++) {
                int row = rbase + r;
                if (row < M) C[(long)row * 320 + col] = f2bf(acc[nt * 4 + f][r]);
            }
        }
    #pragma unroll
    for (int nt = 0; nt < 5; nt++) {
        float av[4], dv[4];
        #pragma unroll
        for (int f = 0; f < 4; f++) {
            av[f] = att_s[nt * 64 + f * 16 + cl];
            dv[f] = att_d[nt * 64 + f * 16 + cl];
        }
        #pragma unroll
        for (int r = 0; r < 4; r++) {
            float ps = 0.f, pd = 0.f;
            #pragma unroll
            for (int f = 0; f < 4; f++) {
                ps += acc[nt * 4 + f][r] * av[f];
                pd += acc[nt * 4 + f][r] * dv[f];
            }
            #pragma unroll
            for (int off = 1; off < 16; off <<= 1) {
                ps += __shfl_xor(ps, off);
                pd += __shfl_xor(pd, off);
            }
            int row = rbase + r;
            if (cl == 0 && row < M) {
                a_s[row * 5 + nt] = ps;
                a_d[row * 5 + nt] = pd;
            }
        }
    }
}

// ---------------------------------------------------------------------------
// Layer-2 GEMM: K=320, all 4 col-tiles per block; ldC=256 (cols>=200 are 0).
__global__ __launch_bounds__(256) void gemm_mfma_l2(
    const unsigned short* __restrict__ A, const unsigned short* __restrict__ Bp,
    unsigned short* __restrict__ C, int M)
{
    const int K = 320, KS = 10;
    const int w = threadIdx.x >> 6, lane = threadIdx.x & 63;
    const int cl = lane & 15, kq = lane >> 4;
    int rowA = blockIdx.x * 64 + w * 16 + cl;
    if (rowA >= M) rowA = M - 1;
    const unsigned short* ap = A + (long)rowA * K + kq * 8;
    const unsigned short* bp = Bp + lane * 8;
    float4v acc[16] = {};
    for (int ks = 0; ks < KS; ks++) {
        short8 a = *(const short8*)(ap + ks * 32);
        #pragma unroll
        for (int nt = 0; nt < 4; nt++)
            #pragma unroll
            for (int f = 0; f < 4; f++) {
                short8 b = *(const short8*)(bp + (nt * KS + ks) * 2048 + f * 512);
                acc[nt * 4 + f] =
                    __builtin_amdgcn_mfma_f32_16x16x32_bf16(a, b, acc[nt * 4 + f], 0, 0, 0);
            }
    }
    int rbase = blockIdx.x * 64 + w * 16 + kq * 4;
    #pragma unroll
    for (int nt = 0; nt < 4; nt++)
        #pragma unroll
        for (int f = 0; f < 4; f++) {
            int col = nt * 64 + f * 16 + cl;
            #pragma unroll
            for (int r = 0; r < 4; r++) {
                int row = rbase + r;
                if (row < M) C[(long)row * 256 + col] = f2bf(acc[nt * 4 + f][r]);
            }
        }
}

// ---------------------------------------------------------------------------
// a_s[n,h] = dot(hp[n,h,:], att_src[h,:]); hp bf16, row stride ld. (layer 2)
__global__ void attn_scores(const unsigned short* __restrict__ hp,
                            const float* __restrict__ att_s,
                            const float* __restrict__ att_d,
                            float* __restrict__ a_s, float* __restrict__ a_d,
                            int N, int C, int ld)
{
    int i = blockIdx.x * blockDim.x + threadIdx.x;
    if (i >= N * HEADS) return;
    int n = i / HEADS, h = i % HEADS;
    const unsigned short* p = hp + (long)n * ld + h * C;
    const float* as = att_s + h * C;
    const float* ad = att_d + h * C;
    float ss = 0.f, sd = 0.f;
    for (int c = 0; c < C; c += 4) {
        ushort4 xq = *(const ushort4*)(p + c);
        float4 uv = *(const float4*)(as + c);
        float4 wv = *(const float4*)(ad + c);
        float x0 = bf2f(xq.x), x1 = bf2f(xq.y), x2 = bf2f(xq.z), x3 = bf2f(xq.w);
        ss += x0 * uv.x + x1 * uv.y + x2 * uv.z + x3 * uv.w;
        sd += x0 * wv.x + x1 * wv.y + x2 * wv.z + x3 * wv.w;
    }
    a_s[i] = ss;
    a_d[i] = sd;
}

// ---------------------------------------------------------------------------
// Fused layer-1 GAT: wave per dst node. Fast path (deg<=64): alpha + src in
// lane registers; src broadcast via shfl; alpha pairs in wave-private LDS.
// Gather unrolled x8 for MLP. No atomics. ELL slots (beg = wid*96).
__global__ __launch_bounds__(256) void aggr1_fused(
    const int* __restrict__ cnt, const unsigned short* __restrict__ slots,
    const float* __restrict__ a_s, const float* __restrict__ a_d,
    const unsigned short* __restrict__ hp, const float* __restrict__ bias,
    unsigned short* __restrict__ out)
{
    __shared__ float2 alph2[4][320];   // [wave][edge*5 + g] = (alpha_g, alpha_4)
    int wid = (blockIdx.x * blockDim.x + threadIdx.x) >> 6;
    int w = threadIdx.x >> 6;
    int lane = threadIdx.x & 63;
    if (wid >= N_NODES) return;
    int deg = cnt[wid];
    if (deg > SLOTW) deg = SLOTW;
    const unsigned short* myslot = slots + wid * SLOTW;

    float adh[HEADS];
    #pragma unroll
    for (int h = 0; h < HEADS; h++) adh[h] = a_d[wid * HEADS + h];

    const int ch4 = lane * 4;
    const int g = lane >> 4;
    const char* hpB = (const char*)hp;
    float acc0 = 0.f, acc1 = 0.f, acc2 = 0.f, acc3 = 0.f, accT = 0.f;

    if (deg <= 64) {
        bool has = lane < deg;
        int s = has ? (int)myslot[lane] : 0;
        int rowoff = s * 640;           // byte offset of src row
        float v[HEADS], mx[HEADS], sm[HEADS];
        #pragma unroll
        for (int h = 0; h < HEADS; h++) {
            v[h] = has ? lrelu(a_s[s * HEADS + h] + adh[h]) : -1e30f;
            mx[h] = v[h];
        }
        #pragma unroll
        for (int h = 0; h < HEADS; h++)
            #pragma unroll
            for (int off = 32; off; off >>= 1)
                mx[h] = fmaxf(mx[h], __shfl_xor(mx[h], off));
        #pragma unroll
        for (int h = 0; h < HEADS; h++) {
            float e = has ? __expf(v[h] - mx[h]) : 0.f;
            v[h] = e;
            sm[h] = e;
        }
        #pragma unroll
        for (int h = 0; h < HEADS; h++)
            #pragma unroll
            for (int off = 32; off; off >>= 1)
                sm[h] += __shfl_xor(sm[h], off);
        if (has) {
            #pragma unroll
            for (int h = 0; h < HEADS; h++)
                v[h] = v[h] / (sm[h] + 1e-16f);
            #pragma unroll
            for (int gg = 0; gg < 4; gg++)
                alph2[w][lane * 5 + gg] = make_float2(v[gg], v[4]);
        }
        // gather, unrolled x8 (wave-private LDS slice: no barrier needed)
        int i = 0;
        for (; i + 7 < deg; i += 8) {
            ushort4 q[8]; unsigned short tt[8]; float2 p[8];
            #pragma unroll
            for (int k = 0; k < 8; k++) {
                int off = __shfl(rowoff, i + k);
                const char* rb = hpB + off;
                q[k]  = *(const ushort4*)(rb + ch4 * 2);
                tt[k] = *(const unsigned short*)(rb + 512 + lane * 2);
                p[k]  = alph2[w][(i + k) * 5 + g];
            }
            #pragma unroll
            for (int k = 0; k < 8; k++) {
                acc0 += bf2f(q[k].x) * p[k].x;
                acc1 += bf2f(q[k].y) * p[k].x;
                acc2 += bf2f(q[k].z) * p[k].x;
                acc3 += bf2f(q[k].w) * p[k].x;
                accT += bf2f(tt[k]) * p[k].y;
            }
        }
        for (; i < deg; i++) {
            int off = __shfl(rowoff, i);
            const char* rb = hpB + off;
            ushort4 q0 = *(const ushort4*)(rb + ch4 * 2);
            unsigned short t0 = *(const unsigned short*)(rb + 512 + lane * 2);
            float2 p0 = alph2[w][i * 5 + g];
            acc0 += bf2f(q0.x) * p0.x;
            acc1 += bf2f(q0.y) * p0.x;
            acc2 += bf2f(q0.z) * p0.x;
            acc3 += bf2f(q0.w) * p0.x;
            accT += bf2f(t0) * p0.y;
        }
    } else {
        float mx[HEADS], inv[HEADS], sm[HEADS] = {};
        #pragma unroll
        for (int h = 0; h < HEADS; h++) mx[h] = -1e30f;
        for (int e = lane; e < deg; e += 64) {
            int s = myslot[e];
            #pragma unroll
            for (int h = 0; h < HEADS; h++)
                mx[h] = fmaxf(mx[h], lrelu(a_s[s * HEADS + h] + adh[h]));
        }
        #pragma unroll
        for (int h = 0; h < HEADS; h++)
            #pragma unroll
            for (int off = 32; off; off >>= 1)
                mx[h] = fmaxf(mx[h], __shfl_xor(mx[h], off));
        for (int e = lane; e < deg; e += 64) {
            int s = myslot[e];
            #pragma unroll
            for (int h = 0; h < HEADS; h++)
                sm[h] += __expf(lrelu(a_s[s * HEADS + h] + adh[h]) - mx[h]);
        }
        #pragma unroll
        for (int h = 0; h < HEADS; h++) {
            #pragma unroll
            for (int off = 32; off; off >>= 1)
                sm[h] += __shfl_xor(sm[h], off);
            inv[h] = 1.f / (sm[h] + 1e-16f);
        }
        for (int e = 0; e < deg; e++) {
            int s0 = myslot[e];
            const char* rb = hpB + s0 * 640;
            ushort4 q0 = *(const ushort4*)(rb + ch4 * 2);
            unsigned short t0 = *(const unsigned short*)(rb + 512 + lane * 2);
            float a0  = __expf(lrelu(a_s[s0 * HEADS + g] + adh[g]) - mx[g]) * inv[g];
            float a0t = __expf(lrelu(a_s[s0 * HEADS + 4] + adh[4]) - mx[4]) * inv[4];
            acc0 += bf2f(q0.x) * a0;
            acc1 += bf2f(q0.y) * a0;
            acc2 += bf2f(q0.z) * a0;
            acc3 += bf2f(q0.w) * a0;
            accT += bf2f(t0) * a0t;
        }
    }

    float v0 = acc0 + bias[ch4 + 0];
    float v1 = acc1 + bias[ch4 + 1];
    float v2 = acc2 + bias[ch4 + 2];
    float v3 = acc3 + bias[ch4 + 3];
    v0 = v0 > 0.f ? v0 : __expf(v0) - 1.f;
    v1 = v1 > 0.f ? v1 : __expf(v1) - 1.f;
    v2 = v2 > 0.f ? v2 : __expf(v2) - 1.f;
    v3 = v3 > 0.f ? v3 : __expf(v3) - 1.f;
    float vt = accT + bias[256 + lane];
    vt = vt > 0.f ? vt : __expf(vt) - 1.f;
    *(ushort4*)(out + (long)wid * 320 + ch4) =
        make_ushort4(f2bf(v0), f2bf(v1), f2bf(v2), f2bf(v3));
    out[(long)wid * 320 + 256 + lane] = f2bf(vt);
}

// ---------------------------------------------------------------------------
// Fused layer-2 GAT: 0.2 head-mean folded into alpha; fused bias +
// log_softmax; hp row stride 256; final rows to d_out. ELL slots.
__global__ __launch_bounds__(256) void aggr2_fused(
    const int* __restrict__ cnt, const unsigned short* __restrict__ slots,
    const float* __restrict__ a_s, const float* __restrict__ a_d,
    const unsigned short* __restrict__ hp, const float* __restrict__ bias,
    float* __restrict__ out)
{
    __shared__ float alph[4][320];   // [wave][edge*5 + h]
    int wid = (blockIdx.x * blockDim.x + threadIdx.x) >> 6;
    int w = threadIdx.x >> 6;
    int lane = threadIdx.x & 63;
    if (wid >= N_NODES) return;
    int deg = cnt[wid];
    if (deg > SLOTW) deg = SLOTW;
    const unsigned short* myslot = slots + wid * SLOTW;

    float adh[HEADS];
    #pragma unroll
    for (int h = 0; h < HEADS; h++) adh[h] = a_d[wid * HEADS + h];

    const bool act = lane < 50;
    const int ch4 = lane * 4;
    const int hq  = act ? lane / 10 : 0;
    const char* hpB = (const char*)hp;
    float acc0 = 0.f, acc1 = 0.f, acc2 = 0.f, acc3 = 0.f;

    if (deg <= 64) {
        bool has = lane < deg;
        int s = has ? (int)myslot[lane] : 0;
        int rowoff = s * 512;
        float v[HEADS], mx[HEADS], sm[HEADS];
        #pragma unroll
        for (int h = 0; h < HEADS; h++) {
            v[h] = has ? lrelu(a_s[s * HEADS + h] + adh[h]) : -1e30f;
            mx[h] = v[h];
        }
        #pragma unroll
        for (int h = 0; h < HEADS; h++)
            #pragma unroll
            for (int off = 32; off; off >>= 1)
                mx[h] = fmaxf(mx[h], __shfl_xor(mx[h], off));
        #pragma unroll
        for (int h = 0; h < HEADS; h++) {
            float e = has ? __expf(v[h] - mx[h]) : 0.f;
            v[h] = e;
            sm[h] = e;
        }
        #pragma unroll
        for (int h = 0; h < HEADS; h++)
            #pragma unroll
            for (int off = 32; off; off >>= 1)
                sm[h] += __shfl_xor(sm[h], off);
        if (has) {
            #pragma unroll
            for (int h = 0; h < HEADS; h++)
                alph[w][lane * 5 + h] = 0.2f * v[h] / (sm[h] + 1e-16f);
        }
        int i = 0;
        for (; i + 7 < deg; i += 8) {
            ushort4 q[8]; float a[8];
            #pragma unroll
            for (int k = 0; k < 8; k++) {
                int off = __shfl(rowoff, i + k);
                q[k] = act ? *(const ushort4*)(hpB + off + ch4 * 2)
                           : make_ushort4(0, 0, 0, 0);
                a[k] = alph[w][(i + k) * 5 + hq];
            }
            #pragma unroll
            for (int k = 0; k < 8; k++) {
                acc0 += bf2f(q[k].x) * a[k];
                acc1 += bf2f(q[k].y) * a[k];
                acc2 += bf2f(q[k].z) * a[k];
                acc3 += bf2f(q[k].w) * a[k];
            }
        }
        for (; i < deg; i++) {
            int off = __shfl(rowoff, i);
            if (act) {
                ushort4 q0 = *(const ushort4*)(hpB + off + ch4 * 2);
                float a0 = alph[w][i * 5 + hq];
                acc0 += bf2f(q0.x) * a0;
                acc1 += bf2f(q0.y) * a0;
                acc2 += bf2f(q0.z) * a0;
                acc3 += bf2f(q0.w) * a0;
            }
        }
    } else {
        float mx[HEADS], inv[HEADS], sm[HEADS] = {};
        #pragma unroll
        for (int h = 0; h < HEADS; h++) mx[h] = -1e30f;
        for (int e = lane; e < deg; e += 64) {
            int s = myslot[e];
            #pragma unroll
            for (int h = 0; h < HEADS; h++)
                mx[h] = fmaxf(mx[h], lrelu(a_s[s * HEADS + h] + adh[h]));
        }
        #pragma unroll
        for (int h = 0; h < HEADS; h++)
            #pragma unroll
            for (int off = 32; off; off >>= 1)
                mx[h] = fmaxf(mx[h], __shfl_xor(mx[h], off));
        for (int e = lane; e < deg; e += 64) {
            int s = myslot[e];
            #pragma unroll
            for (int h = 0; h < HEADS; h++)
                sm[h] += __expf(lrelu(a_s[s * HEADS + h] + adh[h]) - mx[h]);
        }
        #pragma unroll
        for (int h = 0; h < HEADS; h++) {
            #pragma unroll
            for (int off = 32; off; off >>= 1)
                sm[h] += __shfl_xor(sm[h], off);
            inv[h] = 0.2f / (sm[h] + 1e-16f);
        }
        for (int e = 0; e < deg; e++) {
            int s0 = myslot[e];
            if (act) {
                ushort4 q0 = *(const ushort4*)(hpB + s0 * 512 + ch4 * 2);
                float a0 = __expf(lrelu(a_s[s0 * HEADS + hq] + adh[hq]) - mx[hq]) * inv[hq];
                acc0 += bf2f(q0.x) * a0;
                acc1 += bf2f(q0.y) * a0;
                acc2 += bf2f(q0.z) * a0;
                acc3 += bf2f(q0.w) * a0;
            }
        }
    }

    float r0 = acc0, r1 = acc1, r2 = acc2, r3 = acc3;
    #pragma unroll
    for (int h5 = 1; h5 < 5; h5++) {
        int sl = (lane + 10 * h5) & 63;
        r0 += __shfl(acc0, sl);
        r1 += __shfl(acc1, sl);
        r2 += __shfl(acc2, sl);
        r3 += __shfl(acc3, sl);
    }

    float vb0 = -1e30f, vb1 = -1e30f, vb2 = -1e30f, vb3 = -1e30f;
    if (lane < 10) {
        vb0 = r0 + bias[ch4 + 0];
        vb1 = r1 + bias[ch4 + 1];
        vb2 = r2 + bias[ch4 + 2];
        vb3 = r3 + bias[ch4 + 3];
    }
    float mxv = fmaxf(fmaxf(vb0, vb1), fmaxf(vb2, vb3));
    #pragma unroll
    for (int off = 32; off; off >>= 1)
        mxv = fmaxf(mxv, __shfl_xor(mxv, off));
    float sme = 0.f;
    if (lane < 10)
        sme = __expf(vb0 - mxv) + __expf(vb1 - mxv) +
              __expf(vb2 - mxv) + __expf(vb3 - mxv);
    #pragma unroll
    for (int off = 32; off; off >>= 1)
        sme += __shfl_xor(sme, off);
    float ls = mxv + __logf(sme);
    if (lane < 10) {
        float4 o = make_float4(vb0 - ls, vb1 - ls, vb2 - ls, vb3 - ls);
        *(float4*)(out + (long)wid * CLS + ch4) = o;
    }
}

// ---------------------------------------------------------------------------
extern "C" void kernel_launch(void* const* d_in, const int* in_sizes, int n_in,
                              void* d_out, int out_size, void* d_ws, size_t ws_size,
                              hipStream_t stream)
{
    const float* x     = (const float*)d_in[0];
    const int*   ei    = (const int*)d_in[1];
    const float* emb_W = (const float*)d_in[2];
    const float* emb_b = (const float*)d_in[3];
    const float* W1    = (const float*)d_in[4];
    const float* as1   = (const float*)d_in[5];
    const float* ad1   = (const float*)d_in[6];
    const float* b1    = (const float*)d_in[7];
    const float* W2    = (const float*)d_in[8];
    const float* as2   = (const float*)d_in[9];
    const float* ad2   = (const float*)d_in[10];
    const float* b2    = (const float*)d_in[11];

    float* out_emb = (float*)d_out;                         // [N,64] f32
    float* out_cls = (float*)d_out + (size_t)N_NODES * HID; // [N,40] f32

    char* ws = (char*)d_ws;
    unsigned short* hp1b   = (unsigned short*)(ws);               // 32 MB [N,320]
    unsigned short* hp2b   = (unsigned short*)(ws);               // 25.6 MB [N,256] (reuse)
    unsigned short* h1b    = (unsigned short*)(ws + 32000000);    // 32 MB [N,320]
    unsigned short* embb   = (unsigned short*)(ws + 64000000);    // 6.4 MB [N,64]
    float*          a_s    = (float*)(ws + 70400000);             // 1 MB
    float*          a_d    = (float*)(ws + 71400000);             // 1 MB
    unsigned short* Bp0    = (unsigned short*)(ws + 72400000);    // 16 KB
    unsigned short* Bp1    = (unsigned short*)(ws + 72500000);    // 40 KB
    unsigned short* Bp2    = (unsigned short*)(ws + 72600000);    // 160 KB
    int*            cnt    = (int*)(ws + 73000000);               // 200 KB
    unsigned short* slots  = (unsigned short*)(ws + 73300000);    // 9.6 MB

    const dim3 blk(256);
    const int nhb = (N_NODES * HEADS + 255) / 256;
    const int eb  = (ETOT + 255) / 256;
    const int nb4 = (N_NODES + 3) / 4;
    const int mgrid = (N_NODES + 63) / 64;         // 782

    // ---- graph build (ELL slots) + weight packing, one kernel ----
    hipMemsetAsync(cnt, 0, (size_t)N_NODES * 4, stream);
    build_graph<<<eb, blk, 0, stream>>>(ei, cnt, slots, emb_W, W1, W2,
                                        Bp0, Bp1, Bp2);

    // ---- embedding (output 0 f32 + bf16 copy), reads f32 x directly ----
    gemm_mfma_emb<<<mgrid, blk, 0, stream>>>(x, Bp0, emb_b, out_emb, embb, N_NODES);

    // ---- layer 1 ----
    gemm_attn_l1<<<mgrid, blk, 0, stream>>>(embb, Bp1, as1, ad1,
                                            hp1b, a_s, a_d, N_NODES);
    aggr1_fused<<<nb4, blk, 0, stream>>>(cnt, slots, a_s, a_d, hp1b, b1, h1b);

    // ---- layer 2 ----
    gemm_mfma_l2<<<mgrid, blk, 0, stream>>>(h1b, Bp2, hp2b, N_NODES);
    attn_scores<<<nhb, blk, 0, stream>>>(hp2b, as2, ad2, a_s, a_d, N_NODES, 40, 256);
    aggr2_fused<<<nb4, blk, 0, stream>>>(cnt, slots, a_s, a_d, hp2b, b2, out_cls);
}

// Round 9
// 369.727 us; speedup vs baseline: 5.9731x; 1.1169x over previous
//
#include <hip/hip_runtime.h>
#include <math.h>

// Problem constants (from reference)
constexpr int N_NODES = 50000;
constexpr int E_EDGES = 800000;
constexpr int ETOT    = E_EDGES + N_NODES;   // self-loops appended
constexpr int IN_C    = 128;
constexpr int HID     = 64;
constexpr int HEADS   = 5;
constexpr int CLS     = 40;
constexpr int SLOTW   = 96;                  // ELL slot width (max deg ~45)
constexpr float NEG_SLOPE = 0.2f;

typedef __attribute__((ext_vector_type(8))) short short8;
typedef __attribute__((ext_vector_type(4))) float float4v;

__device__ __forceinline__ float lrelu(float v) {
    return v > 0.f ? v : NEG_SLOPE * v;
}
__device__ __forceinline__ float bf2f(unsigned short u) {
    return __uint_as_float(((unsigned)u) << 16);
}
__device__ __forceinline__ unsigned short f2bf(float f) {   // RNE
    unsigned u = __float_as_uint(f);
    return (unsigned short)((u + 0x7fffu + ((u >> 16) & 1u)) >> 16);
}

// ---------------------------------------------------------------------------
// Pack B [K x N] f32 into MFMA b-frag order, bf16 (one thread per 16B frag).
__device__ __forceinline__ void pack_one(const float* __restrict__ B,
                                         unsigned short* __restrict__ Bp,
                                         int N, int KS, int t)
{
    int lane = t & 63;
    int f = (t >> 6) & 3;
    int rest = t >> 8;
    int ks = rest % KS;
    int nt = rest / KS;
    int n = nt * 64 + f * 16 + (lane & 15);
    int kbase = ks * 32 + (lane >> 4) * 8;
    unsigned short vals[8];
    #pragma unroll
    for (int j = 0; j < 8; j++) {
        float v = (n < N) ? B[(long)(kbase + j) * N + n] : 0.f;
        vals[j] = f2bf(v);
    }
    *(ushort4*)(Bp + (long)t * 8)     = make_ushort4(vals[0], vals[1], vals[2], vals[3]);
    *(ushort4*)(Bp + (long)t * 8 + 4) = make_ushort4(vals[4], vals[5], vals[6], vals[7]);
}

// ---------------------------------------------------------------------------
// build_graph: ELL scatter + weight packing + score-vector precompute.
//   u1s[h*64+k]  = sum_c W1[k, h*64+c] * att1s[h,c]   (k<64)
//   u2s[h*320+k] = sum_c W2[k, h*40+c] * att2s[h,c]   (k<320)
__global__ void build_graph(const int* __restrict__ ei, int* __restrict__ cnt,
                            unsigned short* __restrict__ slots,
                            const float* __restrict__ W0, const float* __restrict__ W1,
                            const float* __restrict__ W2,
                            const float* __restrict__ att1s, const float* __restrict__ att1d,
                            const float* __restrict__ att2s, const float* __restrict__ att2d,
                            unsigned short* __restrict__ Bp0,
                            unsigned short* __restrict__ Bp1,
                            unsigned short* __restrict__ Bp2,
                            float* __restrict__ u1s, float* __restrict__ u1d,
                            float* __restrict__ u2s, float* __restrict__ u2d)
{
    int t = blockIdx.x * blockDim.x + threadIdx.x;
    if (t < 13824) {
        if (t < 1024)      pack_one(W0, Bp0, 64,  4,  t);           // emb_W 128x64
        else if (t < 3584) pack_one(W1, Bp1, 320, 2,  t - 1024);    // W1 64x320
        else               pack_one(W2, Bp2, 200, 10, t - 3584);    // W2 320x200
    } else if (t < 14464) {
        int i = t - 13824;                 // 0..639
        bool isd = i >= 320;
        int j = isd ? i - 320 : i;         // true mod-320 (NOT a bitmask!)
        int h = j >> 6, k = j & 63;
        const float* att = isd ? att1d : att1s;
        float sum = 0.f;
        for (int c = 0; c < 64; c++)
            sum += W1[k * 320 + h * 64 + c] * att[h * 64 + c];
        (isd ? u1d : u1s)[j] = sum;
    } else if (t < 17664) {
        int i = t - 14464;                 // 0..3199
        bool isd = i >= 1600;
        int j = isd ? i - 1600 : i;
        int h = j / 320, k = j % 320;
        const float* att = isd ? att2d : att2s;
        float sum = 0.f;
        for (int c = 0; c < 40; c++)
            sum += W2[k * 200 + h * 40 + c] * att[h * 40 + c];
        (isd ? u2d : u2s)[j] = sum;
    }
    if (t >= ETOT) return;
    int s, d;
    if (t < E_EDGES) { s = ei[t]; d = ei[E_EDGES + t]; }
    else             { s = d = t - E_EDGES; }
    int pos = atomicAdd(&cnt[d], 1);
    if (pos < SLOTW) slots[d * SLOTW + pos] = (unsigned short)s;
}

// ---------------------------------------------------------------------------
// Embedding GEMM: f32 A in, K=128, N=64; +bias; writes f32 (d_out) + bf16 copy
// + fused layer-1 attention scores (a_s1/a_d1 via u1 vectors).
__global__ __launch_bounds__(256) void gemm_mfma_emb(
    const float* __restrict__ A, const unsigned short* __restrict__ Bp,
    const float* __restrict__ bias,
    const float* __restrict__ u1s, const float* __restrict__ u1d,
    float* __restrict__ Cf, unsigned short* __restrict__ Cb,
    float* __restrict__ a_s1, float* __restrict__ a_d1, int M)
{
    const int K = 128, KS = 4;
    const int w = threadIdx.x >> 6, lane = threadIdx.x & 63;
    const int cl = lane & 15, kq = lane >> 4;
    int rowA = blockIdx.x * 64 + w * 16 + cl;
    if (rowA >= M) rowA = M - 1;
    const float* ap = A + (long)rowA * K + kq * 8;
    const unsigned short* bp = Bp + lane * 8;
    float4v acc[4] = {};
    #pragma unroll
    for (int ks = 0; ks < KS; ks++) {
        float4 u0 = *(const float4*)(ap + ks * 32);
        float4 u1 = *(const float4*)(ap + ks * 32 + 4);
        short8 a;
        a[0] = f2bf(u0.x); a[1] = f2bf(u0.y); a[2] = f2bf(u0.z); a[3] = f2bf(u0.w);
        a[4] = f2bf(u1.x); a[5] = f2bf(u1.y); a[6] = f2bf(u1.z); a[7] = f2bf(u1.w);
        #pragma unroll
        for (int f = 0; f < 4; f++) {
            short8 b = *(const short8*)(bp + ks * 2048 + f * 512);
            acc[f] = __builtin_amdgcn_mfma_f32_16x16x32_bf16(a, b, acc[f], 0, 0, 0);
        }
    }
    int rbase = blockIdx.x * 64 + w * 16 + kq * 4;
    float bc4[4];
    #pragma unroll
    for (int f = 0; f < 4; f++) {
        int col = f * 16 + cl;
        float bc = bias[col];
        bc4[f] = bc;
        #pragma unroll
        for (int r = 0; r < 4; r++) {
            int row = rbase + r;
            if (row < M) {
                float v = acc[f][r] + bc;
                Cf[(long)row * 64 + col] = v;
                Cb[(long)row * 64 + col] = f2bf(v);
            }
        }
    }
    // fused scores: a_s1[row,h] = dot(emb_row, u1s[h*64:...])
    #pragma unroll
    for (int h = 0; h < HEADS; h++) {
        float us[4], ud[4];
        #pragma unroll
        for (int f = 0; f < 4; f++) {
            us[f] = u1s[h * 64 + f * 16 + cl];
            ud[f] = u1d[h * 64 + f * 16 + cl];
        }
        #pragma unroll
        for (int r = 0; r < 4; r++) {
            float ps = 0.f, pd = 0.f;
            #pragma unroll
            for (int f = 0; f < 4; f++) {
                float v = acc[f][r] + bc4[f];
                ps += v * us[f];
                pd += v * ud[f];
            }
            #pragma unroll
            for (int off = 1; off < 16; off <<= 1) {
                ps += __shfl_xor(ps, off);
                pd += __shfl_xor(pd, off);
            }
            int row = rbase + r;
            if (cl == 0 && row < M) {
                a_s1[row * 5 + h] = ps;
                a_d1[row * 5 + h] = pd;
            }
        }
    }
}

// ---------------------------------------------------------------------------
// Layer-1 aggregation over PRE-PROJECTION features: gathers emb rows (128 B!)
// and produces e[n, h*64+k] = sum_s alpha_{s,h} emb[s,k]  (bf16 out).
// Wave per dst node; lane = channel k. 6.4 MB gather table.
__global__ __launch_bounds__(256) void aggr1_new(
    const int* __restrict__ cnt, const unsigned short* __restrict__ slots,
    const float* __restrict__ a_s, const float* __restrict__ a_d,
    const unsigned short* __restrict__ emb, unsigned short* __restrict__ e_out)
{
    __shared__ float alph[4][64 * 8];   // [wave][edge*8 + h] (padded for b128 align)
    int wid = (blockIdx.x * blockDim.x + threadIdx.x) >> 6;
    int w = threadIdx.x >> 6;
    int lane = threadIdx.x & 63;
    if (wid >= N_NODES) return;
    int deg = cnt[wid];
    if (deg > SLOTW) deg = SLOTW;
    const unsigned short* myslot = slots + wid * SLOTW;

    float adh[HEADS];
    #pragma unroll
    for (int h = 0; h < HEADS; h++) adh[h] = a_d[wid * HEADS + h];

    const char* embB = (const char*)emb;
    float acc[HEADS] = {};

    if (deg <= 64) {
        bool has = lane < deg;
        int s = has ? (int)myslot[lane] : 0;
        int rowoff = s * 128;            // byte offset of emb row
        float v[HEADS], mx[HEADS], sm[HEADS];
        #pragma unroll
        for (int h = 0; h < HEADS; h++) {
            v[h] = has ? lrelu(a_s[s * HEADS + h] + adh[h]) : -1e30f;
            mx[h] = v[h];
        }
        #pragma unroll
        for (int h = 0; h < HEADS; h++)
            #pragma unroll
            for (int off = 32; off; off >>= 1)
                mx[h] = fmaxf(mx[h], __shfl_xor(mx[h], off));
        #pragma unroll
        for (int h = 0; h < HEADS; h++) {
            float e = has ? __expf(v[h] - mx[h]) : 0.f;
            v[h] = e;
            sm[h] = e;
        }
        #pragma unroll
        for (int h = 0; h < HEADS; h++)
            #pragma unroll
            for (int off = 32; off; off >>= 1)
                sm[h] += __shfl_xor(sm[h], off);
        if (has) {
            #pragma unroll
            for (int h = 0; h < HEADS; h++)
                alph[w][lane * 8 + h] = v[h] / (sm[h] + 1e-16f);
        }
        // gather (wave-private LDS slice: no barrier), unroll x8
        int i = 0;
        for (; i + 7 < deg; i += 8) {
            float fv[8]; float4 a4[8]; float a1[8];
            #pragma unroll
            for (int k = 0; k < 8; k++) {
                int off = __shfl(rowoff, i + k);
                unsigned short q = *(const unsigned short*)(embB + off + lane * 2);
                fv[k] = bf2f(q);
                a4[k] = *(const float4*)&alph[w][(i + k) * 8];
                a1[k] = alph[w][(i + k) * 8 + 4];
            }
            #pragma unroll
            for (int k = 0; k < 8; k++) {
                acc[0] += fv[k] * a4[k].x;
                acc[1] += fv[k] * a4[k].y;
                acc[2] += fv[k] * a4[k].z;
                acc[3] += fv[k] * a4[k].w;
                acc[4] += fv[k] * a1[k];
            }
        }
        for (; i < deg; i++) {
            int off = __shfl(rowoff, i);
            float fv = bf2f(*(const unsigned short*)(embB + off + lane * 2));
            float4 a4 = *(const float4*)&alph[w][i * 8];
            float a1 = alph[w][i * 8 + 4];
            acc[0] += fv * a4.x;
            acc[1] += fv * a4.y;
            acc[2] += fv * a4.z;
            acc[3] += fv * a4.w;
            acc[4] += fv * a1;
        }
    } else {
        float mx[HEADS], inv[HEADS], sm[HEADS] = {};
        #pragma unroll
        for (int h = 0; h < HEADS; h++) mx[h] = -1e30f;
        for (int e = lane; e < deg; e += 64) {
            int s = myslot[e];
            #pragma unroll
            for (int h = 0; h < HEADS; h++)
                mx[h] = fmaxf(mx[h], lrelu(a_s[s * HEADS + h] + adh[h]));
        }
        #pragma unroll
        for (int h = 0; h < HEADS; h++)
            #pragma unroll
            for (int off = 32; off; off >>= 1)
                mx[h] = fmaxf(mx[h], __shfl_xor(mx[h], off));
        for (int e = lane; e < deg; e += 64) {
            int s = myslot[e];
            #pragma unroll
            for (int h = 0; h < HEADS; h++)
                sm[h] += __expf(lrelu(a_s[s * HEADS + h] + adh[h]) - mx[h]);
        }
        #pragma unroll
        for (int h = 0; h < HEADS; h++) {
            #pragma unroll
            for (int off = 32; off; off >>= 1)
                sm[h] += __shfl_xor(sm[h], off);
            inv[h] = 1.f / (sm[h] + 1e-16f);
        }
        for (int e = 0; e < deg; e++) {
            int s0 = myslot[e];
            float fv = bf2f(*(const unsigned short*)(embB + s0 * 128 + lane * 2));
            #pragma unroll
            for (int h = 0; h < HEADS; h++) {
                float a0 = __expf(lrelu(a_s[s0 * HEADS + h] + adh[h]) - mx[h]) * inv[h];
                acc[h] += fv * a0;
            }
        }
    }

    #pragma unroll
    for (int h = 0; h < HEADS; h++)
        e_out[(long)wid * 320 + h * 64 + lane] = f2bf(acc[h]);
}

// ---------------------------------------------------------------------------
// Head-mix GEMM: h1[n, h*64+c] = ELU( sum_k e[n,h*64+k] W1[k,h*64+c] + b1 )
// (block-diagonal, 5 heads) + fused layer-2 attention scores via u2 vectors.
__global__ __launch_bounds__(256) void gemm_mix1(
    const unsigned short* __restrict__ A, const unsigned short* __restrict__ Bp,
    const float* __restrict__ bias,
    const float* __restrict__ u2s, const float* __restrict__ u2d,
    unsigned short* __restrict__ C, float* __restrict__ a_s2,
    float* __restrict__ a_d2, int M)
{
    const int w = threadIdx.x >> 6, lane = threadIdx.x & 63;
    const int cl = lane & 15, kq = lane >> 4;
    int rowA = blockIdx.x * 64 + w * 16 + cl;
    if (rowA >= M) rowA = M - 1;
    const unsigned short* ap = A + (long)rowA * 320;
    const unsigned short* bp = Bp + lane * 8;
    float4v acc[20] = {};
    #pragma unroll
    for (int nt = 0; nt < 5; nt++)
        #pragma unroll
        for (int ks = 0; ks < 2; ks++) {
            short8 a = *(const short8*)(ap + nt * 64 + ks * 32 + kq * 8);
            #pragma unroll
            for (int f = 0; f < 4; f++) {
                short8 b = *(const short8*)(bp + (nt * 2 + ks) * 2048 + f * 512);
                acc[nt * 4 + f] =
                    __builtin_amdgcn_mfma_f32_16x16x32_bf16(a, b, acc[nt * 4 + f], 0, 0, 0);
            }
        }
    int rbase = blockIdx.x * 64 + w * 16 + kq * 4;
    // bias + ELU in place, store h1 (bf16)
    #pragma unroll
    for (int nt = 0; nt < 5; nt++)
        #pragma unroll
        for (int f = 0; f < 4; f++) {
            int col = nt * 64 + f * 16 + cl;
            float bc = bias[col];
            #pragma unroll
            for (int r = 0; r < 4; r++) {
                float v = acc[nt * 4 + f][r] + bc;
                v = v > 0.f ? v : __expf(v) - 1.f;
                acc[nt * 4 + f][r] = v;
                int row = rbase + r;
                if (row < M) C[(long)row * 320 + col] = f2bf(v);
            }
        }
    // fused layer-2 scores: a_s2[row,h] = dot(h1_row, u2s[h*320:...])
    #pragma unroll
    for (int h = 0; h < HEADS; h++) {
        float us[20], ud[20];
        #pragma unroll
        for (int nt = 0; nt < 5; nt++)
            #pragma unroll
            for (int f = 0; f < 4; f++) {
                us[nt * 4 + f] = u2s[h * 320 + nt * 64 + f * 16 + cl];
                ud[nt * 4 + f] = u2d[h * 320 + nt * 64 + f * 16 + cl];
            }
        #pragma unroll
        for (int r = 0; r < 4; r++) {
            float ps = 0.f, pd = 0.f;
            #pragma unroll
            for (int j = 0; j < 20; j++) {
                ps += acc[j][r] * us[j];
                pd += acc[j][r] * ud[j];
            }
            #pragma unroll
            for (int off = 1; off < 16; off <<= 1) {
                ps += __shfl_xor(ps, off);
                pd += __shfl_xor(pd, off);
            }
            int row = rbase + r;
            if (cl == 0 && row < M) {
                a_s2[row * 5 + h] = ps;
                a_d2[row * 5 + h] = pd;
            }
        }
    }
}

// ---------------------------------------------------------------------------
// Layer-2 GEMM: K=320, all 4 col-tiles per block; compact ldC=200.
__global__ __launch_bounds__(256) void gemm_mfma_l2(
    const unsigned short* __restrict__ A, const unsigned short* __restrict__ Bp,
    unsigned short* __restrict__ C, int M)
{
    const int K = 320, KS = 10;
    const int w = threadIdx.x >> 6, lane = threadIdx.x & 63;
    const int cl = lane & 15, kq = lane >> 4;
    int rowA = blockIdx.x * 64 + w * 16 + cl;
    if (rowA >= M) rowA = M - 1;
    const unsigned short* ap = A + (long)rowA * K + kq * 8;
    const unsigned short* bp = Bp + lane * 8;
    float4v acc[16] = {};
    for (int ks = 0; ks < KS; ks++) {
        short8 a = *(const short8*)(ap + ks * 32);
        #pragma unroll
        for (int nt = 0; nt < 4; nt++)
            #pragma unroll
            for (int f = 0; f < 4; f++) {
                short8 b = *(const short8*)(bp + (nt * KS + ks) * 2048 + f * 512);
                acc[nt * 4 + f] =
                    __builtin_amdgcn_mfma_f32_16x16x32_bf16(a, b, acc[nt * 4 + f], 0, 0, 0);
            }
    }
    int rbase = blockIdx.x * 64 + w * 16 + kq * 4;
    #pragma unroll
    for (int nt = 0; nt < 4; nt++)
        #pragma unroll
        for (int f = 0; f < 4; f++) {
            int col = nt * 64 + f * 16 + cl;
            if (col >= 200) continue;
            #pragma unroll
            for (int r = 0; r < 4; r++) {
                int row = rbase + r;
                if (row < M) C[(long)row * 200 + col] = f2bf(acc[nt * 4 + f][r]);
            }
        }
}

// ---------------------------------------------------------------------------
// Fused layer-2 GAT: 0.2 head-mean folded into alpha; fused bias +
// log_softmax; hp row stride 200 (400 B); final rows to d_out. ELL slots.
__global__ __launch_bounds__(256) void aggr2_fused(
    const int* __restrict__ cnt, const unsigned short* __restrict__ slots,
    const float* __restrict__ a_s, const float* __restrict__ a_d,
    const unsigned short* __restrict__ hp, const float* __restrict__ bias,
    float* __restrict__ out)
{
    __shared__ float alph[4][320];   // [wave][edge*5 + h]
    int wid = (blockIdx.x * blockDim.x + threadIdx.x) >> 6;
    int w = threadIdx.x >> 6;
    int lane = threadIdx.x & 63;
    if (wid >= N_NODES) return;
    int deg = cnt[wid];
    if (deg > SLOTW) deg = SLOTW;
    const unsigned short* myslot = slots + wid * SLOTW;

    float adh[HEADS];
    #pragma unroll
    for (int h = 0; h < HEADS; h++) adh[h] = a_d[wid * HEADS + h];

    const bool act = lane < 50;
    const int ch4 = lane * 4;
    const int hq  = act ? lane / 10 : 0;
    const char* hpB = (const char*)hp;
    float acc0 = 0.f, acc1 = 0.f, acc2 = 0.f, acc3 = 0.f;

    if (deg <= 64) {
        bool has = lane < deg;
        int s = has ? (int)myslot[lane] : 0;
        int rowoff = s * 400;
        float v[HEADS], mx[HEADS], sm[HEADS];
        #pragma unroll
        for (int h = 0; h < HEADS; h++) {
            v[h] = has ? lrelu(a_s[s * HEADS + h] + adh[h]) : -1e30f;
            mx[h] = v[h];
        }
        #pragma unroll
        for (int h = 0; h < HEADS; h++)
            #pragma unroll
            for (int off = 32; off; off >>= 1)
                mx[h] = fmaxf(mx[h], __shfl_xor(mx[h], off));
        #pragma unroll
        for (int h = 0; h < HEADS; h++) {
            float e = has ? __expf(v[h] - mx[h]) : 0.f;
            v[h] = e;
            sm[h] = e;
        }
        #pragma unroll
        for (int h = 0; h < HEADS; h++)
            #pragma unroll
            for (int off = 32; off; off >>= 1)
                sm[h] += __shfl_xor(sm[h], off);
        if (has) {
            #pragma unroll
            for (int h = 0; h < HEADS; h++)
                alph[w][lane * 5 + h] = 0.2f * v[h] / (sm[h] + 1e-16f);
        }
        int i = 0;
        for (; i + 7 < deg; i += 8) {
            ushort4 q[8]; float a[8];
            #pragma unroll
            for (int k = 0; k < 8; k++) {
                int off = __shfl(rowoff, i + k);
                q[k] = act ? *(const ushort4*)(hpB + off + ch4 * 2)
                           : make_ushort4(0, 0, 0, 0);
                a[k] = alph[w][(i + k) * 5 + hq];
            }
            #pragma unroll
            for (int k = 0; k < 8; k++) {
                acc0 += bf2f(q[k].x) * a[k];
                acc1 += bf2f(q[k].y) * a[k];
                acc2 += bf2f(q[k].z) * a[k];
                acc3 += bf2f(q[k].w) * a[k];
            }
        }
        for (; i < deg; i++) {
            int off = __shfl(rowoff, i);
            if (act) {
                ushort4 q0 = *(const ushort4*)(hpB + off + ch4 * 2);
                float a0 = alph[w][i * 5 + hq];
                acc0 += bf2f(q0.x) * a0;
                acc1 += bf2f(q0.y) * a0;
                acc2 += bf2f(q0.z) * a0;
                acc3 += bf2f(q0.w) * a0;
            }
        }
    } else {
        float mx[HEADS], inv[HEADS], sm[HEADS] = {};
        #pragma unroll
        for (int h = 0; h < HEADS; h++) mx[h] = -1e30f;
        for (int e = lane; e < deg; e += 64) {
            int s = myslot[e];
            #pragma unroll
            for (int h = 0; h < HEADS; h++)
                mx[h] = fmaxf(mx[h], lrelu(a_s[s * HEADS + h] + adh[h]));
        }
        #pragma unroll
        for (int h = 0; h < HEADS; h++)
            #pragma unroll
            for (int off = 32; off; off >>= 1)
                mx[h] = fmaxf(mx[h], __shfl_xor(mx[h], off));
        for (int e = lane; e < deg; e += 64) {
            int s = myslot[e];
            #pragma unroll
            for (int h = 0; h < HEADS; h++)
                sm[h] += __expf(lrelu(a_s[s * HEADS + h] + adh[h]) - mx[h]);
        }
        #pragma unroll
        for (int h = 0; h < HEADS; h++) {
            #pragma unroll
            for (int off = 32; off; off >>= 1)
                sm[h] += __shfl_xor(sm[h], off);
            inv[h] = 0.2f / (sm[h] + 1e-16f);
        }
        for (int e = 0; e < deg; e++) {
            int s0 = myslot[e];
            if (act) {
                ushort4 q0 = *(const ushort4*)(hpB + s0 * 400 + ch4 * 2);
                float a0 = __expf(lrelu(a_s[s0 * HEADS + hq] + adh[hq]) - mx[hq]) * inv[hq];
                acc0 += bf2f(q0.x) * a0;
                acc1 += bf2f(q0.y) * a0;
                acc2 += bf2f(q0.z) * a0;
                acc3 += bf2f(q0.w) * a0;
            }
        }
    }

    float r0 = acc0, r1 = acc1, r2 = acc2, r3 = acc3;
    #pragma unroll
    for (int h5 = 1; h5 < 5; h5++) {
        int sl = (lane + 10 * h5) & 63;
        r0 += __shfl(acc0, sl);
        r1 += __shfl(acc1, sl);
        r2 += __shfl(acc2, sl);
        r3 += __shfl(acc3, sl);
    }

    float vb0 = -1e30f, vb1 = -1e30f, vb2 = -1e30f, vb3 = -1e30f;
    if (lane < 10) {
        vb0 = r0 + bias[ch4 + 0];
        vb1 = r1 + bias[ch4 + 1];
        vb2 = r2 + bias[ch4 + 2];
        vb3 = r3 + bias[ch4 + 3];
    }
    float mxv = fmaxf(fmaxf(vb0, vb1), fmaxf(vb2, vb3));
    #pragma unroll
    for (int off = 32; off; off >>= 1)
        mxv = fmaxf(mxv, __shfl_xor(mxv, off));
    float sme = 0.f;
    if (lane < 10)
        sme = __expf(vb0 - mxv) + __expf(vb1 - mxv) +
              __expf(vb2 - mxv) + __expf(vb3 - mxv);
    #pragma unroll
    for (int off = 32; off; off >>= 1)
        sme += __shfl_xor(sme, off);
    float ls = mxv + __logf(sme);
    if (lane < 10) {
        float4 o = make_float4(vb0 - ls, vb1 - ls, vb2 - ls, vb3 - ls);
        *(float4*)(out + (long)wid * CLS + ch4) = o;
    }
}

// ---------------------------------------------------------------------------
extern "C" void kernel_launch(void* const* d_in, const int* in_sizes, int n_in,
                              void* d_out, int out_size, void* d_ws, size_t ws_size,
                              hipStream_t stream)
{
    const float* x     = (const float*)d_in[0];
    const int*   ei    = (const int*)d_in[1];
    const float* emb_W = (const float*)d_in[2];
    const float* emb_b = (const float*)d_in[3];
    const float* W1    = (const float*)d_in[4];
    const float* as1   = (const float*)d_in[5];
    const float* ad1   = (const float*)d_in[6];
    const float* b1    = (const float*)d_in[7];
    const float* W2    = (const float*)d_in[8];
    const float* as2   = (const float*)d_in[9];
    const float* ad2   = (const float*)d_in[10];
    const float* b2    = (const float*)d_in[11];

    float* out_emb = (float*)d_out;                         // [N,64] f32
    float* out_cls = (float*)d_out + (size_t)N_NODES * HID; // [N,40] f32

    char* ws = (char*)d_ws;
    unsigned short* e_agg  = (unsigned short*)(ws);               // 32 MB [N,320]
    unsigned short* hp2b   = (unsigned short*)(ws);               // 20 MB [N,200] (reuse)
    unsigned short* h1b    = (unsigned short*)(ws + 32000000);    // 32 MB [N,320]
    unsigned short* embb   = (unsigned short*)(ws + 64000000);    // 6.4 MB [N,64]
    float*          a_s1   = (float*)(ws + 70400000);             // 1 MB
    float*          a_d1   = (float*)(ws + 71400000);             // 1 MB
    float*          a_s2   = (float*)(ws + 72400000);             // 1 MB
    float*          a_d2   = (float*)(ws + 73400000);             // 1 MB
    unsigned short* Bp0    = (unsigned short*)(ws + 74400000);    // 16 KB
    unsigned short* Bp1    = (unsigned short*)(ws + 74500000);    // 40 KB
    unsigned short* Bp2    = (unsigned short*)(ws + 74600000);    // 160 KB
    float*          u1s    = (float*)(ws + 74800000);             // 1.3 KB
    float*          u1d    = (float*)(ws + 74810000);
    float*          u2s    = (float*)(ws + 74820000);             // 6.4 KB
    float*          u2d    = (float*)(ws + 74830000);
    int*            cnt    = (int*)(ws + 74840000);               // 200 KB
    unsigned short* slots  = (unsigned short*)(ws + 75100000);    // 9.6 MB

    const dim3 blk(256);
    const int eb  = (ETOT + 255) / 256;
    const int nb4 = (N_NODES + 3) / 4;
    const int mgrid = (N_NODES + 63) / 64;         // 782

    // ---- graph build (ELL) + weight packing + u-vector precompute ----
    hipMemsetAsync(cnt, 0, (size_t)N_NODES * 4, stream);
    build_graph<<<eb, blk, 0, stream>>>(ei, cnt, slots, emb_W, W1, W2,
                                        as1, ad1, as2, ad2,
                                        Bp0, Bp1, Bp2, u1s, u1d, u2s, u2d);

    // ---- embedding (output 0 f32 + bf16 copy) + layer-1 scores ----
    gemm_mfma_emb<<<mgrid, blk, 0, stream>>>(x, Bp0, emb_b, u1s, u1d,
                                             out_emb, embb, a_s1, a_d1, N_NODES);

    // ---- layer 1: aggregate pre-projection emb, then head-mix GEMM ----
    aggr1_new<<<nb4, blk, 0, stream>>>(cnt, slots, a_s1, a_d1, embb, e_agg);
    gemm_mix1<<<mgrid, blk, 0, stream>>>(e_agg, Bp1, b1, u2s, u2d,
                                         h1b, a_s2, a_d2, N_NODES);

    // ---- layer 2 ----
    gemm_mfma_l2<<<mgrid, blk, 0, stream>>>(h1b, Bp2, hp2b, N_NODES);
    aggr2_fused<<<nb4, blk, 0, stream>>>(cnt, slots, a_s2, a_d2, hp2b, b2, out_cls);
}

// Round 11
// 368.540 us; speedup vs baseline: 5.9924x; 1.0032x over previous
//
#include <hip/hip_runtime.h>
#include <math.h>

// Problem constants (from reference)
constexpr int N_NODES = 50000;
constexpr int E_EDGES = 800000;
constexpr int ETOT    = E_EDGES + N_NODES;   // self-loops appended
constexpr int IN_C    = 128;
constexpr int HID     = 64;
constexpr int HEADS   = 5;
constexpr int CLS     = 40;
constexpr int SLOTW   = 96;                  // ELL slot width (max deg ~45)
constexpr float NEG_SLOPE = 0.2f;

typedef __attribute__((ext_vector_type(8))) short short8;
typedef __attribute__((ext_vector_type(4))) float float4v;

__device__ __forceinline__ float lrelu(float v) {
    return v > 0.f ? v : NEG_SLOPE * v;
}
__device__ __forceinline__ float bf2f(unsigned short u) {
    return __uint_as_float(((unsigned)u) << 16);
}
__device__ __forceinline__ unsigned short f2bf(float f) {   // RNE
    unsigned u = __float_as_uint(f);
    return (unsigned short)((u + 0x7fffu + ((u >> 16) & 1u)) >> 16);
}

// ---------------------------------------------------------------------------
// Pack B [K x N] f32 into MFMA b-frag order, bf16 (one thread per 16B frag).
__device__ __forceinline__ void pack_one(const float* __restrict__ B,
                                         unsigned short* __restrict__ Bp,
                                         int N, int KS, int t)
{
    int lane = t & 63;
    int f = (t >> 6) & 3;
    int rest = t >> 8;
    int ks = rest % KS;
    int nt = rest / KS;
    int n = nt * 64 + f * 16 + (lane & 15);
    int kbase = ks * 32 + (lane >> 4) * 8;
    unsigned short vals[8];
    #pragma unroll
    for (int j = 0; j < 8; j++) {
        float v = (n < N) ? B[(long)(kbase + j) * N + n] : 0.f;
        vals[j] = f2bf(v);
    }
    *(ushort4*)(Bp + (long)t * 8)     = make_ushort4(vals[0], vals[1], vals[2], vals[3]);
    *(ushort4*)(Bp + (long)t * 8 + 4) = make_ushort4(vals[4], vals[5], vals[6], vals[7]);
}

// ---------------------------------------------------------------------------
// build_graph: ELL scatter + weight packing + score-vector precompute.
//   u1s[h*64+k]  = sum_c W1[k, h*64+c] * att1s[h,c]   (k<64)
//   u2s[h*320+k] = sum_c W2[k, h*40+c] * att2s[h,c]   (k<320)
__global__ void build_graph(const int* __restrict__ ei, int* __restrict__ cnt,
                            unsigned short* __restrict__ slots,
                            const float* __restrict__ W0, const float* __restrict__ W1,
                            const float* __restrict__ W2,
                            const float* __restrict__ att1s, const float* __restrict__ att1d,
                            const float* __restrict__ att2s, const float* __restrict__ att2d,
                            unsigned short* __restrict__ Bp0,
                            unsigned short* __restrict__ Bp1,
                            unsigned short* __restrict__ Bp2,
                            float* __restrict__ u1s, float* __restrict__ u1d,
                            float* __restrict__ u2s, float* __restrict__ u2d)
{
    int t = blockIdx.x * blockDim.x + threadIdx.x;
    if (t < 13824) {
        if (t < 1024)      pack_one(W0, Bp0, 64,  4,  t);           // emb_W 128x64
        else if (t < 3584) pack_one(W1, Bp1, 320, 2,  t - 1024);    // W1 64x320
        else               pack_one(W2, Bp2, 200, 10, t - 3584);    // W2 320x200
    } else if (t < 14464) {
        int i = t - 13824;                 // 0..639
        bool isd = i >= 320;
        int j = isd ? i - 320 : i;         // true mod-320 (NOT a bitmask!)
        int h = j >> 6, k = j & 63;
        const float* att = isd ? att1d : att1s;
        float sum = 0.f;
        for (int c = 0; c < 64; c++)
            sum += W1[k * 320 + h * 64 + c] * att[h * 64 + c];
        (isd ? u1d : u1s)[j] = sum;
    } else if (t < 17664) {
        int i = t - 14464;                 // 0..3199
        bool isd = i >= 1600;
        int j = isd ? i - 1600 : i;
        int h = j / 320, k = j % 320;
        const float* att = isd ? att2d : att2s;
        float sum = 0.f;
        for (int c = 0; c < 40; c++)
            sum += W2[k * 200 + h * 40 + c] * att[h * 40 + c];
        (isd ? u2d : u2s)[j] = sum;
    }
    if (t >= ETOT) return;
    int s, d;
    if (t < E_EDGES) { s = ei[t]; d = ei[E_EDGES + t]; }
    else             { s = d = t - E_EDGES; }
    int pos = atomicAdd(&cnt[d], 1);
    if (pos < SLOTW) slots[d * SLOTW + pos] = (unsigned short)s;
}

// ---------------------------------------------------------------------------
// Embedding GEMM: f32 A in, K=128, N=64; +bias; writes f32 (d_out) + bf16 copy
// + fused layer-1 attention scores (a_s1/a_d1 via u1 vectors).
__global__ __launch_bounds__(256) void gemm_mfma_emb(
    const float* __restrict__ A, const unsigned short* __restrict__ Bp,
    const float* __restrict__ bias,
    const float* __restrict__ u1s, const float* __restrict__ u1d,
    float* __restrict__ Cf, unsigned short* __restrict__ Cb,
    float* __restrict__ a_s1, float* __restrict__ a_d1, int M)
{
    const int K = 128, KS = 4;
    const int w = threadIdx.x >> 6, lane = threadIdx.x & 63;
    const int cl = lane & 15, kq = lane >> 4;
    int rowA = blockIdx.x * 64 + w * 16 + cl;
    if (rowA >= M) rowA = M - 1;
    const float* ap = A + (long)rowA * K + kq * 8;
    const unsigned short* bp = Bp + lane * 8;
    float4v acc[4] = {};
    #pragma unroll
    for (int ks = 0; ks < KS; ks++) {
        float4 u0 = *(const float4*)(ap + ks * 32);
        float4 u1 = *(const float4*)(ap + ks * 32 + 4);
        short8 a;
        a[0] = f2bf(u0.x); a[1] = f2bf(u0.y); a[2] = f2bf(u0.z); a[3] = f2bf(u0.w);
        a[4] = f2bf(u1.x); a[5] = f2bf(u1.y); a[6] = f2bf(u1.z); a[7] = f2bf(u1.w);
        #pragma unroll
        for (int f = 0; f < 4; f++) {
            short8 b = *(const short8*)(bp + ks * 2048 + f * 512);
            acc[f] = __builtin_amdgcn_mfma_f32_16x16x32_bf16(a, b, acc[f], 0, 0, 0);
        }
    }
    int rbase = blockIdx.x * 64 + w * 16 + kq * 4;
    float bc4[4];
    #pragma unroll
    for (int f = 0; f < 4; f++) {
        int col = f * 16 + cl;
        float bc = bias[col];
        bc4[f] = bc;
        #pragma unroll
        for (int r = 0; r < 4; r++) {
            int row = rbase + r;
            if (row < M) {
                float v = acc[f][r] + bc;
                Cf[(long)row * 64 + col] = v;
                Cb[(long)row * 64 + col] = f2bf(v);
            }
        }
    }
    // fused scores: a_s1[row,h] = dot(emb_row, u1s[h*64:...])
    #pragma unroll
    for (int h = 0; h < HEADS; h++) {
        float us[4], ud[4];
        #pragma unroll
        for (int f = 0; f < 4; f++) {
            us[f] = u1s[h * 64 + f * 16 + cl];
            ud[f] = u1d[h * 64 + f * 16 + cl];
        }
        #pragma unroll
        for (int r = 0; r < 4; r++) {
            float ps = 0.f, pd = 0.f;
            #pragma unroll
            for (int f = 0; f < 4; f++) {
                float v = acc[f][r] + bc4[f];
                ps += v * us[f];
                pd += v * ud[f];
            }
            #pragma unroll
            for (int off = 1; off < 16; off <<= 1) {
                ps += __shfl_xor(ps, off);
                pd += __shfl_xor(pd, off);
            }
            int row = rbase + r;
            if (cl == 0 && row < M) {
                a_s1[row * 5 + h] = ps;
                a_d1[row * 5 + h] = pd;
            }
        }
    }
}

// ---------------------------------------------------------------------------
// Layer-1 aggregation over PRE-PROJECTION features: gathers emb rows (128 B)
// and produces e[n, h*64+k] = sum_s alpha_{s,h} emb[s,k]  (bf16 out).
__global__ __launch_bounds__(256) void aggr1_new(
    const int* __restrict__ cnt, const unsigned short* __restrict__ slots,
    const float* __restrict__ a_s, const float* __restrict__ a_d,
    const unsigned short* __restrict__ emb, unsigned short* __restrict__ e_out)
{
    __shared__ float alph[4][64 * 8];   // [wave][edge*8 + h] (padded for b128 align)
    int wid = (blockIdx.x * blockDim.x + threadIdx.x) >> 6;
    int w = threadIdx.x >> 6;
    int lane = threadIdx.x & 63;
    if (wid >= N_NODES) return;
    int deg = cnt[wid];
    if (deg > SLOTW) deg = SLOTW;
    const unsigned short* myslot = slots + wid * SLOTW;

    float adh[HEADS];
    #pragma unroll
    for (int h = 0; h < HEADS; h++) adh[h] = a_d[wid * HEADS + h];

    const char* embB = (const char*)emb;
    float acc[HEADS] = {};

    if (deg <= 64) {
        bool has = lane < deg;
        int s = has ? (int)myslot[lane] : 0;
        int rowoff = s * 128;            // byte offset of emb row
        float v[HEADS], mx[HEADS], sm[HEADS];
        #pragma unroll
        for (int h = 0; h < HEADS; h++) {
            v[h] = has ? lrelu(a_s[s * HEADS + h] + adh[h]) : -1e30f;
            mx[h] = v[h];
        }
        #pragma unroll
        for (int h = 0; h < HEADS; h++)
            #pragma unroll
            for (int off = 32; off; off >>= 1)
                mx[h] = fmaxf(mx[h], __shfl_xor(mx[h], off));
        #pragma unroll
        for (int h = 0; h < HEADS; h++) {
            float e = has ? __expf(v[h] - mx[h]) : 0.f;
            v[h] = e;
            sm[h] = e;
        }
        #pragma unroll
        for (int h = 0; h < HEADS; h++)
            #pragma unroll
            for (int off = 32; off; off >>= 1)
                sm[h] += __shfl_xor(sm[h], off);
        if (has) {
            #pragma unroll
            for (int h = 0; h < HEADS; h++)
                alph[w][lane * 8 + h] = v[h] / (sm[h] + 1e-16f);
        }
        // gather (wave-private LDS slice: no barrier), unroll x8
        int i = 0;
        for (; i + 7 < deg; i += 8) {
            float fv[8]; float4 a4[8]; float a1[8];
            #pragma unroll
            for (int k = 0; k < 8; k++) {
                int off = __shfl(rowoff, i + k);
                unsigned short q = *(const unsigned short*)(embB + off + lane * 2);
                fv[k] = bf2f(q);
                a4[k] = *(const float4*)&alph[w][(i + k) * 8];
                a1[k] = alph[w][(i + k) * 8 + 4];
            }
            #pragma unroll
            for (int k = 0; k < 8; k++) {
                acc[0] += fv[k] * a4[k].x;
                acc[1] += fv[k] * a4[k].y;
                acc[2] += fv[k] * a4[k].z;
                acc[3] += fv[k] * a4[k].w;
                acc[4] += fv[k] * a1[k];
            }
        }
        for (; i < deg; i++) {
            int off = __shfl(rowoff, i);
            float fv = bf2f(*(const unsigned short*)(embB + off + lane * 2));
            float4 a4 = *(const float4*)&alph[w][i * 8];
            float a1 = alph[w][i * 8 + 4];
            acc[0] += fv * a4.x;
            acc[1] += fv * a4.y;
            acc[2] += fv * a4.z;
            acc[3] += fv * a4.w;
            acc[4] += fv * a1;
        }
    } else {
        float mx[HEADS], inv[HEADS], sm[HEADS] = {};
        #pragma unroll
        for (int h = 0; h < HEADS; h++) mx[h] = -1e30f;
        for (int e = lane; e < deg; e += 64) {
            int s = myslot[e];
            #pragma unroll
            for (int h = 0; h < HEADS; h++)
                mx[h] = fmaxf(mx[h], lrelu(a_s[s * HEADS + h] + adh[h]));
        }
        #pragma unroll
        for (int h = 0; h < HEADS; h++)
            #pragma unroll
            for (int off = 32; off; off >>= 1)
                mx[h] = fmaxf(mx[h], __shfl_xor(mx[h], off));
        for (int e = lane; e < deg; e += 64) {
            int s = myslot[e];
            #pragma unroll
            for (int h = 0; h < HEADS; h++)
                sm[h] += __expf(lrelu(a_s[s * HEADS + h] + adh[h]) - mx[h]);
        }
        #pragma unroll
        for (int h = 0; h < HEADS; h++) {
            #pragma unroll
            for (int off = 32; off; off >>= 1)
                sm[h] += __shfl_xor(sm[h], off);
            inv[h] = 1.f / (sm[h] + 1e-16f);
        }
        for (int e = 0; e < deg; e++) {
            int s0 = myslot[e];
            float fv = bf2f(*(const unsigned short*)(embB + s0 * 128 + lane * 2));
            #pragma unroll
            for (int h = 0; h < HEADS; h++) {
                float a0 = __expf(lrelu(a_s[s0 * HEADS + h] + adh[h]) - mx[h]) * inv[h];
                acc[h] += fv * a0;
            }
        }
    }

    #pragma unroll
    for (int h = 0; h < HEADS; h++)
        e_out[(long)wid * 320 + h * 64 + lane] = f2bf(acc[h]);
}

// ---------------------------------------------------------------------------
// FUSED mix + layer-2 GEMM. Phase 1 (mix): h1[n,h*64+c] = ELU(e@W1_h + b1),
// kept in registers; written to a wave-private LDS band (stride 328 to avoid
// 16-way bank conflicts) — no barrier needed (same wave writes & reads; DS ops
// from one wave execute in program order). Epilogue-1: layer-2 scores via u2
// vectors. Phase 2: hp2 = h1 @ W2 (K=320), compact ldC=200.
__global__ __launch_bounds__(256) void gemm_mix_l2(
    const unsigned short* __restrict__ A, const unsigned short* __restrict__ Bp1,
    const unsigned short* __restrict__ Bp2, const float* __restrict__ bias,
    const float* __restrict__ u2s, const float* __restrict__ u2d,
    unsigned short* __restrict__ hp2, float* __restrict__ a_s2,
    float* __restrict__ a_d2, int M)
{
    constexpr int LDP = 328;               // padded row stride (ushorts)
    __shared__ unsigned short tile[64 * LDP];   // 41 KB
    const int w = threadIdx.x >> 6, lane = threadIdx.x & 63;
    const int cl = lane & 15, kq = lane >> 4;
    int rowA = blockIdx.x * 64 + w * 16 + cl;
    if (rowA >= M) rowA = M - 1;
    const unsigned short* ap = A + (long)rowA * 320;
    const unsigned short* bp1 = Bp1 + lane * 8;

    // ---- phase 1: block-diagonal mix GEMM (K=64 per head) ----
    float4v acc[20] = {};
    #pragma unroll
    for (int nt = 0; nt < 5; nt++)
        #pragma unroll
        for (int ks = 0; ks < 2; ks++) {
            short8 a = *(const short8*)(ap + nt * 64 + ks * 32 + kq * 8);
            #pragma unroll
            for (int f = 0; f < 4; f++) {
                short8 b = *(const short8*)(bp1 + (nt * 2 + ks) * 2048 + f * 512);
                acc[nt * 4 + f] =
                    __builtin_amdgcn_mfma_f32_16x16x32_bf16(a, b, acc[nt * 4 + f], 0, 0, 0);
            }
        }
    int rbase = blockIdx.x * 64 + w * 16 + kq * 4;
    const int lrow = w * 16 + kq * 4;      // local row base of this lane's C rows
    // bias + ELU, stash h1 tile in LDS (own wave's band only)
    #pragma unroll
    for (int nt = 0; nt < 5; nt++)
        #pragma unroll
        for (int f = 0; f < 4; f++) {
            int col = nt * 64 + f * 16 + cl;
            float bc = bias[col];
            #pragma unroll
            for (int r = 0; r < 4; r++) {
                float v = acc[nt * 4 + f][r] + bc;
                v = v > 0.f ? v : __expf(v) - 1.f;
                acc[nt * 4 + f][r] = v;
                tile[(lrow + r) * LDP + col] = f2bf(v);
            }
        }
    // epilogue-1: layer-2 scores a_s2[row,h] = dot(h1_row, u2s[h*320:...])
    #pragma unroll
    for (int h = 0; h < HEADS; h++) {
        float us[20], ud[20];
        #pragma unroll
        for (int nt = 0; nt < 5; nt++)
            #pragma unroll
            for (int f = 0; f < 4; f++) {
                us[nt * 4 + f] = u2s[h * 320 + nt * 64 + f * 16 + cl];
                ud[nt * 4 + f] = u2d[h * 320 + nt * 64 + f * 16 + cl];
            }
        #pragma unroll
        for (int r = 0; r < 4; r++) {
            float ps = 0.f, pd = 0.f;
            #pragma unroll
            for (int j = 0; j < 20; j++) {
                ps += acc[j][r] * us[j];
                pd += acc[j][r] * ud[j];
            }
            #pragma unroll
            for (int off = 1; off < 16; off <<= 1) {
                ps += __shfl_xor(ps, off);
                pd += __shfl_xor(pd, off);
            }
            int row = rbase + r;
            if (cl == 0 && row < M) {
                a_s2[row * 5 + h] = ps;
                a_d2[row * 5 + h] = pd;
            }
        }
    }

    // ---- phase 2: hp2 = h1 @ W2, K=320 (A-frags from own wave's LDS band) ----
    const unsigned short* bp2 = Bp2 + lane * 8;
    const unsigned short* arow = tile + (w * 16 + cl) * LDP;  // A row m = cl
    float4v acc2[16] = {};
    #pragma unroll
    for (int ks = 0; ks < 10; ks++) {
        short8 a2 = *(const short8*)(arow + ks * 32 + kq * 8);
        #pragma unroll
        for (int nt = 0; nt < 4; nt++)
            #pragma unroll
            for (int f = 0; f < 4; f++) {
                short8 b = *(const short8*)(bp2 + (nt * 10 + ks) * 2048 + f * 512);
                acc2[nt * 4 + f] =
                    __builtin_amdgcn_mfma_f32_16x16x32_bf16(a2, b, acc2[nt * 4 + f], 0, 0, 0);
            }
    }
    #pragma unroll
    for (int nt = 0; nt < 4; nt++)
        #pragma unroll
        for (int f = 0; f < 4; f++) {
            int col = nt * 64 + f * 16 + cl;
            if (col >= 200) continue;
            #pragma unroll
            for (int r = 0; r < 4; r++) {
                int row = rbase + r;
                if (row < M) hp2[(long)row * 200 + col] = f2bf(acc2[nt * 4 + f][r]);
            }
        }
}

// ---------------------------------------------------------------------------
// Fused layer-2 GAT: 0.2 head-mean folded into alpha; fused bias +
// log_softmax; hp row stride 200 (400 B); final rows to d_out. ELL slots.
__global__ __launch_bounds__(256) void aggr2_fused(
    const int* __restrict__ cnt, const unsigned short* __restrict__ slots,
    const float* __restrict__ a_s, const float* __restrict__ a_d,
    const unsigned short* __restrict__ hp, const float* __restrict__ bias,
    float* __restrict__ out)
{
    __shared__ float alph[4][320];   // [wave][edge*5 + h]
    int wid = (blockIdx.x * blockDim.x + threadIdx.x) >> 6;
    int w = threadIdx.x >> 6;
    int lane = threadIdx.x & 63;
    if (wid >= N_NODES) return;
    int deg = cnt[wid];
    if (deg > SLOTW) deg = SLOTW;
    const unsigned short* myslot = slots + wid * SLOTW;

    float adh[HEADS];
    #pragma unroll
    for (int h = 0; h < HEADS; h++) adh[h] = a_d[wid * HEADS + h];

    const bool act = lane < 50;
    const int ch4 = lane * 4;
    const int hq  = act ? lane / 10 : 0;
    const char* hpB = (const char*)hp;
    float acc0 = 0.f, acc1 = 0.f, acc2 = 0.f, acc3 = 0.f;

    if (deg <= 64) {
        bool has = lane < deg;
        int s = has ? (int)myslot[lane] : 0;
        int rowoff = s * 400;
        float v[HEADS], mx[HEADS], sm[HEADS];
        #pragma unroll
        for (int h = 0; h < HEADS; h++) {
            v[h] = has ? lrelu(a_s[s * HEADS + h] + adh[h]) : -1e30f;
            mx[h] = v[h];
        }
        #pragma unroll
        for (int h = 0; h < HEADS; h++)
            #pragma unroll
            for (int off = 32; off; off >>= 1)
                mx[h] = fmaxf(mx[h], __shfl_xor(mx[h], off));
        #pragma unroll
        for (int h = 0; h < HEADS; h++) {
            float e = has ? __expf(v[h] - mx[h]) : 0.f;
            v[h] = e;
            sm[h] = e;
        }
        #pragma unroll
        for (int h = 0; h < HEADS; h++)
            #pragma unroll
            for (int off = 32; off; off >>= 1)
                sm[h] += __shfl_xor(sm[h], off);
        if (has) {
            #pragma unroll
            for (int h = 0; h < HEADS; h++)
                alph[w][lane * 5 + h] = 0.2f * v[h] / (sm[h] + 1e-16f);
        }
        int i = 0;
        for (; i + 7 < deg; i += 8) {
            ushort4 q[8]; float a[8];
            #pragma unroll
            for (int k = 0; k < 8; k++) {
                int off = __shfl(rowoff, i + k);
                q[k] = act ? *(const ushort4*)(hpB + off + ch4 * 2)
                           : make_ushort4(0, 0, 0, 0);
                a[k] = alph[w][(i + k) * 5 + hq];
            }
            #pragma unroll
            for (int k = 0; k < 8; k++) {
                acc0 += bf2f(q[k].x) * a[k];
                acc1 += bf2f(q[k].y) * a[k];
                acc2 += bf2f(q[k].z) * a[k];
                acc3 += bf2f(q[k].w) * a[k];
            }
        }
        for (; i < deg; i++) {
            int off = __shfl(rowoff, i);
            if (act) {
                ushort4 q0 = *(const ushort4*)(hpB + off + ch4 * 2);
                float a0 = alph[w][i * 5 + hq];
                acc0 += bf2f(q0.x) * a0;
                acc1 += bf2f(q0.y) * a0;
                acc2 += bf2f(q0.z) * a0;
                acc3 += bf2f(q0.w) * a0;
            }
        }
    } else {
        float mx[HEADS], inv[HEADS], sm[HEADS] = {};
        #pragma unroll
        for (int h = 0; h < HEADS; h++) mx[h] = -1e30f;
        for (int e = lane; e < deg; e += 64) {
            int s = myslot[e];
            #pragma unroll
            for (int h = 0; h < HEADS; h++)
                mx[h] = fmaxf(mx[h], lrelu(a_s[s * HEADS + h] + adh[h]));
        }
        #pragma unroll
        for (int h = 0; h < HEADS; h++)
            #pragma unroll
            for (int off = 32; off; off >>= 1)
                mx[h] = fmaxf(mx[h], __shfl_xor(mx[h], off));
        for (int e = lane; e < deg; e += 64) {
            int s = myslot[e];
            #pragma unroll
            for (int h = 0; h < HEADS; h++)
                sm[h] += __expf(lrelu(a_s[s * HEADS + h] + adh[h]) - mx[h]);
        }
        #pragma unroll
        for (int h = 0; h < HEADS; h++) {
            #pragma unroll
            for (int off = 32; off; off >>= 1)
                sm[h] += __shfl_xor(sm[h], off);
            inv[h] = 0.2f / (sm[h] + 1e-16f);
        }
        for (int e = 0; e < deg; e++) {
            int s0 = myslot[e];
            if (act) {
                ushort4 q0 = *(const ushort4*)(hpB + s0 * 400 + ch4 * 2);
                float a0 = __expf(lrelu(a_s[s0 * HEADS + hq] + adh[hq]) - mx[hq]) * inv[hq];
                acc0 += bf2f(q0.x) * a0;
                acc1 += bf2f(q0.y) * a0;
                acc2 += bf2f(q0.z) * a0;
                acc3 += bf2f(q0.w) * a0;
            }
        }
    }

    float r0 = acc0, r1 = acc1, r2 = acc2, r3 = acc3;
    #pragma unroll
    for (int h5 = 1; h5 < 5; h5++) {
        int sl = (lane + 10 * h5) & 63;
        r0 += __shfl(acc0, sl);
        r1 += __shfl(acc1, sl);
        r2 += __shfl(acc2, sl);
        r3 += __shfl(acc3, sl);
    }

    float vb0 = -1e30f, vb1 = -1e30f, vb2 = -1e30f, vb3 = -1e30f;
    if (lane < 10) {
        vb0 = r0 + bias[ch4 + 0];
        vb1 = r1 + bias[ch4 + 1];
        vb2 = r2 + bias[ch4 + 2];
        vb3 = r3 + bias[ch4 + 3];
    }
    float mxv = fmaxf(fmaxf(vb0, vb1), fmaxf(vb2, vb3));
    #pragma unroll
    for (int off = 32; off; off >>= 1)
        mxv = fmaxf(mxv, __shfl_xor(mxv, off));
    float sme = 0.f;
    if (lane < 10)
        sme = __expf(vb0 - mxv) + __expf(vb1 - mxv) +
              __expf(vb2 - mxv) + __expf(vb3 - mxv);
    #pragma unroll
    for (int off = 32; off; off >>= 1)
        sme += __shfl_xor(sme, off);
    float ls = mxv + __logf(sme);
    if (lane < 10) {
        float4 o = make_float4(vb0 - ls, vb1 - ls, vb2 - ls, vb3 - ls);
        *(float4*)(out + (long)wid * CLS + ch4) = o;
    }
}

// ---------------------------------------------------------------------------
extern "C" void kernel_launch(void* const* d_in, const int* in_sizes, int n_in,
                              void* d_out, int out_size, void* d_ws, size_t ws_size,
                              hipStream_t stream)
{
    const float* x     = (const float*)d_in[0];
    const int*   ei    = (const int*)d_in[1];
    const float* emb_W = (const float*)d_in[2];
    const float* emb_b = (const float*)d_in[3];
    const float* W1    = (const float*)d_in[4];
    const float* as1   = (const float*)d_in[5];
    const float* ad1   = (const float*)d_in[6];
    const float* b1    = (const float*)d_in[7];
    const float* W2    = (const float*)d_in[8];
    const float* as2   = (const float*)d_in[9];
    const float* ad2   = (const float*)d_in[10];
    const float* b2    = (const float*)d_in[11];

    float* out_emb = (float*)d_out;                         // [N,64] f32
    float* out_cls = (float*)d_out + (size_t)N_NODES * HID; // [N,40] f32

    char* ws = (char*)d_ws;
    unsigned short* e_agg  = (unsigned short*)(ws);               // 32 MB [N,320]
    unsigned short* hp2b   = (unsigned short*)(ws + 32000000);    // 20 MB [N,200]
    unsigned short* embb   = (unsigned short*)(ws + 64000000);    // 6.4 MB [N,64]
    float*          a_s1   = (float*)(ws + 70400000);             // 1 MB
    float*          a_d1   = (float*)(ws + 71400000);             // 1 MB
    float*          a_s2   = (float*)(ws + 72400000);             // 1 MB
    float*          a_d2   = (float*)(ws + 73400000);             // 1 MB
    unsigned short* Bp0    = (unsigned short*)(ws + 74400000);    // 16 KB
    unsigned short* Bp1    = (unsigned short*)(ws + 74500000);    // 40 KB
    unsigned short* Bp2    = (unsigned short*)(ws + 74600000);    // 160 KB
    float*          u1s    = (float*)(ws + 74800000);             // 1.3 KB
    float*          u1d    = (float*)(ws + 74810000);
    float*          u2s    = (float*)(ws + 74820000);             // 6.4 KB
    float*          u2d    = (float*)(ws + 74830000);
    int*            cnt    = (int*)(ws + 74840000);               // 200 KB
    unsigned short* slots  = (unsigned short*)(ws + 75100000);    // 9.6 MB

    const dim3 blk(256);
    const int eb  = (ETOT + 255) / 256;
    const int nb4 = (N_NODES + 3) / 4;
    const int mgrid = (N_NODES + 63) / 64;         // 782

    // ---- graph build (ELL) + weight packing + u-vector precompute ----
    hipMemsetAsync(cnt, 0, (size_t)N_NODES * 4, stream);
    build_graph<<<eb, blk, 0, stream>>>(ei, cnt, slots, emb_W, W1, W2,
                                        as1, ad1, as2, ad2,
                                        Bp0, Bp1, Bp2, u1s, u1d, u2s, u2d);

    // ---- embedding (output 0 f32 + bf16 copy) + layer-1 scores ----
    gemm_mfma_emb<<<mgrid, blk, 0, stream>>>(x, Bp0, emb_b, u1s, u1d,
                                             out_emb, embb, a_s1, a_d1, N_NODES);

    // ---- layer 1: aggregate pre-projection emb ----
    aggr1_new<<<nb4, blk, 0, stream>>>(cnt, slots, a_s1, a_d1, embb, e_agg);

    // ---- fused: head-mix GEMM + ELU + layer-2 scores + layer-2 GEMM ----
    gemm_mix_l2<<<mgrid, blk, 0, stream>>>(e_agg, Bp1, Bp2, b1, u2s, u2d,
                                           hp2b, a_s2, a_d2, N_NODES);

    // ---- layer-2 aggregation + log_softmax ----
    aggr2_fused<<<nb4, blk, 0, stream>>>(cnt, slots, a_s2, a_d2, hp2b, b2, out_cls);
}